// Round 1
// baseline (6536.304 us; speedup 1.0000x reference)
//
#include <hip/hip_runtime.h>
#include <math.h>

// ---------------- problem constants ----------------
#define NN    50000
#define EE    800000
#define CIN   64
#define HH    192
#define EDIM  16
#define GG    2048
#define H3    576   // 3*H

// ---------------- helpers ----------------
__device__ __forceinline__ unsigned fmap(float f) {
    unsigned u = __float_as_uint(f);
    return (u & 0x80000000u) ? ~u : (u | 0x80000000u);
}
__device__ __forceinline__ float funmap(unsigned u) {
    if (u == 0u) return 0.0f;                 // empty segment sentinel
    return (u & 0x80000000u) ? __uint_as_float(u ^ 0x80000000u)
                             : __uint_as_float(~u);
}

// ---------------- generic tiled GEMM: C[M,Nout] = act(A[M,K] @ W[Nout,K]^T + bias) ----------------
// Nout must be a multiple of 64; K a multiple of 16. act: 0=none, 1=leaky_relu(0.01)
__global__ __launch_bounds__(256) void gemm_nt(const float* __restrict__ A,
                                               const float* __restrict__ W,
                                               const float* __restrict__ bias,
                                               float* __restrict__ C,
                                               int M, int Nout, int K, int act)
{
    __shared__ __align__(16) float sA[16][68];
    __shared__ __align__(16) float sB[16][68];
    const int tid = threadIdx.x;
    const int tx = tid & 15, ty = tid >> 4;
    const int m0 = blockIdx.x << 6, n0 = blockIdx.y << 6;
    const int lr = tid >> 2;            // 0..63
    const int lk = (tid & 3) << 2;      // 0,4,8,12
    float acc[4][4] = {};

    for (int k0 = 0; k0 < K; k0 += 16) {
        float4 av = {0.f, 0.f, 0.f, 0.f};
        int gm = m0 + lr;
        if (gm < M) av = *(const float4*)(A + (size_t)gm * K + k0 + lk);
        sA[lk + 0][lr] = av.x; sA[lk + 1][lr] = av.y;
        sA[lk + 2][lr] = av.z; sA[lk + 3][lr] = av.w;
        float4 bv = *(const float4*)(W + (size_t)(n0 + lr) * K + k0 + lk);
        sB[lk + 0][lr] = bv.x; sB[lk + 1][lr] = bv.y;
        sB[lk + 2][lr] = bv.z; sB[lk + 3][lr] = bv.w;
        __syncthreads();
        #pragma unroll
        for (int kk = 0; kk < 16; kk++) {
            float4 a = *(const float4*)&sA[kk][ty << 2];
            float4 b = *(const float4*)&sB[kk][tx << 2];
            acc[0][0] += a.x * b.x; acc[0][1] += a.x * b.y; acc[0][2] += a.x * b.z; acc[0][3] += a.x * b.w;
            acc[1][0] += a.y * b.x; acc[1][1] += a.y * b.y; acc[1][2] += a.y * b.z; acc[1][3] += a.y * b.w;
            acc[2][0] += a.z * b.x; acc[2][1] += a.z * b.y; acc[2][2] += a.z * b.z; acc[2][3] += a.z * b.w;
            acc[3][0] += a.w * b.x; acc[3][1] += a.w * b.y; acc[3][2] += a.w * b.z; acc[3][3] += a.w * b.w;
        }
        __syncthreads();
    }
    const int gn = n0 + (tx << 2);
    #pragma unroll
    for (int i = 0; i < 4; i++) {
        int gm = m0 + (ty << 2) + i;
        if (gm >= M) continue;
        float4 c = {acc[i][0], acc[i][1], acc[i][2], acc[i][3]};
        if (bias) {
            float4 b4 = *(const float4*)(bias + gn);
            c.x += b4.x; c.y += b4.y; c.z += b4.z; c.w += b4.w;
        }
        if (act == 1) {
            c.x = c.x >= 0.f ? c.x : 0.01f * c.x;
            c.y = c.y >= 0.f ? c.y : 0.01f * c.y;
            c.z = c.z >= 0.f ? c.z : 0.01f * c.z;
            c.w = c.w >= 0.f ? c.w : 0.01f * c.w;
        }
        *(float4*)(C + (size_t)gm * Nout + gn) = c;
    }
}

// ---------------- fused GRU: x = relu(GRU(h, x)) in place. K=192, 3H=576 hardcoded. ----------------
// Block: 256 threads, 32 rows. Thread (r=tid&15, cg=tid>>4) owns rows r,r+16 and cols cg*4+64q+i.
// Col quads q and q+3 and q+6 form the (c, c+192, c+384) gate triples in-thread.
__global__ __launch_bounds__(256) void gru_fused(const float* __restrict__ Hm,
                                                 float* __restrict__ X,
                                                 const float* __restrict__ Wih,
                                                 const float* __restrict__ Whh,
                                                 const float* __restrict__ bih,
                                                 const float* __restrict__ bhh,
                                                 int M)
{
    __shared__ __align__(16) float sAh[32][17];
    __shared__ __align__(16) float sAx[32][17];
    __shared__ __align__(16) float sWi[16][580];
    __shared__ __align__(16) float sWh[16][580];
    const int tid = threadIdx.x;
    const int r  = tid & 15;
    const int cg = tid >> 4;            // 0..15
    const int node0 = blockIdx.x << 5;  // *32

    float gi[2][36];
    float gh[2][36];
    #pragma unroll
    for (int h = 0; h < 2; h++)
        #pragma unroll
        for (int j = 0; j < 36; j++) { gi[h][j] = 0.f; gh[h][j] = 0.f; }

    for (int k0 = 0; k0 < 192; k0 += 16) {
        // stage A tiles (h rows and x rows), 32x16 each
        {
            int t = tid & 127;
            int row = t >> 2;
            int kq = (t & 3) << 2;
            int gm = node0 + row;
            const float* srcp = (tid >= 128) ? X : Hm;
            float4 v = {0.f, 0.f, 0.f, 0.f};
            if (gm < M) v = *(const float4*)(srcp + (size_t)gm * 192 + k0 + kq);
            float* dp = (tid >= 128) ? &sAx[row][kq] : &sAh[row][kq];
            dp[0] = v.x; dp[1] = v.y; dp[2] = v.z; dp[3] = v.w;
        }
        // stage W tiles transposed: sW[kk][c] = W[c*192 + k0 + kk], 576x16 each
        #pragma unroll
        for (int it = 0; it < 9; it++) {
            int idx = it * 256 + tid;       // 0..2303
            int c = idx >> 2;
            int kq = (idx & 3) << 2;
            float4 vi = *(const float4*)(Wih + (size_t)c * 192 + k0 + kq);
            float4 vh = *(const float4*)(Whh + (size_t)c * 192 + k0 + kq);
            sWi[kq + 0][c] = vi.x; sWi[kq + 1][c] = vi.y; sWi[kq + 2][c] = vi.z; sWi[kq + 3][c] = vi.w;
            sWh[kq + 0][c] = vh.x; sWh[kq + 1][c] = vh.y; sWh[kq + 2][c] = vh.z; sWh[kq + 3][c] = vh.w;
        }
        __syncthreads();
        #pragma unroll
        for (int kk = 0; kk < 16; kk++) {
            float ah0 = sAh[r][kk];
            float ah1 = sAh[r + 16][kk];
            float ax0 = sAx[r][kk];
            float ax1 = sAx[r + 16][kk];
            #pragma unroll
            for (int q = 0; q < 9; q++) {
                float4 wi = *(const float4*)&sWi[kk][(cg << 2) + (q << 6)];
                float4 wh = *(const float4*)&sWh[kk][(cg << 2) + (q << 6)];
                gi[0][q * 4 + 0] += ah0 * wi.x; gi[0][q * 4 + 1] += ah0 * wi.y;
                gi[0][q * 4 + 2] += ah0 * wi.z; gi[0][q * 4 + 3] += ah0 * wi.w;
                gi[1][q * 4 + 0] += ah1 * wi.x; gi[1][q * 4 + 1] += ah1 * wi.y;
                gi[1][q * 4 + 2] += ah1 * wi.z; gi[1][q * 4 + 3] += ah1 * wi.w;
                gh[0][q * 4 + 0] += ax0 * wh.x; gh[0][q * 4 + 1] += ax0 * wh.y;
                gh[0][q * 4 + 2] += ax0 * wh.z; gh[0][q * 4 + 3] += ax0 * wh.w;
                gh[1][q * 4 + 0] += ax1 * wh.x; gh[1][q * 4 + 1] += ax1 * wh.y;
                gh[1][q * 4 + 2] += ax1 * wh.z; gh[1][q * 4 + 3] += ax1 * wh.w;
            }
        }
        __syncthreads();
    }
    // epilogue: combine gates, relu, write x in place
    #pragma unroll
    for (int half = 0; half < 2; half++) {
        int node = node0 + r + (half << 4);
        if (node >= M) continue;
        #pragma unroll
        for (int q = 0; q < 3; q++) {
            int cb = (cg << 2) + (q << 6);   // in [0,192)
            float4 hx4 = *(const float4*)(X + (size_t)node * 192 + cb);
            float hxv[4] = {hx4.x, hx4.y, hx4.z, hx4.w};
            float res[4];
            #pragma unroll
            for (int j = 0; j < 4; j++) {
                int c = cb + j;
                float ir  = gi[half][q * 4 + j]       + bih[c];
                float iz  = gi[half][(q + 3) * 4 + j] + bih[c + 192];
                float inn = gi[half][(q + 6) * 4 + j] + bih[c + 384];
                float hr  = gh[half][q * 4 + j]       + bhh[c];
                float hz  = gh[half][(q + 3) * 4 + j] + bhh[c + 192];
                float hn  = gh[half][(q + 6) * 4 + j] + bhh[c + 384];
                float rg = 1.f / (1.f + expf(-(ir + hr)));
                float zg = 1.f / (1.f + expf(-(iz + hz)));
                float ng = tanhf(inn + rg * hn);
                float o = (1.f - zg) * ng + zg * hxv[j];
                res[j] = o > 0.f ? o : 0.f;
            }
            float4 r4 = {res[0], res[1], res[2], res[3]};
            *(float4*)(X + (size_t)node * 192 + cb) = r4;
        }
    }
}

// ---------------- small vector compose: out[j] = sum_i v[i]*W[i*cols+j] ----------------
__global__ void compose_vec(const float* __restrict__ W, const float* __restrict__ v,
                            float* __restrict__ out, int rows, int cols)
{
    int j = threadIdx.x;
    if (j >= cols) return;
    float acc = 0.f;
    for (int i = 0; i < rows; i++) acc += v[i] * W[(size_t)i * cols + j];
    out[j] = acc;
}

// ---------------- edge_attr column sums (for mean fill) ----------------
__global__ void ea_sum_kernel(const float* __restrict__ ea, float* __restrict__ sums, int E)
{
    int lane = threadIdx.x & 63;
    float acc[16];
    #pragma unroll
    for (int f = 0; f < 16; f++) acc[f] = 0.f;
    for (int e = blockIdx.x * blockDim.x + threadIdx.x; e < E; e += gridDim.x * blockDim.x) {
        const float4* p = (const float4*)(ea + (size_t)e * 16);
        float4 v0 = p[0], v1 = p[1], v2 = p[2], v3 = p[3];
        acc[0] += v0.x; acc[1] += v0.y; acc[2] += v0.z; acc[3] += v0.w;
        acc[4] += v1.x; acc[5] += v1.y; acc[6] += v1.z; acc[7] += v1.w;
        acc[8] += v2.x; acc[9] += v2.y; acc[10] += v2.z; acc[11] += v2.w;
        acc[12] += v3.x; acc[13] += v3.y; acc[14] += v3.z; acc[15] += v3.w;
    }
    #pragma unroll
    for (int off = 32; off > 0; off >>= 1)
        #pragma unroll
        for (int f = 0; f < 16; f++) acc[f] += __shfl_down(acc[f], off);
    if (lane == 0)
        #pragma unroll
        for (int f = 0; f < 16; f++) atomicAdd(&sums[f], acc[f]);
}

__global__ void finalize_aloop(const float* __restrict__ sums, const float* __restrict__ ve,
                               float* __restrict__ aloop, float invE)
{
    if (threadIdx.x == 0) {
        float a = 0.f;
        for (int f = 0; f < 16; f++) a += sums[f] * invE * ve[f];
        *aloop = a;
    }
}

// ---------------- per-row dots: o1 = Mat[row].v1 (+bias), o2 = Mat[row].v2 ----------------
__global__ void row_dots(const float* __restrict__ Mat, int M,
                         const float* __restrict__ v1, float* __restrict__ o1,
                         const float* __restrict__ v2, float* __restrict__ o2,
                         const float* __restrict__ bias)
{
    int row = blockIdx.x * 4 + (threadIdx.x >> 6);
    if (row >= M) return;
    int lane = threadIdx.x & 63;
    const float* rp = Mat + (size_t)row * 192;
    float a1 = 0.f, a2 = 0.f;
    #pragma unroll
    for (int k = 0; k < 3; k++) {
        int f = lane + 64 * k;
        float x = rp[f];
        a1 += x * v1[f];
        if (o2) a2 += x * v2[f];
    }
    #pragma unroll
    for (int off = 32; off > 0; off >>= 1) {
        a1 += __shfl_down(a1, off);
        a2 += __shfl_down(a2, off);
    }
    if (lane == 0) {
        o1[row] = a1 + (bias ? bias[0] : 0.f);
        if (o2) o2[row] = a2;
    }
}

// ---------------- alpha + segment max ----------------
// i < E_real: real edge (src = src[i] or i if src==nullptr; dst=dstp[i]); i >= E_real: self loop i-E_real.
__global__ void edge_alpha_max(const int* __restrict__ srcp, const int* __restrict__ dstp,
                               int E_real, int Etot,
                               const float* __restrict__ as_, const float* __restrict__ ad_,
                               const float* __restrict__ ea, const float* __restrict__ ve,
                               const float* __restrict__ aloop, float slope,
                               float* __restrict__ ab, unsigned* __restrict__ mb)
{
    int i = blockIdx.x * blockDim.x + threadIdx.x;
    if (i >= Etot) return;
    int s_, d_;
    float aext = 0.f;
    if (i < E_real) {
        s_ = srcp ? srcp[i] : i;
        d_ = dstp[i];
        if (ea) {
            const float4* p = (const float4*)(ea + (size_t)i * 16);
            const float4* q = (const float4*)ve;
            float4 e0 = p[0], e1 = p[1], e2 = p[2], e3 = p[3];
            float4 w0 = q[0], w1 = q[1], w2 = q[2], w3 = q[3];
            aext = e0.x * w0.x + e0.y * w0.y + e0.z * w0.z + e0.w * w0.w
                 + e1.x * w1.x + e1.y * w1.y + e1.z * w1.z + e1.w * w1.w
                 + e2.x * w2.x + e2.y * w2.y + e2.z * w2.z + e2.w * w2.w
                 + e3.x * w3.x + e3.y * w3.y + e3.z * w3.z + e3.w * w3.w;
        }
    } else {
        s_ = d_ = i - E_real;
        aext = *aloop;
    }
    float a = as_[s_] + ad_[d_] + aext;
    a = a >= 0.f ? a : slope * a;
    ab[i] = a;
    atomicMax(&mb[d_], fmap(a));
}

// ---------------- exp(alpha - max) + segment sum ----------------
__global__ void edge_exp_sum(const int* __restrict__ dstp, int E_real, int Etot,
                             float* __restrict__ ab, const unsigned* __restrict__ mb,
                             float* __restrict__ sb)
{
    int i = blockIdx.x * blockDim.x + threadIdx.x;
    if (i >= Etot) return;
    int d_ = (i < E_real) ? dstp[i] : i - E_real;
    float m = funmap(mb[d_]);
    float e = expf(ab[i] - m);
    ab[i] = e;
    atomicAdd(&sb[d_], e);
}

// ---------------- aggregate: out[dst] += (e/(s+eps)) * F[src] ---- wave per edge ----------------
__global__ void edge_aggregate(const int* __restrict__ srcp, const int* __restrict__ dstp,
                               int E_real, int Etot,
                               const float* __restrict__ ab, const float* __restrict__ sb,
                               const float* __restrict__ F, float* __restrict__ out)
{
    int e = blockIdx.x * 4 + (threadIdx.x >> 6);
    if (e >= Etot) return;
    int lane = threadIdx.x & 63;
    int s_, d_;
    if (e < E_real) { s_ = srcp ? srcp[e] : e; d_ = dstp[e]; }
    else            { s_ = d_ = e - E_real; }
    float w = ab[e] / (sb[d_] + 1e-16f);
    const float* fr = F + (size_t)s_ * 192;
    float* orow = out + (size_t)d_ * 192;
    atomicAdd(&orow[lane],       w * fr[lane]);
    atomicAdd(&orow[lane + 64],  w * fr[lane + 64]);
    atomicAdd(&orow[lane + 128], w * fr[lane + 128]);
}

// ---------------- h = elu(h + b[f]) ----------------
__global__ void bias_elu_kernel(float* __restrict__ h, const float* __restrict__ b, int total)
{
    int i = blockIdx.x * blockDim.x + threadIdx.x;
    if (i >= total) return;
    int f = i % 192;
    float v = h[i] + b[f];
    h[i] = v > 0.f ? v : expm1f(v);
}

// ---------------- global add pool (batch scatter) ----------------
__global__ void pool_kernel(const float* __restrict__ X, const int* __restrict__ batch,
                            float* __restrict__ outg, int n_nodes)
{
    int idx = blockIdx.x * blockDim.x + threadIdx.x;
    if (idx >= n_nodes * 192) return;
    int n = idx / 192, f = idx % 192;
    atomicAdd(&outg[(size_t)batch[n] * 192 + f], X[idx]);
}

__global__ void relu_kernel(float* __restrict__ p, int total)
{
    int i = blockIdx.x * blockDim.x + threadIdx.x;
    if (i >= total) return;
    float v = p[i];
    p[i] = v > 0.f ? v : 0.f;
}

// ---------------- launch ----------------
extern "C" void kernel_launch(void* const* d_in, const int* in_sizes, int n_in,
                              void* d_out, int out_size, void* d_ws, size_t ws_size,
                              hipStream_t stream)
{
    const float* x_in        = (const float*)d_in[0];
    const int*   ei          = (const int*)  d_in[1];
    const float* eattr       = (const float*)d_in[2];
    const int*   batch       = (const int*)  d_in[3];
    const float* lin1_W      = (const float*)d_in[4];
    const float* lin1_b      = (const float*)d_in[5];
    const float* conv0_W     = (const float*)d_in[6];
    const float* conv0_att_s = (const float*)d_in[7];
    const float* conv0_att_d = (const float*)d_in[8];
    const float* conv0_We    = (const float*)d_in[9];
    const float* conv0_att_e = (const float*)d_in[10];
    const float* conv0_b     = (const float*)d_in[11];
    const float* convs_W     = (const float*)d_in[12];
    const float* convs_att_s = (const float*)d_in[13];
    const float* convs_att_d = (const float*)d_in[14];
    const float* convs_b     = (const float*)d_in[15];
    const float* gru_Wih     = (const float*)d_in[16];
    const float* gru_Whh     = (const float*)d_in[17];
    const float* gru_bih     = (const float*)d_in[18];
    const float* gru_bhh     = (const float*)d_in[19];
    const float* mol_Wsrc    = (const float*)d_in[20];
    const float* mol_Wdst    = (const float*)d_in[21];
    const float* mol_att_s   = (const float*)d_in[22];
    const float* mol_att_d   = (const float*)d_in[23];
    const float* mol_b       = (const float*)d_in[24];
    const float* mgru_Wih    = (const float*)d_in[25];
    const float* mgru_Whh    = (const float*)d_in[26];
    const float* mgru_bih    = (const float*)d_in[27];
    const float* mgru_bhh    = (const float*)d_in[28];
    const float* lin2_W      = (const float*)d_in[29];
    const float* lin2_b      = (const float*)d_in[30];

    const int* src = ei;
    const int* dst = ei + EE;

    // workspace layout (floats)
    float* ws = (float*)d_ws;
    size_t o = 0;
    auto alloc = [&](size_t n) { float* p = ws + o; o += n; return p; };
    float*    xbuf  = alloc((size_t)NN * HH);
    float*    wbuf  = alloc((size_t)NN * HH);
    float*    hbuf  = alloc((size_t)NN * HH);
    float*    abuf  = alloc(EE + NN);
    float*    asb   = alloc(NN);
    float*    adb   = alloc(NN);
    unsigned* mb    = (unsigned*)alloc(NN);
    float*    sb    = alloc(NN);
    float*    outg  = alloc((size_t)GG * HH);
    float*    hg    = alloc((size_t)GG * HH);
    float*    adg   = alloc(GG);
    unsigned* mg    = (unsigned*)alloc(GG);
    float*    sg    = alloc(GG);
    float*    ve    = alloc(16);
    float*    easum = alloc(16);
    float*    vd    = alloc(HH);
    float*    aloop = alloc(4);
    if (ws_size < o * sizeof(float)) return;   // insufficient scratch: bail (fails visibly)

    const int gemmMx = (NN + 63) / 64;

    // ---- lin1: x = lrelu(x @ lin1_W^T + b, 0.01) ----
    gemm_nt<<<dim3(gemmMx, HH / 64), 256, 0, stream>>>(x_in, lin1_W, lin1_b, xbuf, NN, HH, CIN, 1);

    // ---- conv0 prep: ve = att_e @ We ; mean edge_attr -> aloop ----
    compose_vec<<<1, 256, 0, stream>>>(conv0_We, conv0_att_e, ve, HH, EDIM);
    hipMemsetAsync(easum, 0, 16 * sizeof(float), stream);
    ea_sum_kernel<<<256, 256, 0, stream>>>(eattr, easum, EE);
    finalize_aloop<<<1, 64, 0, stream>>>(easum, ve, aloop, 1.0f / EE);

    // ---- conv0 (edge feats + self loops, slope 0.2) ----
    gemm_nt<<<dim3(gemmMx, HH / 64), 256, 0, stream>>>(xbuf, conv0_W, nullptr, wbuf, NN, HH, HH, 0);
    row_dots<<<(NN + 3) / 4, 256, 0, stream>>>(wbuf, NN, conv0_att_s, asb, conv0_att_d, adb, nullptr);
    hipMemsetAsync(mb, 0, NN * sizeof(unsigned), stream);
    edge_alpha_max<<<(EE + NN + 255) / 256, 256, 0, stream>>>(src, dst, EE, EE + NN, asb, adb,
                                                              eattr, ve, aloop, 0.2f, abuf, mb);
    hipMemsetAsync(sb, 0, NN * sizeof(float), stream);
    edge_exp_sum<<<(EE + NN + 255) / 256, 256, 0, stream>>>(dst, EE, EE + NN, abuf, mb, sb);
    hipMemsetAsync(hbuf, 0, (size_t)NN * HH * sizeof(float), stream);
    edge_aggregate<<<(EE + NN + 3) / 4, 256, 0, stream>>>(src, dst, EE, EE + NN, abuf, sb, wbuf, hbuf);
    bias_elu_kernel<<<(NN * HH + 255) / 256, 256, 0, stream>>>(hbuf, conv0_b, NN * HH);
    gru_fused<<<(NN + 31) / 32, 256, 0, stream>>>(hbuf, xbuf, gru_Wih, gru_Whh, gru_bih, gru_bhh, NN);

    // ---- remaining atom convs (no self loops, slope 0.01) ----
    for (int l = 0; l < 2; l++) {
        gemm_nt<<<dim3(gemmMx, HH / 64), 256, 0, stream>>>(xbuf, convs_W + (size_t)l * HH * HH,
                                                           nullptr, wbuf, NN, HH, HH, 0);
        row_dots<<<(NN + 3) / 4, 256, 0, stream>>>(wbuf, NN, convs_att_s + l * HH, asb,
                                                   convs_att_d + l * HH, adb, nullptr);
        hipMemsetAsync(mb, 0, NN * sizeof(unsigned), stream);
        edge_alpha_max<<<(EE + 255) / 256, 256, 0, stream>>>(src, dst, EE, EE, asb, adb,
                                                             nullptr, nullptr, nullptr, 0.01f, abuf, mb);
        hipMemsetAsync(sb, 0, NN * sizeof(float), stream);
        edge_exp_sum<<<(EE + 255) / 256, 256, 0, stream>>>(dst, EE, EE, abuf, mb, sb);
        hipMemsetAsync(hbuf, 0, (size_t)NN * HH * sizeof(float), stream);
        edge_aggregate<<<(EE + 3) / 4, 256, 0, stream>>>(src, dst, EE, EE, abuf, sb, wbuf, hbuf);
        bias_elu_kernel<<<(NN * HH + 255) / 256, 256, 0, stream>>>(hbuf, convs_b + l * HH, NN * HH);
        gru_fused<<<(NN + 31) / 32, 256, 0, stream>>>(hbuf, xbuf,
                                                      gru_Wih + (size_t)(l + 1) * H3 * HH,
                                                      gru_Whh + (size_t)(l + 1) * H3 * HH,
                                                      gru_bih + (size_t)(l + 1) * H3,
                                                      gru_bhh + (size_t)(l + 1) * H3, NN);
    }

    // ---- molecule readout ----
    hipMemsetAsync(outg, 0, (size_t)GG * HH * sizeof(float), stream);
    pool_kernel<<<(NN * HH + 255) / 256, 256, 0, stream>>>(xbuf, batch, outg, NN);
    relu_kernel<<<(GG * HH + 255) / 256, 256, 0, stream>>>(outg, GG * HH);
    gemm_nt<<<dim3(gemmMx, HH / 64), 256, 0, stream>>>(xbuf, mol_Wsrc, nullptr, wbuf, NN, HH, HH, 0);
    row_dots<<<(NN + 3) / 4, 256, 0, stream>>>(wbuf, NN, mol_att_s, asb, nullptr, nullptr, nullptr);
    compose_vec<<<1, 256, 0, stream>>>(mol_Wdst, mol_att_d, vd, HH, HH);

    for (int t = 0; t < 2; t++) {
        row_dots<<<(GG + 3) / 4, 256, 0, stream>>>(outg, GG, vd, adg, nullptr, nullptr, nullptr);
        hipMemsetAsync(mg, 0, GG * sizeof(unsigned), stream);
        edge_alpha_max<<<(NN + 255) / 256, 256, 0, stream>>>(nullptr, batch, NN, NN, asb, adg,
                                                             nullptr, nullptr, nullptr, 0.01f, abuf, mg);
        hipMemsetAsync(sg, 0, GG * sizeof(float), stream);
        edge_exp_sum<<<(NN + 255) / 256, 256, 0, stream>>>(batch, NN, NN, abuf, mg, sg);
        hipMemsetAsync(hg, 0, (size_t)GG * HH * sizeof(float), stream);
        edge_aggregate<<<(NN + 3) / 4, 256, 0, stream>>>(nullptr, batch, NN, NN, abuf, sg, wbuf, hg);
        bias_elu_kernel<<<(GG * HH + 255) / 256, 256, 0, stream>>>(hg, mol_b, GG * HH);
        gru_fused<<<(GG + 31) / 32, 256, 0, stream>>>(hg, outg, mgru_Wih, mgru_Whh, mgru_bih, mgru_bhh, GG);
    }

    // ---- final linear ----
    row_dots<<<(GG + 3) / 4, 256, 0, stream>>>(outg, GG, lin2_W, (float*)d_out,
                                               nullptr, nullptr, lin2_b);
}

// Round 2
// 3253.278 us; speedup vs baseline: 2.0091x; 2.0091x over previous
//
#include <hip/hip_runtime.h>
#include <math.h>

// ---------------- problem constants ----------------
#define NN    50000
#define EE    800000
#define CIN   64
#define HH    192
#define EDIM  16
#define GG    2048
#define H3    576   // 3*H

typedef _Float16 f16;
typedef _Float16 half8 __attribute__((ext_vector_type(8)));
typedef float f32x4 __attribute__((ext_vector_type(4)));

// ---------------- helpers ----------------
__device__ __forceinline__ unsigned fmap(float f) {
    unsigned u = __float_as_uint(f);
    return (u & 0x80000000u) ? ~u : (u | 0x80000000u);
}
__device__ __forceinline__ float funmap(unsigned u) {
    if (u == 0u) return 0.0f;                 // empty segment sentinel
    return (u & 0x80000000u) ? __uint_as_float(u ^ 0x80000000u)
                             : __uint_as_float(~u);
}

// ---------------- fp32 -> fp16 converts ----------------
__global__ void cvt_f2h(const float* __restrict__ s, f16* __restrict__ d, int n)
{
    int i = blockIdx.x * blockDim.x + threadIdx.x;
    if (i < n) d[i] = (f16)s[i];
}

struct Cvt8 { const float* s[8]; f16* d[8]; int n[8]; };
__global__ void cvt_multi(Cvt8 c)
{
    int slot = blockIdx.y;
    int i = blockIdx.x * blockDim.x + threadIdx.x;
    if (i < c.n[slot]) c.d[slot][i] = (f16)c.s[slot][i];
}

// ---------------- MFMA GEMM: C[M,N] = act(A16[M,K] @ W16[N,K]^T + bias) ----------------
// block 256 thr = 4 waves (2x2), wave tile 32x32 (2x2 of 16x16), block tile 64x64.
// K multiple of 32; N multiple of 64. Cf (fp32) and/or Ch (fp16) outputs optional.
__global__ __launch_bounds__(256) void gemm_mfma(const f16* __restrict__ A,
                                                 const f16* __restrict__ W,
                                                 const float* __restrict__ bias,
                                                 float* __restrict__ Cf,
                                                 f16* __restrict__ Ch,
                                                 int M, int N, int K, int act)
{
    __shared__ __align__(16) f16 sA[64 * 40];
    const int tid  = threadIdx.x;
    const int lane = tid & 63;
    const int wid  = tid >> 6;
    const int wy = wid >> 1, wx = wid & 1;
    const int m0 = blockIdx.x << 6, n0 = blockIdx.y << 6;
    const int n_ = lane & 15, quad = lane >> 4;

    f32x4 acc[2][2] = {};
    int boff0 = (n0 + wx * 32 + n_) * K + quad * 8;
    int boff1 = boff0 + 16 * K;

    const int srow = tid >> 2;            // 0..63
    const int skc  = (tid & 3) << 3;      // 0,8,16,24

    for (int k0 = 0; k0 < K; k0 += 32) {
        half8 av = {};
        int gm = m0 + srow;
        if (gm < M) av = *(const half8*)(A + (size_t)gm * K + k0 + skc);
        *(half8*)(sA + srow * 40 + skc) = av;
        __syncthreads();
        half8 a0 = *(const half8*)(sA + (wy * 32 + n_) * 40 + quad * 8);
        half8 a1 = *(const half8*)(sA + (wy * 32 + 16 + n_) * 40 + quad * 8);
        half8 b0 = *(const half8*)(W + boff0 + k0);
        half8 b1 = *(const half8*)(W + boff1 + k0);
        acc[0][0] = __builtin_amdgcn_mfma_f32_16x16x32_f16(a0, b0, acc[0][0], 0, 0, 0);
        acc[0][1] = __builtin_amdgcn_mfma_f32_16x16x32_f16(a0, b1, acc[0][1], 0, 0, 0);
        acc[1][0] = __builtin_amdgcn_mfma_f32_16x16x32_f16(a1, b0, acc[1][0], 0, 0, 0);
        acc[1][1] = __builtin_amdgcn_mfma_f32_16x16x32_f16(a1, b1, acc[1][1], 0, 0, 0);
        __syncthreads();
    }
    #pragma unroll
    for (int i = 0; i < 2; i++)
        #pragma unroll
        for (int j = 0; j < 2; j++) {
            int col = n0 + wx * 32 + j * 16 + n_;
            float bv = bias ? bias[col] : 0.f;
            #pragma unroll
            for (int reg = 0; reg < 4; reg++) {
                int row = m0 + wy * 32 + i * 16 + quad * 4 + reg;
                if (row >= M) continue;
                float v = acc[i][j][reg] + bv;
                if (act == 1) v = v >= 0.f ? v : 0.01f * v;
                if (Cf) Cf[(size_t)row * N + col] = v;
                if (Ch) Ch[(size_t)row * N + col] = (f16)v;
            }
        }
}

// ---------------- fused MFMA GRU: X16 = relu(GRU(Hf, X16)) in place ----------------
// block 256 thr = 4 waves, 16 rows. Wave w owns gate-cols [w*48,(w+1)*48) of all 3 gates
// for BOTH gi (A=h) and gh (A=x): 18 MFMA tiles, gate triples land in-lane (C/D layout).
// Safe in-place: each block reads/writes only its own 16 rows of X16.
__global__ __launch_bounds__(256) void gru_mfma(const float* __restrict__ Hf,
                                                f16* __restrict__ X16,
                                                const f16* __restrict__ Wih,
                                                const f16* __restrict__ Whh,
                                                const float* __restrict__ bih,
                                                const float* __restrict__ bhh,
                                                int M)
{
    __shared__ __align__(16) f16 sH[16 * 40];
    __shared__ __align__(16) f16 sX[16 * 40];
    const int tid  = threadIdx.x;
    const int lane = tid & 63;
    const int w    = tid >> 6;
    const int n_ = lane & 15, quad = lane >> 4;
    const int node0 = blockIdx.x << 4;

    f32x4 aI[3][3] = {};
    f32x4 aH[3][3] = {};
    int boff[3][3];
    #pragma unroll
    for (int g = 0; g < 3; g++)
        #pragma unroll
        for (int t = 0; t < 3; t++)
            boff[g][t] = (g * 192 + w * 48 + t * 16 + n_) * 192 + quad * 8;

    const int sr  = (tid >> 2) & 15;
    const int skc = (tid & 3) << 3;

    #pragma unroll 1
    for (int k0 = 0; k0 < 192; k0 += 32) {
        if (tid < 64) {
            const float* p = Hf + (size_t)(node0 + sr) * 192 + k0 + skc;
            float4 f0 = *(const float4*)p;
            float4 f1 = *(const float4*)(p + 4);
            half8 h;
            h[0] = (f16)f0.x; h[1] = (f16)f0.y; h[2] = (f16)f0.z; h[3] = (f16)f0.w;
            h[4] = (f16)f1.x; h[5] = (f16)f1.y; h[6] = (f16)f1.z; h[7] = (f16)f1.w;
            *(half8*)(sH + sr * 40 + skc) = h;
        } else if (tid < 128) {
            *(half8*)(sX + sr * 40 + skc) =
                *(const half8*)(X16 + (size_t)(node0 + sr) * 192 + k0 + skc);
        }
        __syncthreads();
        half8 ah = *(const half8*)(sH + n_ * 40 + quad * 8);
        half8 ax = *(const half8*)(sX + n_ * 40 + quad * 8);
        #pragma unroll
        for (int g = 0; g < 3; g++)
            #pragma unroll
            for (int t = 0; t < 3; t++) {
                half8 bI = *(const half8*)(Wih + boff[g][t] + k0);
                half8 bH = *(const half8*)(Whh + boff[g][t] + k0);
                aI[g][t] = __builtin_amdgcn_mfma_f32_16x16x32_f16(ah, bI, aI[g][t], 0, 0, 0);
                aH[g][t] = __builtin_amdgcn_mfma_f32_16x16x32_f16(ax, bH, aH[g][t], 0, 0, 0);
            }
        __syncthreads();
    }
    // epilogue: gates in-lane, relu, fp16 in-place write
    #pragma unroll
    for (int t = 0; t < 3; t++) {
        int c0 = w * 48 + t * 16 + n_;
        float bir = bih[c0], biz = bih[c0 + 192], bin = bih[c0 + 384];
        float bhr = bhh[c0], bhz = bhh[c0 + 192], bhn = bhh[c0 + 384];
        #pragma unroll
        for (int reg = 0; reg < 4; reg++) {
            int node = node0 + quad * 4 + reg;
            if (node >= M) continue;
            float hx = (float)X16[(size_t)node * 192 + c0];
            float ir = aI[0][t][reg] + bir;
            float iz = aI[1][t][reg] + biz;
            float in = aI[2][t][reg] + bin;
            float hr = aH[0][t][reg] + bhr;
            float hz = aH[1][t][reg] + bhz;
            float hn = aH[2][t][reg] + bhn;
            float r  = 1.f / (1.f + expf(-(ir + hr)));
            float z  = 1.f / (1.f + expf(-(iz + hz)));
            float nn = tanhf(in + r * hn);
            float o  = (1.f - z) * nn + z * hx;
            X16[(size_t)node * 192 + c0] = (f16)(o > 0.f ? o : 0.f);
        }
    }
}

// ---------------- small vector compose: out[j] = sum_i v[i]*W[i*cols+j] ----------------
__global__ void compose_vec(const float* __restrict__ W, const float* __restrict__ v,
                            float* __restrict__ out, int rows, int cols)
{
    int j = threadIdx.x;
    if (j >= cols) return;
    float acc = 0.f;
    for (int i = 0; i < rows; i++) acc += v[i] * W[(size_t)i * cols + j];
    out[j] = acc;
}

// ---------------- edge_attr column sums (for mean fill) ----------------
__global__ void ea_sum_kernel(const float* __restrict__ ea, float* __restrict__ sums, int E)
{
    int lane = threadIdx.x & 63;
    float acc[16];
    #pragma unroll
    for (int f = 0; f < 16; f++) acc[f] = 0.f;
    for (int e = blockIdx.x * blockDim.x + threadIdx.x; e < E; e += gridDim.x * blockDim.x) {
        const float4* p = (const float4*)(ea + (size_t)e * 16);
        float4 v0 = p[0], v1 = p[1], v2 = p[2], v3 = p[3];
        acc[0] += v0.x; acc[1] += v0.y; acc[2] += v0.z; acc[3] += v0.w;
        acc[4] += v1.x; acc[5] += v1.y; acc[6] += v1.z; acc[7] += v1.w;
        acc[8] += v2.x; acc[9] += v2.y; acc[10] += v2.z; acc[11] += v2.w;
        acc[12] += v3.x; acc[13] += v3.y; acc[14] += v3.z; acc[15] += v3.w;
    }
    #pragma unroll
    for (int off = 32; off > 0; off >>= 1)
        #pragma unroll
        for (int f = 0; f < 16; f++) acc[f] += __shfl_down(acc[f], off);
    if (lane == 0)
        #pragma unroll
        for (int f = 0; f < 16; f++) atomicAdd(&sums[f], acc[f]);
}

__global__ void finalize_aloop(const float* __restrict__ sums, const float* __restrict__ ve,
                               float* __restrict__ aloop, float invE)
{
    if (threadIdx.x == 0) {
        float a = 0.f;
        for (int f = 0; f < 16; f++) a += sums[f] * invE * ve[f];
        *aloop = a;
    }
}

// ---------------- per-row dots (fp32 matrix) ----------------
__global__ void row_dots(const float* __restrict__ Mat, int M,
                         const float* __restrict__ v1, float* __restrict__ o1,
                         const float* __restrict__ v2, float* __restrict__ o2,
                         const float* __restrict__ bias)
{
    int row = blockIdx.x * 4 + (threadIdx.x >> 6);
    if (row >= M) return;
    int lane = threadIdx.x & 63;
    const float* rp = Mat + (size_t)row * 192;
    float a1 = 0.f, a2 = 0.f;
    #pragma unroll
    for (int k = 0; k < 3; k++) {
        int f = lane + 64 * k;
        float x = rp[f];
        a1 += x * v1[f];
        if (o2) a2 += x * v2[f];
    }
    #pragma unroll
    for (int off = 32; off > 0; off >>= 1) {
        a1 += __shfl_down(a1, off);
        a2 += __shfl_down(a2, off);
    }
    if (lane == 0) {
        o1[row] = a1 + (bias ? bias[0] : 0.f);
        if (o2) o2[row] = a2;
    }
}

// ---------------- per-row dots (fp16 matrix) ----------------
__global__ void row_dots_h(const f16* __restrict__ Mat, int M,
                           const float* __restrict__ v1, float* __restrict__ o1,
                           const float* __restrict__ bias)
{
    int row = blockIdx.x * 4 + (threadIdx.x >> 6);
    if (row >= M) return;
    int lane = threadIdx.x & 63;
    const f16* rp = Mat + (size_t)row * 192;
    float a1 = 0.f;
    #pragma unroll
    for (int k = 0; k < 3; k++) {
        int f = lane + 64 * k;
        a1 += (float)rp[f] * v1[f];
    }
    #pragma unroll
    for (int off = 32; off > 0; off >>= 1) a1 += __shfl_down(a1, off);
    if (lane == 0) o1[row] = a1 + (bias ? bias[0] : 0.f);
}

// ---------------- alpha + segment max ----------------
__global__ void edge_alpha_max(const int* __restrict__ srcp, const int* __restrict__ dstp,
                               int E_real, int Etot,
                               const float* __restrict__ as_, const float* __restrict__ ad_,
                               const float* __restrict__ ea, const float* __restrict__ ve,
                               const float* __restrict__ aloop, float slope,
                               float* __restrict__ ab, unsigned* __restrict__ mb)
{
    int i = blockIdx.x * blockDim.x + threadIdx.x;
    if (i >= Etot) return;
    int s_, d_;
    float aext = 0.f;
    if (i < E_real) {
        s_ = srcp ? srcp[i] : i;
        d_ = dstp[i];
        if (ea) {
            const float4* p = (const float4*)(ea + (size_t)i * 16);
            const float4* q = (const float4*)ve;
            float4 e0 = p[0], e1 = p[1], e2 = p[2], e3 = p[3];
            float4 w0 = q[0], w1 = q[1], w2 = q[2], w3 = q[3];
            aext = e0.x * w0.x + e0.y * w0.y + e0.z * w0.z + e0.w * w0.w
                 + e1.x * w1.x + e1.y * w1.y + e1.z * w1.z + e1.w * w1.w
                 + e2.x * w2.x + e2.y * w2.y + e2.z * w2.z + e2.w * w2.w
                 + e3.x * w3.x + e3.y * w3.y + e3.z * w3.z + e3.w * w3.w;
        }
    } else {
        s_ = d_ = i - E_real;
        aext = *aloop;
    }
    float a = as_[s_] + ad_[d_] + aext;
    a = a >= 0.f ? a : slope * a;
    ab[i] = a;
    atomicMax(&mb[d_], fmap(a));
}

// ---------------- exp(alpha - max) + segment sum ----------------
__global__ void edge_exp_sum(const int* __restrict__ dstp, int E_real, int Etot,
                             float* __restrict__ ab, const unsigned* __restrict__ mb,
                             float* __restrict__ sb)
{
    int i = blockIdx.x * blockDim.x + threadIdx.x;
    if (i >= Etot) return;
    int d_ = (i < E_real) ? dstp[i] : i - E_real;
    float m = funmap(mb[d_]);
    float e = expf(ab[i] - m);
    ab[i] = e;
    atomicAdd(&sb[d_], e);
}

// ---------------- aggregate: out[dst] += (e/(s+eps)) * F[src] ---- wave per edge ----------------
__global__ void edge_aggregate(const int* __restrict__ srcp, const int* __restrict__ dstp,
                               int E_real, int Etot,
                               const float* __restrict__ ab, const float* __restrict__ sb,
                               const float* __restrict__ F, float* __restrict__ out)
{
    int e = blockIdx.x * 4 + (threadIdx.x >> 6);
    if (e >= Etot) return;
    int lane = threadIdx.x & 63;
    int s_, d_;
    if (e < E_real) { s_ = srcp ? srcp[e] : e; d_ = dstp[e]; }
    else            { s_ = d_ = e - E_real; }
    float w = ab[e] / (sb[d_] + 1e-16f);
    const float* fr = F + (size_t)s_ * 192;
    float* orow = out + (size_t)d_ * 192;
    atomicAdd(&orow[lane],       w * fr[lane]);
    atomicAdd(&orow[lane + 64],  w * fr[lane + 64]);
    atomicAdd(&orow[lane + 128], w * fr[lane + 128]);
}

// ---------------- h = elu(h + b[f]) in place (fp32) ----------------
__global__ void bias_elu_kernel(float* __restrict__ h, const float* __restrict__ b, int total)
{
    int i = blockIdx.x * blockDim.x + threadIdx.x;
    if (i >= total) return;
    int f = i % 192;
    float v = h[i] + b[f];
    h[i] = v > 0.f ? v : expm1f(v);
}

// ---------------- global add pool from fp16 x ----------------
__global__ void pool_kernel(const f16* __restrict__ X, const int* __restrict__ batch,
                            float* __restrict__ outg, int n_nodes)
{
    int idx = blockIdx.x * blockDim.x + threadIdx.x;
    if (idx >= n_nodes * 192) return;
    int n = idx / 192, f = idx % 192;
    atomicAdd(&outg[(size_t)batch[n] * 192 + f], (float)X[idx]);
}

// ---------------- relu + fp32->fp16 ----------------
__global__ void relu_cvt_kernel(const float* __restrict__ p, f16* __restrict__ d, int total)
{
    int i = blockIdx.x * blockDim.x + threadIdx.x;
    if (i >= total) return;
    float v = p[i];
    d[i] = (f16)(v > 0.f ? v : 0.f);
}

// ---------------- launch ----------------
extern "C" void kernel_launch(void* const* d_in, const int* in_sizes, int n_in,
                              void* d_out, int out_size, void* d_ws, size_t ws_size,
                              hipStream_t stream)
{
    const float* x_in        = (const float*)d_in[0];
    const int*   ei          = (const int*)  d_in[1];
    const float* eattr       = (const float*)d_in[2];
    const int*   batch       = (const int*)  d_in[3];
    const float* lin1_W      = (const float*)d_in[4];
    const float* lin1_b      = (const float*)d_in[5];
    const float* conv0_W     = (const float*)d_in[6];
    const float* conv0_att_s = (const float*)d_in[7];
    const float* conv0_att_d = (const float*)d_in[8];
    const float* conv0_We    = (const float*)d_in[9];
    const float* conv0_att_e = (const float*)d_in[10];
    const float* conv0_b     = (const float*)d_in[11];
    const float* convs_W     = (const float*)d_in[12];
    const float* convs_att_s = (const float*)d_in[13];
    const float* convs_att_d = (const float*)d_in[14];
    const float* convs_b     = (const float*)d_in[15];
    const float* gru_Wih     = (const float*)d_in[16];
    const float* gru_Whh     = (const float*)d_in[17];
    const float* gru_bih     = (const float*)d_in[18];
    const float* gru_bhh     = (const float*)d_in[19];
    const float* mol_Wsrc    = (const float*)d_in[20];
    const float* mol_Wdst    = (const float*)d_in[21];
    const float* mol_att_s   = (const float*)d_in[22];
    const float* mol_att_d   = (const float*)d_in[23];
    const float* mol_b       = (const float*)d_in[24];
    const float* mgru_Wih    = (const float*)d_in[25];
    const float* mgru_Whh    = (const float*)d_in[26];
    const float* mgru_bih    = (const float*)d_in[27];
    const float* mgru_bhh    = (const float*)d_in[28];
    const float* lin2_W      = (const float*)d_in[29];
    const float* lin2_b      = (const float*)d_in[30];

    const int* src = ei;
    const int* dst = ei + EE;

    // ---- workspace layout (byte allocator, 64B aligned) ----
    char* base = (char*)d_ws;
    size_t off = 0;
    auto alloc = [&](size_t bytes) -> void* {
        void* p = base + off;
        off = (off + bytes + 63) & ~(size_t)63;
        return p;
    };
    float*    wbuf   = (float*)alloc((size_t)NN * HH * 4);
    float*    hbuf   = (float*)alloc((size_t)NN * HH * 4);
    float*    abuf   = (float*)alloc((size_t)(EE + NN) * 4);
    float*    asb    = (float*)alloc((size_t)NN * 4);
    float*    adb    = (float*)alloc((size_t)NN * 4);
    float*    sb     = (float*)alloc((size_t)NN * 4);
    unsigned* mb     = (unsigned*)alloc((size_t)NN * 4);
    float*    outgp  = (float*)alloc((size_t)GG * HH * 4);
    float*    hg     = (float*)alloc((size_t)GG * HH * 4);
    float*    adg    = (float*)alloc((size_t)GG * 4);
    float*    sg     = (float*)alloc((size_t)GG * 4);
    unsigned* mg     = (unsigned*)alloc((size_t)GG * 4);
    float*    ve     = (float*)alloc(64);
    float*    easum  = (float*)alloc(64);
    float*    vd     = (float*)alloc(HH * 4);
    float*    aloop  = (float*)alloc(64);
    f16*      x16    = (f16*)alloc((size_t)NN * HH * 2);
    f16*      xin16  = (f16*)alloc((size_t)NN * CIN * 2);
    f16*      outg16 = (f16*)alloc((size_t)GG * HH * 2);
    f16*      lin1W16  = (f16*)alloc((size_t)HH * CIN * 2);
    f16*      conv0W16 = (f16*)alloc((size_t)HH * HH * 2);
    f16*      convsW16 = (f16*)alloc((size_t)2 * HH * HH * 2);
    f16*      gruWih16 = (f16*)alloc((size_t)3 * H3 * HH * 2);
    f16*      gruWhh16 = (f16*)alloc((size_t)3 * H3 * HH * 2);
    f16*      molWs16  = (f16*)alloc((size_t)HH * HH * 2);
    f16*      mgruWih16 = (f16*)alloc((size_t)H3 * HH * 2);
    f16*      mgruWhh16 = (f16*)alloc((size_t)H3 * HH * 2);
    if (off > ws_size) return;   // insufficient scratch -> visible failure (zero out)

    // ---- weight + input converts ----
    cvt_f2h<<<(NN * CIN + 255) / 256, 256, 0, stream>>>(x_in, xin16, NN * CIN);
    Cvt8 cv;
    cv.s[0] = lin1_W;   cv.d[0] = lin1W16;   cv.n[0] = HH * CIN;
    cv.s[1] = conv0_W;  cv.d[1] = conv0W16;  cv.n[1] = HH * HH;
    cv.s[2] = convs_W;  cv.d[2] = convsW16;  cv.n[2] = 2 * HH * HH;
    cv.s[3] = gru_Wih;  cv.d[3] = gruWih16;  cv.n[3] = 3 * H3 * HH;
    cv.s[4] = gru_Whh;  cv.d[4] = gruWhh16;  cv.n[4] = 3 * H3 * HH;
    cv.s[5] = mol_Wsrc; cv.d[5] = molWs16;   cv.n[5] = HH * HH;
    cv.s[6] = mgru_Wih; cv.d[6] = mgruWih16; cv.n[6] = H3 * HH;
    cv.s[7] = mgru_Whh; cv.d[7] = mgruWhh16; cv.n[7] = H3 * HH;
    cvt_multi<<<dim3((3 * H3 * HH + 255) / 256, 8), 256, 0, stream>>>(cv);

    const int gMx = (NN + 63) / 64;   // 782
    const dim3 gemmGrid(gMx, HH / 64);

    // ---- lin1: x16 = lrelu(x_in @ lin1_W^T + b) ----
    gemm_mfma<<<gemmGrid, 256, 0, stream>>>(xin16, lin1W16, lin1_b, nullptr, x16,
                                            NN, HH, CIN, 1);

    // ---- conv0 prep ----
    compose_vec<<<1, 256, 0, stream>>>(conv0_We, conv0_att_e, ve, HH, EDIM);
    hipMemsetAsync(easum, 0, 16 * sizeof(float), stream);
    ea_sum_kernel<<<256, 256, 0, stream>>>(eattr, easum, EE);
    finalize_aloop<<<1, 64, 0, stream>>>(easum, ve, aloop, 1.0f / EE);

    // ---- conv0 (edge feats + self loops, slope 0.2) ----
    gemm_mfma<<<gemmGrid, 256, 0, stream>>>(x16, conv0W16, nullptr, wbuf, nullptr,
                                            NN, HH, HH, 0);
    row_dots<<<(NN + 3) / 4, 256, 0, stream>>>(wbuf, NN, conv0_att_s, asb, conv0_att_d, adb, nullptr);
    hipMemsetAsync(mb, 0, NN * sizeof(unsigned), stream);
    edge_alpha_max<<<(EE + NN + 255) / 256, 256, 0, stream>>>(src, dst, EE, EE + NN, asb, adb,
                                                              eattr, ve, aloop, 0.2f, abuf, mb);
    hipMemsetAsync(sb, 0, NN * sizeof(float), stream);
    edge_exp_sum<<<(EE + NN + 255) / 256, 256, 0, stream>>>(dst, EE, EE + NN, abuf, mb, sb);
    hipMemsetAsync(hbuf, 0, (size_t)NN * HH * sizeof(float), stream);
    edge_aggregate<<<(EE + NN + 3) / 4, 256, 0, stream>>>(src, dst, EE, EE + NN, abuf, sb, wbuf, hbuf);
    bias_elu_kernel<<<(NN * HH + 255) / 256, 256, 0, stream>>>(hbuf, conv0_b, NN * HH);
    gru_mfma<<<NN / 16, 256, 0, stream>>>(hbuf, x16, gruWih16, gruWhh16, gru_bih, gru_bhh, NN);

    // ---- remaining atom convs (no self loops, slope 0.01) ----
    for (int l = 0; l < 2; l++) {
        gemm_mfma<<<gemmGrid, 256, 0, stream>>>(x16, convsW16 + (size_t)l * HH * HH,
                                                nullptr, wbuf, nullptr, NN, HH, HH, 0);
        row_dots<<<(NN + 3) / 4, 256, 0, stream>>>(wbuf, NN, convs_att_s + l * HH, asb,
                                                   convs_att_d + l * HH, adb, nullptr);
        hipMemsetAsync(mb, 0, NN * sizeof(unsigned), stream);
        edge_alpha_max<<<(EE + 255) / 256, 256, 0, stream>>>(src, dst, EE, EE, asb, adb,
                                                             nullptr, nullptr, nullptr, 0.01f, abuf, mb);
        hipMemsetAsync(sb, 0, NN * sizeof(float), stream);
        edge_exp_sum<<<(EE + 255) / 256, 256, 0, stream>>>(dst, EE, EE, abuf, mb, sb);
        hipMemsetAsync(hbuf, 0, (size_t)NN * HH * sizeof(float), stream);
        edge_aggregate<<<(EE + 3) / 4, 256, 0, stream>>>(src, dst, EE, EE, abuf, sb, wbuf, hbuf);
        bias_elu_kernel<<<(NN * HH + 255) / 256, 256, 0, stream>>>(hbuf, convs_b + l * HH, NN * HH);
        gru_mfma<<<NN / 16, 256, 0, stream>>>(hbuf, x16,
                                              gruWih16 + (size_t)(l + 1) * H3 * HH,
                                              gruWhh16 + (size_t)(l + 1) * H3 * HH,
                                              gru_bih + (size_t)(l + 1) * H3,
                                              gru_bhh + (size_t)(l + 1) * H3, NN);
    }

    // ---- molecule readout ----
    hipMemsetAsync(outgp, 0, (size_t)GG * HH * sizeof(float), stream);
    pool_kernel<<<(NN * HH + 255) / 256, 256, 0, stream>>>(x16, batch, outgp, NN);
    relu_cvt_kernel<<<(GG * HH + 255) / 256, 256, 0, stream>>>(outgp, outg16, GG * HH);
    gemm_mfma<<<gemmGrid, 256, 0, stream>>>(x16, molWs16, nullptr, wbuf, nullptr, NN, HH, HH, 0);
    row_dots<<<(NN + 3) / 4, 256, 0, stream>>>(wbuf, NN, mol_att_s, asb, nullptr, nullptr, nullptr);
    compose_vec<<<1, 256, 0, stream>>>(mol_Wdst, mol_att_d, vd, HH, HH);

    for (int t = 0; t < 2; t++) {
        row_dots_h<<<(GG + 3) / 4, 256, 0, stream>>>(outg16, GG, vd, adg, nullptr);
        hipMemsetAsync(mg, 0, GG * sizeof(unsigned), stream);
        edge_alpha_max<<<(NN + 255) / 256, 256, 0, stream>>>(nullptr, batch, NN, NN, asb, adg,
                                                             nullptr, nullptr, nullptr, 0.01f, abuf, mg);
        hipMemsetAsync(sg, 0, GG * sizeof(float), stream);
        edge_exp_sum<<<(NN + 255) / 256, 256, 0, stream>>>(batch, NN, NN, abuf, mg, sg);
        hipMemsetAsync(hg, 0, (size_t)GG * HH * sizeof(float), stream);
        edge_aggregate<<<(NN + 3) / 4, 256, 0, stream>>>(nullptr, batch, NN, NN, abuf, sg, wbuf, hg);
        bias_elu_kernel<<<(GG * HH + 255) / 256, 256, 0, stream>>>(hg, mol_b, GG * HH);
        gru_mfma<<<GG / 16, 256, 0, stream>>>(hg, outg16, mgruWih16, mgruWhh16,
                                              mgru_bih, mgru_bhh, GG);
    }

    // ---- final linear ----
    row_dots_h<<<(GG + 3) / 4, 256, 0, stream>>>(outg16, GG, lin2_W, (float*)d_out, lin2_b);
}

// Round 5
// 2380.769 us; speedup vs baseline: 2.7455x; 1.3665x over previous
//
#include <hip/hip_runtime.h>
#include <math.h>

// ---------------- problem constants ----------------
#define NN    50000
#define EE    800000
#define CIN   64
#define HH    192
#define EDIM  16
#define GG    2048
#define H3    576   // 3*H

typedef _Float16 f16;
typedef _Float16 half8 __attribute__((ext_vector_type(8)));
typedef float f32x4 __attribute__((ext_vector_type(4)));

// ---------------- helpers ----------------
__device__ __forceinline__ unsigned fmap(float f) {
    unsigned u = __float_as_uint(f);
    return (u & 0x80000000u) ? ~u : (u | 0x80000000u);
}
__device__ __forceinline__ float funmap(unsigned u) {
    if (u == 0u) return 0.0f;
    return (u & 0x80000000u) ? __uint_as_float(u ^ 0x80000000u)
                             : __uint_as_float(~u);
}

// ---------------- fp32 -> fp16 converts ----------------
__global__ void cvt_f2h(const float* __restrict__ s, f16* __restrict__ d, int n)
{
    int i = blockIdx.x * blockDim.x + threadIdx.x;
    if (i < n) d[i] = (f16)s[i];
}

struct Cvt8 { const float* s[8]; f16* d[8]; int n[8]; };
__global__ void cvt_multi(Cvt8 c)
{
    int slot = blockIdx.y;
    int i = blockIdx.x * blockDim.x + threadIdx.x;
    if (i < c.n[slot]) c.d[slot][i] = (f16)c.s[slot][i];
}

// ---------------- CSR build ----------------
__global__ void hist_kernel(const int* __restrict__ idx, int* __restrict__ deg, int n, int nbins)
{
    int i = blockIdx.x * blockDim.x + threadIdx.x;
    if (i < n) {
        unsigned b = (unsigned)idx[i];
        if (b < (unsigned)nbins) atomicAdd(&deg[b], 1);
    }
}

// single-WAVE exclusive scan: 64 threads, shfl-based, no LDS, no barriers.
__global__ void scan_wave(const int* __restrict__ deg, int* __restrict__ rowptr,
                          unsigned* __restrict__ cursor, int n)
{
    int lane = threadIdx.x & 63;
    int carry = 0;
    for (int base = 0; base < n; base += 64) {
        int i = base + lane;
        int v = (i < n) ? deg[i] : 0;
        int x = v;
        #pragma unroll
        for (int off = 1; off < 64; off <<= 1) {
            int t = __shfl_up(x, off);
            if (lane >= off) x += t;
        }
        int ex = carry + x - v;
        if (i < n) {
            rowptr[i] = ex;
            if (cursor) cursor[i] = (unsigned)ex;
        }
        carry += __shfl(x, 63);
    }
    if (lane == 0) rowptr[n] = carry;
}

__global__ void scatter_kernel(const int* __restrict__ src, const int* __restrict__ dst,
                               unsigned* __restrict__ cursor,
                               int* __restrict__ csr_src, int* __restrict__ csr_eid, int E)
{
    int e = blockIdx.x * blockDim.x + threadIdx.x;
    if (e >= E) return;
    unsigned d = (unsigned)dst[e];
    if (d >= (unsigned)NN) return;
    unsigned p = atomicAdd(&cursor[d], 1u);
    if (p < (unsigned)E) {
        csr_src[p] = src[e];
        csr_eid[p] = e;
    }
}

// ---------------- MFMA GEMM: C[M,N] = act(A16[M,K] @ W16[N,K]^T + bias) ----------------
__global__ __launch_bounds__(256) void gemm_mfma(const f16* __restrict__ A,
                                                 const f16* __restrict__ W,
                                                 const float* __restrict__ bias,
                                                 float* __restrict__ Cf,
                                                 f16* __restrict__ Ch,
                                                 int M, int N, int K, int act)
{
    __shared__ __align__(16) f16 sA[64 * 40];
    const int tid  = threadIdx.x;
    const int lane = tid & 63;
    const int wid  = tid >> 6;
    const int wy = wid >> 1, wx = wid & 1;
    const int m0 = blockIdx.x << 6, n0 = blockIdx.y << 6;
    const int n_ = lane & 15, quad = lane >> 4;

    f32x4 acc[2][2] = {};
    int boff0 = (n0 + wx * 32 + n_) * K + quad * 8;
    int boff1 = boff0 + 16 * K;

    const int srow = tid >> 2;
    const int skc  = (tid & 3) << 3;

    for (int k0 = 0; k0 < K; k0 += 32) {
        half8 av = {};
        int gm = m0 + srow;
        if (gm < M) av = *(const half8*)(A + (size_t)gm * K + k0 + skc);
        *(half8*)(sA + srow * 40 + skc) = av;
        __syncthreads();
        half8 a0 = *(const half8*)(sA + (wy * 32 + n_) * 40 + quad * 8);
        half8 a1 = *(const half8*)(sA + (wy * 32 + 16 + n_) * 40 + quad * 8);
        half8 b0 = *(const half8*)(W + boff0 + k0);
        half8 b1 = *(const half8*)(W + boff1 + k0);
        acc[0][0] = __builtin_amdgcn_mfma_f32_16x16x32_f16(a0, b0, acc[0][0], 0, 0, 0);
        acc[0][1] = __builtin_amdgcn_mfma_f32_16x16x32_f16(a0, b1, acc[0][1], 0, 0, 0);
        acc[1][0] = __builtin_amdgcn_mfma_f32_16x16x32_f16(a1, b0, acc[1][0], 0, 0, 0);
        acc[1][1] = __builtin_amdgcn_mfma_f32_16x16x32_f16(a1, b1, acc[1][1], 0, 0, 0);
        __syncthreads();
    }
    #pragma unroll
    for (int i = 0; i < 2; i++)
        #pragma unroll
        for (int j = 0; j < 2; j++) {
            int col = n0 + wx * 32 + j * 16 + n_;
            float bv = bias ? bias[col] : 0.f;
            #pragma unroll
            for (int reg = 0; reg < 4; reg++) {
                int row = m0 + wy * 32 + i * 16 + quad * 4 + reg;
                if (row >= M) continue;
                float v = acc[i][j][reg] + bv;
                if (act == 1) v = v >= 0.f ? v : 0.01f * v;
                if (Cf) Cf[(size_t)row * N + col] = v;
                if (Ch) Ch[(size_t)row * N + col] = (f16)v;
            }
        }
}

// ---------------- fused MFMA GRU (round-2 exact): X16 = relu(GRU(Hf, X16)) in place ----------------
__global__ __launch_bounds__(256) void gru_mfma(const float* __restrict__ Hf,
                                                f16* __restrict__ X16,
                                                const f16* __restrict__ Wih,
                                                const f16* __restrict__ Whh,
                                                const float* __restrict__ bih,
                                                const float* __restrict__ bhh,
                                                int M)
{
    __shared__ __align__(16) f16 sH[16 * 40];
    __shared__ __align__(16) f16 sX[16 * 40];
    const int tid  = threadIdx.x;
    const int lane = tid & 63;
    const int w    = tid >> 6;
    const int n_ = lane & 15, quad = lane >> 4;
    const int node0 = blockIdx.x << 4;

    f32x4 aI[3][3] = {};
    f32x4 aH[3][3] = {};
    int boff[3][3];
    #pragma unroll
    for (int g = 0; g < 3; g++)
        #pragma unroll
        for (int t = 0; t < 3; t++)
            boff[g][t] = (g * 192 + w * 48 + t * 16 + n_) * 192 + quad * 8;

    const int sr  = (tid >> 2) & 15;
    const int skc = (tid & 3) << 3;

    #pragma unroll 1
    for (int k0 = 0; k0 < 192; k0 += 32) {
        if (tid < 64) {
            const float* p = Hf + (size_t)(node0 + sr) * 192 + k0 + skc;
            if (node0 + sr < M) {
                float4 f0 = *(const float4*)p;
                float4 f1 = *(const float4*)(p + 4);
                half8 h;
                h[0] = (f16)f0.x; h[1] = (f16)f0.y; h[2] = (f16)f0.z; h[3] = (f16)f0.w;
                h[4] = (f16)f1.x; h[5] = (f16)f1.y; h[6] = (f16)f1.z; h[7] = (f16)f1.w;
                *(half8*)(sH + sr * 40 + skc) = h;
            } else {
                half8 h = {};
                *(half8*)(sH + sr * 40 + skc) = h;
            }
        } else if (tid < 128) {
            half8 v = {};
            if (node0 + sr < M)
                v = *(const half8*)(X16 + (size_t)(node0 + sr) * 192 + k0 + skc);
            *(half8*)(sX + sr * 40 + skc) = v;
        }
        __syncthreads();
        half8 ah = *(const half8*)(sH + n_ * 40 + quad * 8);
        half8 ax = *(const half8*)(sX + n_ * 40 + quad * 8);
        #pragma unroll
        for (int g = 0; g < 3; g++)
            #pragma unroll
            for (int t = 0; t < 3; t++) {
                half8 bI = *(const half8*)(Wih + boff[g][t] + k0);
                half8 bH = *(const half8*)(Whh + boff[g][t] + k0);
                aI[g][t] = __builtin_amdgcn_mfma_f32_16x16x32_f16(ah, bI, aI[g][t], 0, 0, 0);
                aH[g][t] = __builtin_amdgcn_mfma_f32_16x16x32_f16(ax, bH, aH[g][t], 0, 0, 0);
            }
        __syncthreads();
    }
    #pragma unroll
    for (int t = 0; t < 3; t++) {
        int c0 = w * 48 + t * 16 + n_;
        float bir = bih[c0], biz = bih[c0 + 192], bin = bih[c0 + 384];
        float bhr = bhh[c0], bhz = bhh[c0 + 192], bhn = bhh[c0 + 384];
        #pragma unroll
        for (int reg = 0; reg < 4; reg++) {
            int node = node0 + quad * 4 + reg;
            if (node >= M) continue;
            float hx = (float)X16[(size_t)node * 192 + c0];
            float ir = aI[0][t][reg] + bir;
            float iz = aI[1][t][reg] + biz;
            float in = aI[2][t][reg] + bin;
            float hr = aH[0][t][reg] + bhr;
            float hz = aH[1][t][reg] + bhz;
            float hn = aH[2][t][reg] + bhn;
            float r  = 1.f / (1.f + expf(-(ir + hr)));
            float z  = 1.f / (1.f + expf(-(iz + hz)));
            float nn = tanhf(in + r * hn);
            float o  = (1.f - z) * nn + z * hx;
            X16[(size_t)node * 192 + c0] = (f16)(o > 0.f ? o : 0.f);
        }
    }
}

// ---------------- small vector compose ----------------
__global__ void compose_vec(const float* __restrict__ W, const float* __restrict__ v,
                            float* __restrict__ out, int rows, int cols)
{
    int j = threadIdx.x;
    if (j >= cols) return;
    float acc = 0.f;
    for (int i = 0; i < rows; i++) acc += v[i] * W[(size_t)i * cols + j];
    out[j] = acc;
}

// ---------------- edge_attr column sums ----------------
__global__ void ea_sum_kernel(const float* __restrict__ ea, float* __restrict__ sums, int E)
{
    int lane = threadIdx.x & 63;
    float acc[16];
    #pragma unroll
    for (int f = 0; f < 16; f++) acc[f] = 0.f;
    for (int e = blockIdx.x * blockDim.x + threadIdx.x; e < E; e += gridDim.x * blockDim.x) {
        const float4* p = (const float4*)(ea + (size_t)e * 16);
        float4 v0 = p[0], v1 = p[1], v2 = p[2], v3 = p[3];
        acc[0] += v0.x; acc[1] += v0.y; acc[2] += v0.z; acc[3] += v0.w;
        acc[4] += v1.x; acc[5] += v1.y; acc[6] += v1.z; acc[7] += v1.w;
        acc[8] += v2.x; acc[9] += v2.y; acc[10] += v2.z; acc[11] += v2.w;
        acc[12] += v3.x; acc[13] += v3.y; acc[14] += v3.z; acc[15] += v3.w;
    }
    #pragma unroll
    for (int off = 32; off > 0; off >>= 1)
        #pragma unroll
        for (int f = 0; f < 16; f++) acc[f] += __shfl_down(acc[f], off);
    if (lane == 0)
        #pragma unroll
        for (int f = 0; f < 16; f++) atomicAdd(&sums[f], acc[f]);
}

__global__ void finalize_aloop(const float* __restrict__ sums, const float* __restrict__ ve,
                               float* __restrict__ aloop, float invE)
{
    if (threadIdx.x == 0) {
        float a = 0.f;
        for (int f = 0; f < 16; f++) a += sums[f] * invE * ve[f];
        *aloop = a;
    }
}

// ---------------- per-row dots on fp16 matrix (1-2 vectors) ----------------
__global__ void row_dots_h(const f16* __restrict__ Mat, int M,
                           const float* __restrict__ v1, float* __restrict__ o1,
                           const float* __restrict__ v2, float* __restrict__ o2,
                           const float* __restrict__ bias)
{
    int row = blockIdx.x * 4 + (threadIdx.x >> 6);
    if (row >= M) return;
    int lane = threadIdx.x & 63;
    const f16* rp = Mat + (size_t)row * 192;
    float a1 = 0.f, a2 = 0.f;
    #pragma unroll
    for (int k = 0; k < 3; k++) {
        int f = lane + 64 * k;
        float x = (float)rp[f];
        a1 += x * v1[f];
        if (o2) a2 += x * v2[f];
    }
    #pragma unroll
    for (int off = 32; off > 0; off >>= 1) {
        a1 += __shfl_down(a1, off);
        a2 += __shfl_down(a2, off);
    }
    if (lane == 0) {
        o1[row] = a1 + (bias ? bias[0] : 0.f);
        if (o2) o2[row] = a2;
    }
}

// ---------------- alpha + segment max (round-2 exact) ----------------
__global__ void edge_alpha_max(const int* __restrict__ srcp, const int* __restrict__ dstp,
                               int E_real, int Etot,
                               const float* __restrict__ as_, const float* __restrict__ ad_,
                               const float* __restrict__ ea, const float* __restrict__ ve,
                               const float* __restrict__ aloop, float slope,
                               float* __restrict__ ab, unsigned* __restrict__ mb)
{
    int i = blockIdx.x * blockDim.x + threadIdx.x;
    if (i >= Etot) return;
    int s_, d_;
    float aext = 0.f;
    if (i < E_real) {
        s_ = srcp ? srcp[i] : i;
        d_ = dstp[i];
        if (ea) {
            const float4* p = (const float4*)(ea + (size_t)i * 16);
            const float4* q = (const float4*)ve;
            float4 e0 = p[0], e1 = p[1], e2 = p[2], e3 = p[3];
            float4 w0 = q[0], w1 = q[1], w2 = q[2], w3 = q[3];
            aext = e0.x * w0.x + e0.y * w0.y + e0.z * w0.z + e0.w * w0.w
                 + e1.x * w1.x + e1.y * w1.y + e1.z * w1.z + e1.w * w1.w
                 + e2.x * w2.x + e2.y * w2.y + e2.z * w2.z + e2.w * w2.w
                 + e3.x * w3.x + e3.y * w3.y + e3.z * w3.z + e3.w * w3.w;
        }
    } else {
        s_ = d_ = i - E_real;
        aext = *aloop;
    }
    float a = as_[s_] + ad_[d_] + aext;
    a = a >= 0.f ? a : slope * a;
    ab[i] = a;
    atomicMax(&mb[d_], fmap(a));
}

// ---------------- exp(alpha - max) + segment sum (round-2 exact) ----------------
__global__ void edge_exp_sum(const int* __restrict__ dstp, int E_real, int Etot,
                             float* __restrict__ ab, const unsigned* __restrict__ mb,
                             float* __restrict__ sb)
{
    int i = blockIdx.x * blockDim.x + threadIdx.x;
    if (i >= Etot) return;
    int d_ = (i < E_real) ? dstp[i] : i - E_real;
    float m = funmap(mb[d_]);
    float e = expf(ab[i] - m);
    ab[i] = e;
    atomicAdd(&sb[d_], e);
}

// ---------------- CSR aggregate: Hout[dst] = elu(sum_e w_e*F[src_e]/sum + bias), fp32 out ----------------
// csr_src==null -> src = csr position; csr_eid==null -> eid = csr position.
// selfloop: add edge (src=node, eid=selfAb+node).
__global__ __launch_bounds__(256) void csr_aggregate(const int* __restrict__ rowptr,
                                                     const int* __restrict__ csr_src,
                                                     const int* __restrict__ csr_eid,
                                                     int Ndst, int nF, int nAb,
                                                     int selfloop, int selfAb,
                                                     const float* __restrict__ ab,
                                                     const float* __restrict__ sb,
                                                     const f16* __restrict__ F,
                                                     const float* __restrict__ bias,
                                                     float* __restrict__ Hout)
{
    int node = blockIdx.x * 4 + (threadIdx.x >> 6);
    if (node >= Ndst) return;
    int lane = threadIdx.x & 63;
    int start = rowptr[node];
    int deg = rowptr[node + 1] - start;
    deg = min(max(deg, 0), 1 << 20);
    float inv = 1.f / (sb[node] + 1e-16f);

    float acc0 = 0.f, acc1 = 0.f, acc2 = 0.f;
    for (int base = 0; base < deg; base += 64) {
        int i = base + lane;
        float wv = 0.f;
        int s = 0;
        if (i < deg) {
            int pos = start + i;
            s = csr_src ? csr_src[pos] : pos;
            if ((unsigned)s >= (unsigned)nF) s = 0;
            unsigned eid = csr_eid ? (unsigned)csr_eid[pos] : (unsigned)pos;
            if (eid >= (unsigned)nAb) eid = 0;
            wv = ab[eid];
        }
        int cnt = min(64, deg - base);
        for (int j = 0; j < cnt; j++) {
            float wj = __shfl(wv, j);
            int   sj = __shfl(s, j);
            const f16* fr = F + (size_t)sj * 192;
            acc0 += wj * (float)fr[lane];
            acc1 += wj * (float)fr[lane + 64];
            acc2 += wj * (float)fr[lane + 128];
        }
    }
    if (selfloop) {
        unsigned eid = (unsigned)(selfAb + node);
        float wv = (eid < (unsigned)nAb) ? ab[eid] : 0.f;
        int s = min(node, nF - 1);
        const f16* fr = F + (size_t)s * 192;
        acc0 += wv * (float)fr[lane];
        acc1 += wv * (float)fr[lane + 64];
        acc2 += wv * (float)fr[lane + 128];
    }
    float h0 = acc0 * inv + bias[lane];
    float h1 = acc1 * inv + bias[lane + 64];
    float h2 = acc2 * inv + bias[lane + 128];
    float* orow = Hout + (size_t)node * 192;
    orow[lane]       = h0 > 0.f ? h0 : expm1f(h0);
    orow[lane + 64]  = h1 > 0.f ? h1 : expm1f(h1);
    orow[lane + 128] = h2 > 0.f ? h2 : expm1f(h2);
}

// ---------------- global add pool from fp16 x (round-2 exact) ----------------
__global__ void pool_kernel(const f16* __restrict__ X, const int* __restrict__ batch,
                            float* __restrict__ outg, int n_nodes)
{
    int idx = blockIdx.x * blockDim.x + threadIdx.x;
    if (idx >= n_nodes * 192) return;
    int n = idx / 192, f = idx % 192;
    atomicAdd(&outg[(size_t)batch[n] * 192 + f], (float)X[idx]);
}

// ---------------- relu + fp32->fp16 ----------------
__global__ void relu_cvt_kernel(const float* __restrict__ p, f16* __restrict__ d, int total)
{
    int i = blockIdx.x * blockDim.x + threadIdx.x;
    if (i >= total) return;
    float v = p[i];
    d[i] = (f16)(v > 0.f ? v : 0.f);
}

// ---------------- launch ----------------
extern "C" void kernel_launch(void* const* d_in, const int* in_sizes, int n_in,
                              void* d_out, int out_size, void* d_ws, size_t ws_size,
                              hipStream_t stream)
{
    const float* x_in        = (const float*)d_in[0];
    const int*   ei          = (const int*)  d_in[1];
    const float* eattr       = (const float*)d_in[2];
    const int*   batch       = (const int*)  d_in[3];
    const float* lin1_W      = (const float*)d_in[4];
    const float* lin1_b      = (const float*)d_in[5];
    const float* conv0_W     = (const float*)d_in[6];
    const float* conv0_att_s = (const float*)d_in[7];
    const float* conv0_att_d = (const float*)d_in[8];
    const float* conv0_We    = (const float*)d_in[9];
    const float* conv0_att_e = (const float*)d_in[10];
    const float* conv0_b     = (const float*)d_in[11];
    const float* convs_W     = (const float*)d_in[12];
    const float* convs_att_s = (const float*)d_in[13];
    const float* convs_att_d = (const float*)d_in[14];
    const float* convs_b     = (const float*)d_in[15];
    const float* gru_Wih     = (const float*)d_in[16];
    const float* gru_Whh     = (const float*)d_in[17];
    const float* gru_bih     = (const float*)d_in[18];
    const float* gru_bhh     = (const float*)d_in[19];
    const float* mol_Wsrc    = (const float*)d_in[20];
    const float* mol_Wdst    = (const float*)d_in[21];
    const float* mol_att_s   = (const float*)d_in[22];
    const float* mol_att_d   = (const float*)d_in[23];
    const float* mol_b       = (const float*)d_in[24];
    const float* mgru_Wih    = (const float*)d_in[25];
    const float* mgru_Whh    = (const float*)d_in[26];
    const float* mgru_bih    = (const float*)d_in[27];
    const float* mgru_bhh    = (const float*)d_in[28];
    const float* lin2_W      = (const float*)d_in[29];
    const float* lin2_b      = (const float*)d_in[30];

    const int* src = ei;
    const int* dst = ei + EE;

    // ---- workspace layout ----
    char* base = (char*)d_ws;
    size_t off = 0;
    auto alloc = [&](size_t bytes) -> void* {
        void* p = base + off;
        off = (off + bytes + 63) & ~(size_t)63;
        return p;
    };
    f16*      w16    = (f16*)alloc((size_t)NN * HH * 2);
    float*    hbuf   = (float*)alloc((size_t)NN * HH * 4);
    f16*      x16    = (f16*)alloc((size_t)NN * HH * 2);
    f16*      xin16  = (f16*)alloc((size_t)NN * CIN * 2);
    float*    abuf   = (float*)alloc((size_t)(EE + NN) * 4);
    float*    asb    = (float*)alloc((size_t)NN * 4);
    float*    adb    = (float*)alloc((size_t)NN * 4);
    float*    sb     = (float*)alloc((size_t)NN * 4);
    unsigned* mb     = (unsigned*)alloc((size_t)NN * 4);
    float*    outgp  = (float*)alloc((size_t)GG * HH * 4);
    float*    hg     = (float*)alloc((size_t)GG * HH * 4);
    f16*      outg16 = (f16*)alloc((size_t)GG * HH * 2);
    float*    adg    = (float*)alloc((size_t)GG * 4);
    float*    sg     = (float*)alloc((size_t)GG * 4);
    unsigned* mg     = (unsigned*)alloc((size_t)GG * 4);
    int*      degb   = (int*)alloc((size_t)NN * 4);
    int*      rowptr = (int*)alloc((size_t)(NN + 1) * 4);
    unsigned* cursor = (unsigned*)alloc((size_t)NN * 4);
    int*      csr_src = (int*)alloc((size_t)EE * 4);
    int*      csr_eid = (int*)alloc((size_t)EE * 4);
    int*      bdeg   = (int*)alloc((size_t)GG * 4);
    int*      brow   = (int*)alloc((size_t)(GG + 1) * 4);
    float*    ve     = (float*)alloc(64);
    float*    easum  = (float*)alloc(64);
    float*    vd     = (float*)alloc(HH * 4);
    float*    aloop  = (float*)alloc(64);
    f16*      lin1W16   = (f16*)alloc((size_t)HH * CIN * 2);
    f16*      conv0W16  = (f16*)alloc((size_t)HH * HH * 2);
    f16*      convsW16  = (f16*)alloc((size_t)2 * HH * HH * 2);
    f16*      gruWih16  = (f16*)alloc((size_t)3 * H3 * HH * 2);
    f16*      gruWhh16  = (f16*)alloc((size_t)3 * H3 * HH * 2);
    f16*      molWs16   = (f16*)alloc((size_t)HH * HH * 2);
    f16*      mgruWih16 = (f16*)alloc((size_t)H3 * HH * 2);
    f16*      mgruWhh16 = (f16*)alloc((size_t)H3 * HH * 2);
    if (off > ws_size) return;

    // ---- weight + input converts ----
    cvt_f2h<<<(NN * CIN + 255) / 256, 256, 0, stream>>>(x_in, xin16, NN * CIN);
    Cvt8 cv;
    cv.s[0] = lin1_W;   cv.d[0] = lin1W16;   cv.n[0] = HH * CIN;
    cv.s[1] = conv0_W;  cv.d[1] = conv0W16;  cv.n[1] = HH * HH;
    cv.s[2] = convs_W;  cv.d[2] = convsW16;  cv.n[2] = 2 * HH * HH;
    cv.s[3] = gru_Wih;  cv.d[3] = gruWih16;  cv.n[3] = 3 * H3 * HH;
    cv.s[4] = gru_Whh;  cv.d[4] = gruWhh16;  cv.n[4] = 3 * H3 * HH;
    cv.s[5] = mol_Wsrc; cv.d[5] = molWs16;   cv.n[5] = HH * HH;
    cv.s[6] = mgru_Wih; cv.d[6] = mgruWih16; cv.n[6] = H3 * HH;
    cv.s[7] = mgru_Whh; cv.d[7] = mgruWhh16; cv.n[7] = H3 * HH;
    cvt_multi<<<dim3((3 * H3 * HH + 255) / 256, 8), 256, 0, stream>>>(cv);

    // ---- CSR build ----
    hipMemsetAsync(degb, 0, NN * sizeof(int), stream);
    hist_kernel<<<(EE + 255) / 256, 256, 0, stream>>>(dst, degb, EE, NN);
    scan_wave<<<1, 64, 0, stream>>>(degb, rowptr, cursor, NN);
    scatter_kernel<<<(EE + 255) / 256, 256, 0, stream>>>(src, dst, cursor, csr_src, csr_eid, EE);
    hipMemsetAsync(bdeg, 0, GG * sizeof(int), stream);
    hist_kernel<<<(NN + 255) / 256, 256, 0, stream>>>(batch, bdeg, NN, GG);
    scan_wave<<<1, 64, 0, stream>>>(bdeg, brow, nullptr, GG);

    // ---- conv0 prep ----
    compose_vec<<<1, 256, 0, stream>>>(conv0_We, conv0_att_e, ve, HH, EDIM);
    hipMemsetAsync(easum, 0, 16 * sizeof(float), stream);
    ea_sum_kernel<<<256, 256, 0, stream>>>(eattr, easum, EE);
    finalize_aloop<<<1, 64, 0, stream>>>(easum, ve, aloop, 1.0f / EE);

    const dim3 gemmGrid((NN + 63) / 64, HH / 64);

    // ---- lin1 ----
    gemm_mfma<<<gemmGrid, 256, 0, stream>>>(xin16, lin1W16, lin1_b, nullptr, x16, NN, HH, CIN, 1);

    // ---- conv0 (edge feats + self loops, slope 0.2) ----
    gemm_mfma<<<gemmGrid, 256, 0, stream>>>(x16, conv0W16, nullptr, nullptr, w16, NN, HH, HH, 0);
    row_dots_h<<<(NN + 3) / 4, 256, 0, stream>>>(w16, NN, conv0_att_s, asb, conv0_att_d, adb, nullptr);
    hipMemsetAsync(mb, 0, NN * sizeof(unsigned), stream);
    edge_alpha_max<<<(EE + NN + 255) / 256, 256, 0, stream>>>(src, dst, EE, EE + NN, asb, adb,
                                                              eattr, ve, aloop, 0.2f, abuf, mb);
    hipMemsetAsync(sb, 0, NN * sizeof(float), stream);
    edge_exp_sum<<<(EE + NN + 255) / 256, 256, 0, stream>>>(dst, EE, EE + NN, abuf, mb, sb);
    csr_aggregate<<<(NN + 3) / 4, 256, 0, stream>>>(rowptr, csr_src, csr_eid, NN, NN, EE + NN,
                                                    1, EE, abuf, sb, w16, conv0_b, hbuf);
    gru_mfma<<<(NN + 15) / 16, 256, 0, stream>>>(hbuf, x16, gruWih16, gruWhh16, gru_bih, gru_bhh, NN);

    // ---- remaining atom convs (no self loops, slope 0.01) ----
    for (int l = 0; l < 2; l++) {
        gemm_mfma<<<gemmGrid, 256, 0, stream>>>(x16, convsW16 + (size_t)l * HH * HH,
                                                nullptr, nullptr, w16, NN, HH, HH, 0);
        row_dots_h<<<(NN + 3) / 4, 256, 0, stream>>>(w16, NN, convs_att_s + l * HH, asb,
                                                     convs_att_d + l * HH, adb, nullptr);
        hipMemsetAsync(mb, 0, NN * sizeof(unsigned), stream);
        edge_alpha_max<<<(EE + 255) / 256, 256, 0, stream>>>(src, dst, EE, EE, asb, adb,
                                                             nullptr, nullptr, nullptr, 0.01f, abuf, mb);
        hipMemsetAsync(sb, 0, NN * sizeof(float), stream);
        edge_exp_sum<<<(EE + 255) / 256, 256, 0, stream>>>(dst, EE, EE, abuf, mb, sb);
        csr_aggregate<<<(NN + 3) / 4, 256, 0, stream>>>(rowptr, csr_src, csr_eid, NN, NN, EE,
                                                        0, 0, abuf, sb, w16, convs_b + l * HH, hbuf);
        gru_mfma<<<(NN + 15) / 16, 256, 0, stream>>>(hbuf, x16,
                                                     gruWih16 + (size_t)(l + 1) * H3 * HH,
                                                     gruWhh16 + (size_t)(l + 1) * H3 * HH,
                                                     gru_bih + (size_t)(l + 1) * H3,
                                                     gru_bhh + (size_t)(l + 1) * H3, NN);
    }

    // ---- molecule readout ----
    hipMemsetAsync(outgp, 0, (size_t)GG * HH * sizeof(float), stream);
    pool_kernel<<<(NN * HH + 255) / 256, 256, 0, stream>>>(x16, batch, outgp, NN);
    relu_cvt_kernel<<<(GG * HH + 255) / 256, 256, 0, stream>>>(outgp, outg16, GG * HH);
    gemm_mfma<<<gemmGrid, 256, 0, stream>>>(x16, molWs16, nullptr, nullptr, w16, NN, HH, HH, 0);
    row_dots_h<<<(NN + 3) / 4, 256, 0, stream>>>(w16, NN, mol_att_s, asb, nullptr, nullptr, nullptr);
    compose_vec<<<1, 256, 0, stream>>>(mol_Wdst, mol_att_d, vd, HH, HH);

    for (int t = 0; t < 2; t++) {
        row_dots_h<<<(GG + 3) / 4, 256, 0, stream>>>(outg16, GG, vd, adg, nullptr, nullptr, nullptr);
        hipMemsetAsync(mg, 0, GG * sizeof(unsigned), stream);
        edge_alpha_max<<<(NN + 255) / 256, 256, 0, stream>>>(nullptr, batch, NN, NN, asb, adg,
                                                             nullptr, nullptr, nullptr, 0.01f, abuf, mg);
        hipMemsetAsync(sg, 0, GG * sizeof(float), stream);
        edge_exp_sum<<<(NN + 255) / 256, 256, 0, stream>>>(batch, NN, NN, abuf, mg, sg);
        csr_aggregate<<<(GG + 3) / 4, 256, 0, stream>>>(brow, nullptr, nullptr, GG, NN, NN,
                                                        0, 0, abuf, sg, w16, mol_b, hg);
        gru_mfma<<<(GG + 15) / 16, 256, 0, stream>>>(hg, outg16, mgruWih16, mgruWhh16,
                                                     mgru_bih, mgru_bhh, GG);
    }

    // ---- final linear ----
    row_dots_h<<<(GG + 3) / 4, 256, 0, stream>>>(outg16, GG, lin2_W, (float*)d_out,
                                                 nullptr, nullptr, lin2_b);
}

// Round 6
// 1978.631 us; speedup vs baseline: 3.3034x; 1.2032x over previous
//
#include <hip/hip_runtime.h>
#include <math.h>

// ---------------- problem constants ----------------
#define NN    50000
#define EE    800000
#define CIN   64
#define HH    192
#define EDIM  16
#define GG    2048
#define H3    576   // 3*H

typedef _Float16 f16;
typedef _Float16 half8 __attribute__((ext_vector_type(8)));
typedef float f32x4 __attribute__((ext_vector_type(4)));

// ---------------- helpers ----------------
__device__ __forceinline__ unsigned fmap(float f) {
    unsigned u = __float_as_uint(f);
    return (u & 0x80000000u) ? ~u : (u | 0x80000000u);
}
__device__ __forceinline__ float funmap(unsigned u) {
    if (u == 0u) return 0.0f;
    return (u & 0x80000000u) ? __uint_as_float(u ^ 0x80000000u)
                             : __uint_as_float(~u);
}

// ---------------- fp32 -> fp16 converts ----------------
__global__ void cvt_f2h(const float* __restrict__ s, f16* __restrict__ d, int n)
{
    int i = blockIdx.x * blockDim.x + threadIdx.x;
    if (i < n) d[i] = (f16)s[i];
}

struct Cvt8 { const float* s[8]; f16* d[8]; int n[8]; };
__global__ void cvt_multi(Cvt8 c)
{
    int slot = blockIdx.y;
    int i = blockIdx.x * blockDim.x + threadIdx.x;
    if (i < c.n[slot]) c.d[slot][i] = (f16)c.s[slot][i];
}

// ---------------- CSR build ----------------
__global__ void hist_kernel(const int* __restrict__ idx, int* __restrict__ deg, int n, int nbins)
{
    int i = blockIdx.x * blockDim.x + threadIdx.x;
    if (i < n) {
        unsigned b = (unsigned)idx[i];
        if (b < (unsigned)nbins) atomicAdd(&deg[b], 1);
    }
}

// single-WAVE exclusive scan (serial over 64-chunks) — used only for small arrays
__global__ void scan_wave(const int* __restrict__ deg, int* __restrict__ rowptr,
                          unsigned* __restrict__ cursor, int n)
{
    int lane = threadIdx.x & 63;
    int carry = 0;
    for (int base = 0; base < n; base += 64) {
        int i = base + lane;
        int v = (i < n) ? deg[i] : 0;
        int x = v;
        #pragma unroll
        for (int off = 1; off < 64; off <<= 1) {
            int t = __shfl_up(x, off);
            if (lane >= off) x += t;
        }
        int ex = carry + x - v;
        if (i < n) {
            rowptr[i] = ex;
            if (cursor) cursor[i] = (unsigned)ex;
        }
        carry += __shfl(x, 63);
    }
    if (lane == 0) rowptr[n] = carry;
}

// hierarchical scan, level 1: per-1024-chunk sums (256 thr, 4 elems/thr)
__global__ __launch_bounds__(256) void chunk_sum(const int* __restrict__ deg,
                                                 int* __restrict__ csum, int n)
{
    int base = blockIdx.x * 1024;
    int tid = threadIdx.x;
    int i0 = base + tid * 4;
    int s = 0;
    #pragma unroll
    for (int k = 0; k < 4; k++) { int i = i0 + k; if (i < n) s += deg[i]; }
    #pragma unroll
    for (int off = 32; off > 0; off >>= 1) s += __shfl_down(s, off);
    __shared__ int ws[4];
    int lane = tid & 63, w = tid >> 6;
    if (lane == 0) ws[w] = s;
    __syncthreads();
    if (tid == 0) csum[blockIdx.x] = ws[0] + ws[1] + ws[2] + ws[3];
}

// hierarchical scan, level 3: local exclusive scan + chunk offset
__global__ __launch_bounds__(256) void local_scan(const int* __restrict__ deg,
                                                  const int* __restrict__ choff,
                                                  int* __restrict__ rowptr,
                                                  unsigned* __restrict__ cursor,
                                                  int n, int nchunks)
{
    int base = blockIdx.x * 1024;
    int tid = threadIdx.x;
    int lane = tid & 63, w = tid >> 6;
    int i0 = base + tid * 4;
    int v[4];
    #pragma unroll
    for (int k = 0; k < 4; k++) { int i = i0 + k; v[k] = (i < n) ? deg[i] : 0; }
    int tsum = v[0] + v[1] + v[2] + v[3];
    int x = tsum;
    #pragma unroll
    for (int off = 1; off < 64; off <<= 1) {
        int t = __shfl_up(x, off);
        if (lane >= off) x += t;
    }
    __shared__ int wtot[4];
    if (lane == 63) wtot[w] = x;
    __syncthreads();
    int woff = 0;
    #pragma unroll
    for (int j = 0; j < 4; j++) if (j < w) woff += wtot[j];
    int ex = choff[blockIdx.x] + woff + x - tsum;
    #pragma unroll
    for (int k = 0; k < 4; k++) {
        int i = i0 + k;
        if (i < n) {
            rowptr[i] = ex;
            if (cursor) cursor[i] = (unsigned)ex;
        }
        ex += v[k];
    }
    if (blockIdx.x == 0 && tid == 0) rowptr[n] = choff[nchunks];
}

__global__ void scatter_kernel(const int* __restrict__ src, const int* __restrict__ dst,
                               unsigned* __restrict__ cursor,
                               int* __restrict__ csr_src, int* __restrict__ csr_eid, int E)
{
    int e = blockIdx.x * blockDim.x + threadIdx.x;
    if (e >= E) return;
    unsigned d = (unsigned)dst[e];
    if (d >= (unsigned)NN) return;
    unsigned p = atomicAdd(&cursor[d], 1u);
    if (p < (unsigned)E) {
        csr_src[p] = src[e];
        csr_eid[p] = e;
    }
}

// ---------------- MFMA GEMM: C[M,N] = act(A16[M,K] @ W16[N,K]^T + bias) ----------------
__global__ __launch_bounds__(256) void gemm_mfma(const f16* __restrict__ A,
                                                 const f16* __restrict__ W,
                                                 const float* __restrict__ bias,
                                                 float* __restrict__ Cf,
                                                 f16* __restrict__ Ch,
                                                 int M, int N, int K, int act)
{
    __shared__ __align__(16) f16 sA[64 * 40];
    const int tid  = threadIdx.x;
    const int lane = tid & 63;
    const int wid  = tid >> 6;
    const int wy = wid >> 1, wx = wid & 1;
    const int m0 = blockIdx.x << 6, n0 = blockIdx.y << 6;
    const int n_ = lane & 15, quad = lane >> 4;

    f32x4 acc[2][2] = {};
    int boff0 = (n0 + wx * 32 + n_) * K + quad * 8;
    int boff1 = boff0 + 16 * K;

    const int srow = tid >> 2;
    const int skc  = (tid & 3) << 3;

    for (int k0 = 0; k0 < K; k0 += 32) {
        half8 av = {};
        int gm = m0 + srow;
        if (gm < M) av = *(const half8*)(A + (size_t)gm * K + k0 + skc);
        *(half8*)(sA + srow * 40 + skc) = av;
        __syncthreads();
        half8 a0 = *(const half8*)(sA + (wy * 32 + n_) * 40 + quad * 8);
        half8 a1 = *(const half8*)(sA + (wy * 32 + 16 + n_) * 40 + quad * 8);
        half8 b0 = *(const half8*)(W + boff0 + k0);
        half8 b1 = *(const half8*)(W + boff1 + k0);
        acc[0][0] = __builtin_amdgcn_mfma_f32_16x16x32_f16(a0, b0, acc[0][0], 0, 0, 0);
        acc[0][1] = __builtin_amdgcn_mfma_f32_16x16x32_f16(a0, b1, acc[0][1], 0, 0, 0);
        acc[1][0] = __builtin_amdgcn_mfma_f32_16x16x32_f16(a1, b0, acc[1][0], 0, 0, 0);
        acc[1][1] = __builtin_amdgcn_mfma_f32_16x16x32_f16(a1, b1, acc[1][1], 0, 0, 0);
        __syncthreads();
    }
    #pragma unroll
    for (int i = 0; i < 2; i++)
        #pragma unroll
        for (int j = 0; j < 2; j++) {
            int col = n0 + wx * 32 + j * 16 + n_;
            float bv = bias ? bias[col] : 0.f;
            #pragma unroll
            for (int reg = 0; reg < 4; reg++) {
                int row = m0 + wy * 32 + i * 16 + quad * 4 + reg;
                if (row >= M) continue;
                float v = acc[i][j][reg] + bv;
                if (act == 1) v = v >= 0.f ? v : 0.01f * v;
                if (Cf) Cf[(size_t)row * N + col] = v;
                if (Ch) Ch[(size_t)row * N + col] = (f16)v;
            }
        }
}

// ---------------- fused MFMA GRU: X16 = relu(GRU(Hf, X16)) in place ----------------
__global__ __launch_bounds__(256) void gru_mfma(const float* __restrict__ Hf,
                                                f16* __restrict__ X16,
                                                const f16* __restrict__ Wih,
                                                const f16* __restrict__ Whh,
                                                const float* __restrict__ bih,
                                                const float* __restrict__ bhh,
                                                int M)
{
    __shared__ __align__(16) f16 sH[16 * 40];
    __shared__ __align__(16) f16 sX[16 * 40];
    const int tid  = threadIdx.x;
    const int lane = tid & 63;
    const int w    = tid >> 6;
    const int n_ = lane & 15, quad = lane >> 4;
    const int node0 = blockIdx.x << 4;

    f32x4 aI[3][3] = {};
    f32x4 aH[3][3] = {};
    int boff[3][3];
    #pragma unroll
    for (int g = 0; g < 3; g++)
        #pragma unroll
        for (int t = 0; t < 3; t++)
            boff[g][t] = (g * 192 + w * 48 + t * 16 + n_) * 192 + quad * 8;

    const int sr  = (tid >> 2) & 15;
    const int skc = (tid & 3) << 3;

    #pragma unroll 1
    for (int k0 = 0; k0 < 192; k0 += 32) {
        if (tid < 64) {
            const float* p = Hf + (size_t)(node0 + sr) * 192 + k0 + skc;
            if (node0 + sr < M) {
                float4 f0 = *(const float4*)p;
                float4 f1 = *(const float4*)(p + 4);
                half8 h;
                h[0] = (f16)f0.x; h[1] = (f16)f0.y; h[2] = (f16)f0.z; h[3] = (f16)f0.w;
                h[4] = (f16)f1.x; h[5] = (f16)f1.y; h[6] = (f16)f1.z; h[7] = (f16)f1.w;
                *(half8*)(sH + sr * 40 + skc) = h;
            } else {
                half8 h = {};
                *(half8*)(sH + sr * 40 + skc) = h;
            }
        } else if (tid < 128) {
            half8 v = {};
            if (node0 + sr < M)
                v = *(const half8*)(X16 + (size_t)(node0 + sr) * 192 + k0 + skc);
            *(half8*)(sX + sr * 40 + skc) = v;
        }
        __syncthreads();
        half8 ah = *(const half8*)(sH + n_ * 40 + quad * 8);
        half8 ax = *(const half8*)(sX + n_ * 40 + quad * 8);
        #pragma unroll
        for (int g = 0; g < 3; g++)
            #pragma unroll
            for (int t = 0; t < 3; t++) {
                half8 bI = *(const half8*)(Wih + boff[g][t] + k0);
                half8 bH = *(const half8*)(Whh + boff[g][t] + k0);
                aI[g][t] = __builtin_amdgcn_mfma_f32_16x16x32_f16(ah, bI, aI[g][t], 0, 0, 0);
                aH[g][t] = __builtin_amdgcn_mfma_f32_16x16x32_f16(ax, bH, aH[g][t], 0, 0, 0);
            }
        __syncthreads();
    }
    #pragma unroll
    for (int t = 0; t < 3; t++) {
        int c0 = w * 48 + t * 16 + n_;
        float bir = bih[c0], biz = bih[c0 + 192], bin = bih[c0 + 384];
        float bhr = bhh[c0], bhz = bhh[c0 + 192], bhn = bhh[c0 + 384];
        #pragma unroll
        for (int reg = 0; reg < 4; reg++) {
            int node = node0 + quad * 4 + reg;
            if (node >= M) continue;
            float hx = (float)X16[(size_t)node * 192 + c0];
            float ir = aI[0][t][reg] + bir;
            float iz = aI[1][t][reg] + biz;
            float in = aI[2][t][reg] + bin;
            float hr = aH[0][t][reg] + bhr;
            float hz = aH[1][t][reg] + bhz;
            float hn = aH[2][t][reg] + bhn;
            float r  = 1.f / (1.f + expf(-(ir + hr)));
            float z  = 1.f / (1.f + expf(-(iz + hz)));
            float nn = tanhf(in + r * hn);
            float o  = (1.f - z) * nn + z * hx;
            X16[(size_t)node * 192 + c0] = (f16)(o > 0.f ? o : 0.f);
        }
    }
}

// ---------------- small vector compose ----------------
__global__ void compose_vec(const float* __restrict__ W, const float* __restrict__ v,
                            float* __restrict__ out, int rows, int cols)
{
    int j = threadIdx.x;
    if (j >= cols) return;
    float acc = 0.f;
    for (int i = 0; i < rows; i++) acc += v[i] * W[(size_t)i * cols + j];
    out[j] = acc;
}

// ---------------- edge_attr column sums ----------------
__global__ void ea_sum_kernel(const float* __restrict__ ea, float* __restrict__ sums, int E)
{
    int lane = threadIdx.x & 63;
    float acc[16];
    #pragma unroll
    for (int f = 0; f < 16; f++) acc[f] = 0.f;
    for (int e = blockIdx.x * blockDim.x + threadIdx.x; e < E; e += gridDim.x * blockDim.x) {
        const float4* p = (const float4*)(ea + (size_t)e * 16);
        float4 v0 = p[0], v1 = p[1], v2 = p[2], v3 = p[3];
        acc[0] += v0.x; acc[1] += v0.y; acc[2] += v0.z; acc[3] += v0.w;
        acc[4] += v1.x; acc[5] += v1.y; acc[6] += v1.z; acc[7] += v1.w;
        acc[8] += v2.x; acc[9] += v2.y; acc[10] += v2.z; acc[11] += v2.w;
        acc[12] += v3.x; acc[13] += v3.y; acc[14] += v3.z; acc[15] += v3.w;
    }
    #pragma unroll
    for (int off = 32; off > 0; off >>= 1)
        #pragma unroll
        for (int f = 0; f < 16; f++) acc[f] += __shfl_down(acc[f], off);
    if (lane == 0)
        #pragma unroll
        for (int f = 0; f < 16; f++) atomicAdd(&sums[f], acc[f]);
}

__global__ void finalize_aloop(const float* __restrict__ sums, const float* __restrict__ ve,
                               float* __restrict__ aloop, float invE)
{
    if (threadIdx.x == 0) {
        float a = 0.f;
        for (int f = 0; f < 16; f++) a += sums[f] * invE * ve[f];
        *aloop = a;
    }
}

// ---------------- per-row dots on fp16 matrix (1-2 vectors) ----------------
__global__ void row_dots_h(const f16* __restrict__ Mat, int M,
                           const float* __restrict__ v1, float* __restrict__ o1,
                           const float* __restrict__ v2, float* __restrict__ o2,
                           const float* __restrict__ bias)
{
    int row = blockIdx.x * 4 + (threadIdx.x >> 6);
    if (row >= M) return;
    int lane = threadIdx.x & 63;
    const f16* rp = Mat + (size_t)row * 192;
    float a1 = 0.f, a2 = 0.f;
    #pragma unroll
    for (int k = 0; k < 3; k++) {
        int f = lane + 64 * k;
        float x = (float)rp[f];
        a1 += x * v1[f];
        if (o2) a2 += x * v2[f];
    }
    #pragma unroll
    for (int off = 32; off > 0; off >>= 1) {
        a1 += __shfl_down(a1, off);
        a2 += __shfl_down(a2, off);
    }
    if (lane == 0) {
        o1[row] = a1 + (bias ? bias[0] : 0.f);
        if (o2) o2[row] = a2;
    }
}

// ---------------- alpha + segment max ----------------
__global__ void edge_alpha_max(const int* __restrict__ srcp, const int* __restrict__ dstp,
                               int E_real, int Etot,
                               const float* __restrict__ as_, const float* __restrict__ ad_,
                               const float* __restrict__ ea, const float* __restrict__ ve,
                               const float* __restrict__ aloop, float slope,
                               float* __restrict__ ab, unsigned* __restrict__ mb)
{
    int i = blockIdx.x * blockDim.x + threadIdx.x;
    if (i >= Etot) return;
    int s_, d_;
    float aext = 0.f;
    if (i < E_real) {
        s_ = srcp ? srcp[i] : i;
        d_ = dstp[i];
        if (ea) {
            const float4* p = (const float4*)(ea + (size_t)i * 16);
            const float4* q = (const float4*)ve;
            float4 e0 = p[0], e1 = p[1], e2 = p[2], e3 = p[3];
            float4 w0 = q[0], w1 = q[1], w2 = q[2], w3 = q[3];
            aext = e0.x * w0.x + e0.y * w0.y + e0.z * w0.z + e0.w * w0.w
                 + e1.x * w1.x + e1.y * w1.y + e1.z * w1.z + e1.w * w1.w
                 + e2.x * w2.x + e2.y * w2.y + e2.z * w2.z + e2.w * w2.w
                 + e3.x * w3.x + e3.y * w3.y + e3.z * w3.z + e3.w * w3.w;
        }
    } else {
        s_ = d_ = i - E_real;
        aext = *aloop;
    }
    float a = as_[s_] + ad_[d_] + aext;
    a = a >= 0.f ? a : slope * a;
    ab[i] = a;
    atomicMax(&mb[d_], fmap(a));
}

// ---------------- exp(alpha - max) + segment sum ----------------
__global__ void edge_exp_sum(const int* __restrict__ dstp, int E_real, int Etot,
                             float* __restrict__ ab, const unsigned* __restrict__ mb,
                             float* __restrict__ sb)
{
    int i = blockIdx.x * blockDim.x + threadIdx.x;
    if (i >= Etot) return;
    int d_ = (i < E_real) ? dstp[i] : i - E_real;
    float m = funmap(mb[d_]);
    float e = expf(ab[i] - m);
    ab[i] = e;
    atomicAdd(&sb[d_], e);
}

// ---------------- CSR aggregate: Hout[dst] = elu(sum_e w_e*F[src_e]/sum + bias), fp32 out ----------------
__global__ __launch_bounds__(256) void csr_aggregate(const int* __restrict__ rowptr,
                                                     const int* __restrict__ csr_src,
                                                     const int* __restrict__ csr_eid,
                                                     int Ndst, int nF, int nAb,
                                                     int selfloop, int selfAb,
                                                     const float* __restrict__ ab,
                                                     const float* __restrict__ sb,
                                                     const f16* __restrict__ F,
                                                     const float* __restrict__ bias,
                                                     float* __restrict__ Hout)
{
    int node = blockIdx.x * 4 + (threadIdx.x >> 6);
    if (node >= Ndst) return;
    int lane = threadIdx.x & 63;
    int start = rowptr[node];
    int deg = rowptr[node + 1] - start;
    deg = min(max(deg, 0), 1 << 20);
    float inv = 1.f / (sb[node] + 1e-16f);

    float acc0 = 0.f, acc1 = 0.f, acc2 = 0.f;
    for (int base = 0; base < deg; base += 64) {
        int i = base + lane;
        float wv = 0.f;
        int s = 0;
        if (i < deg) {
            int pos = start + i;
            s = csr_src ? csr_src[pos] : pos;
            if ((unsigned)s >= (unsigned)nF) s = 0;
            unsigned eid = csr_eid ? (unsigned)csr_eid[pos] : (unsigned)pos;
            if (eid >= (unsigned)nAb) eid = 0;
            wv = ab[eid];
        }
        int cnt = min(64, deg - base);
        for (int j = 0; j < cnt; j++) {
            float wj = __shfl(wv, j);
            int   sj = __shfl(s, j);
            const f16* fr = F + (size_t)sj * 192;
            acc0 += wj * (float)fr[lane];
            acc1 += wj * (float)fr[lane + 64];
            acc2 += wj * (float)fr[lane + 128];
        }
    }
    if (selfloop) {
        unsigned eid = (unsigned)(selfAb + node);
        float wv = (eid < (unsigned)nAb) ? ab[eid] : 0.f;
        int s = min(node, nF - 1);
        const f16* fr = F + (size_t)s * 192;
        acc0 += wv * (float)fr[lane];
        acc1 += wv * (float)fr[lane + 64];
        acc2 += wv * (float)fr[lane + 128];
    }
    float h0 = acc0 * inv + bias[lane];
    float h1 = acc1 * inv + bias[lane + 64];
    float h2 = acc2 * inv + bias[lane + 128];
    float* orow = Hout + (size_t)node * 192;
    orow[lane]       = h0 > 0.f ? h0 : expm1f(h0);
    orow[lane + 64]  = h1 > 0.f ? h1 : expm1f(h1);
    orow[lane + 128] = h2 > 0.f ? h2 : expm1f(h2);
}

// ---------------- pool: per-graph wave sum over contiguous node range, relu, fp16 ----------------
__global__ void pool_csr(const int* __restrict__ brow, const f16* __restrict__ X,
                         f16* __restrict__ outg16, int G)
{
    int g = blockIdx.x * 4 + (threadIdx.x >> 6);
    if (g >= G) return;
    int lane = threadIdx.x & 63;
    float a0 = 0.f, a1 = 0.f, a2 = 0.f;
    int s = max(brow[g], 0);
    int e = min(brow[g + 1], NN);
    for (int n = s; n < e; n++) {
        const f16* xr = X + (size_t)n * 192;
        a0 += (float)xr[lane];
        a1 += (float)xr[lane + 64];
        a2 += (float)xr[lane + 128];
    }
    f16* o = outg16 + (size_t)g * 192;
    o[lane]       = (f16)(a0 > 0.f ? a0 : 0.f);
    o[lane + 64]  = (f16)(a1 > 0.f ? a1 : 0.f);
    o[lane + 128] = (f16)(a2 > 0.f ? a2 : 0.f);
}

// ---------------- launch ----------------
extern "C" void kernel_launch(void* const* d_in, const int* in_sizes, int n_in,
                              void* d_out, int out_size, void* d_ws, size_t ws_size,
                              hipStream_t stream)
{
    const float* x_in        = (const float*)d_in[0];
    const int*   ei          = (const int*)  d_in[1];
    const float* eattr       = (const float*)d_in[2];
    const int*   batch       = (const int*)  d_in[3];
    const float* lin1_W      = (const float*)d_in[4];
    const float* lin1_b      = (const float*)d_in[5];
    const float* conv0_W     = (const float*)d_in[6];
    const float* conv0_att_s = (const float*)d_in[7];
    const float* conv0_att_d = (const float*)d_in[8];
    const float* conv0_We    = (const float*)d_in[9];
    const float* conv0_att_e = (const float*)d_in[10];
    const float* conv0_b     = (const float*)d_in[11];
    const float* convs_W     = (const float*)d_in[12];
    const float* convs_att_s = (const float*)d_in[13];
    const float* convs_att_d = (const float*)d_in[14];
    const float* convs_b     = (const float*)d_in[15];
    const float* gru_Wih     = (const float*)d_in[16];
    const float* gru_Whh     = (const float*)d_in[17];
    const float* gru_bih     = (const float*)d_in[18];
    const float* gru_bhh     = (const float*)d_in[19];
    const float* mol_Wsrc    = (const float*)d_in[20];
    const float* mol_Wdst    = (const float*)d_in[21];
    const float* mol_att_s   = (const float*)d_in[22];
    const float* mol_att_d   = (const float*)d_in[23];
    const float* mol_b       = (const float*)d_in[24];
    const float* mgru_Wih    = (const float*)d_in[25];
    const float* mgru_Whh    = (const float*)d_in[26];
    const float* mgru_bih    = (const float*)d_in[27];
    const float* mgru_bhh    = (const float*)d_in[28];
    const float* lin2_W      = (const float*)d_in[29];
    const float* lin2_b      = (const float*)d_in[30];

    const int* src = ei;
    const int* dst = ei + EE;

    // ---- workspace layout ----
    char* base = (char*)d_ws;
    size_t off = 0;
    auto alloc = [&](size_t bytes) -> void* {
        void* p = base + off;
        off = (off + bytes + 63) & ~(size_t)63;
        return p;
    };
    f16*      w16    = (f16*)alloc((size_t)NN * HH * 2);
    float*    hbuf   = (float*)alloc((size_t)NN * HH * 4);
    f16*      x16    = (f16*)alloc((size_t)NN * HH * 2);
    f16*      xin16  = (f16*)alloc((size_t)NN * CIN * 2);
    float*    abuf   = (float*)alloc((size_t)(EE + NN) * 4);
    float*    asb    = (float*)alloc((size_t)NN * 4);
    float*    adb    = (float*)alloc((size_t)NN * 4);
    float*    sb     = (float*)alloc((size_t)NN * 4);
    unsigned* mb     = (unsigned*)alloc((size_t)NN * 4);
    float*    hg     = (float*)alloc((size_t)GG * HH * 4);
    f16*      outg16 = (f16*)alloc((size_t)GG * HH * 2);
    float*    adg    = (float*)alloc((size_t)GG * 4);
    float*    sg     = (float*)alloc((size_t)GG * 4);
    unsigned* mg     = (unsigned*)alloc((size_t)GG * 4);
    int*      degb   = (int*)alloc((size_t)NN * 4);
    int*      rowptr = (int*)alloc((size_t)(NN + 1) * 4);
    unsigned* cursor = (unsigned*)alloc((size_t)NN * 4);
    int*      csr_src = (int*)alloc((size_t)EE * 4);
    int*      csr_eid = (int*)alloc((size_t)EE * 4);
    int*      bdeg   = (int*)alloc((size_t)GG * 4);
    int*      brow   = (int*)alloc((size_t)(GG + 1) * 4);
    int*      csum   = (int*)alloc(64 * 4);
    int*      choff  = (int*)alloc(65 * 4);
    float*    ve     = (float*)alloc(64);
    float*    easum  = (float*)alloc(64);
    float*    vd     = (float*)alloc(HH * 4);
    float*    aloop  = (float*)alloc(64);
    f16*      lin1W16   = (f16*)alloc((size_t)HH * CIN * 2);
    f16*      conv0W16  = (f16*)alloc((size_t)HH * HH * 2);
    f16*      convsW16  = (f16*)alloc((size_t)2 * HH * HH * 2);
    f16*      gruWih16  = (f16*)alloc((size_t)3 * H3 * HH * 2);
    f16*      gruWhh16  = (f16*)alloc((size_t)3 * H3 * HH * 2);
    f16*      molWs16   = (f16*)alloc((size_t)HH * HH * 2);
    f16*      mgruWih16 = (f16*)alloc((size_t)H3 * HH * 2);
    f16*      mgruWhh16 = (f16*)alloc((size_t)H3 * HH * 2);
    if (off > ws_size) return;

    // ---- weight + input converts ----
    cvt_f2h<<<(NN * CIN + 255) / 256, 256, 0, stream>>>(x_in, xin16, NN * CIN);
    Cvt8 cv;
    cv.s[0] = lin1_W;   cv.d[0] = lin1W16;   cv.n[0] = HH * CIN;
    cv.s[1] = conv0_W;  cv.d[1] = conv0W16;  cv.n[1] = HH * HH;
    cv.s[2] = convs_W;  cv.d[2] = convsW16;  cv.n[2] = 2 * HH * HH;
    cv.s[3] = gru_Wih;  cv.d[3] = gruWih16;  cv.n[3] = 3 * H3 * HH;
    cv.s[4] = gru_Whh;  cv.d[4] = gruWhh16;  cv.n[4] = 3 * H3 * HH;
    cv.s[5] = mol_Wsrc; cv.d[5] = molWs16;   cv.n[5] = HH * HH;
    cv.s[6] = mgru_Wih; cv.d[6] = mgruWih16; cv.n[6] = H3 * HH;
    cv.s[7] = mgru_Whh; cv.d[7] = mgruWhh16; cv.n[7] = H3 * HH;
    cvt_multi<<<dim3((3 * H3 * HH + 255) / 256, 8), 256, 0, stream>>>(cv);

    // ---- CSR build (hierarchical scan for NN; single-wave scan for GG) ----
    const int nchunks = (NN + 1023) / 1024;   // 49
    hipMemsetAsync(degb, 0, NN * sizeof(int), stream);
    hist_kernel<<<(EE + 255) / 256, 256, 0, stream>>>(dst, degb, EE, NN);
    chunk_sum<<<nchunks, 256, 0, stream>>>(degb, csum, NN);
    scan_wave<<<1, 64, 0, stream>>>(csum, choff, nullptr, nchunks);
    local_scan<<<nchunks, 256, 0, stream>>>(degb, choff, rowptr, cursor, NN, nchunks);
    scatter_kernel<<<(EE + 255) / 256, 256, 0, stream>>>(src, dst, cursor, csr_src, csr_eid, EE);
    hipMemsetAsync(bdeg, 0, GG * sizeof(int), stream);
    hist_kernel<<<(NN + 255) / 256, 256, 0, stream>>>(batch, bdeg, NN, GG);
    scan_wave<<<1, 64, 0, stream>>>(bdeg, brow, nullptr, GG);

    // ---- conv0 prep ----
    compose_vec<<<1, 256, 0, stream>>>(conv0_We, conv0_att_e, ve, HH, EDIM);
    hipMemsetAsync(easum, 0, 16 * sizeof(float), stream);
    ea_sum_kernel<<<256, 256, 0, stream>>>(eattr, easum, EE);
    finalize_aloop<<<1, 64, 0, stream>>>(easum, ve, aloop, 1.0f / EE);

    const dim3 gemmGrid((NN + 63) / 64, HH / 64);

    // ---- lin1 ----
    gemm_mfma<<<gemmGrid, 256, 0, stream>>>(xin16, lin1W16, lin1_b, nullptr, x16, NN, HH, CIN, 1);

    // ---- conv0 (edge feats + self loops, slope 0.2) ----
    gemm_mfma<<<gemmGrid, 256, 0, stream>>>(x16, conv0W16, nullptr, nullptr, w16, NN, HH, HH, 0);
    row_dots_h<<<(NN + 3) / 4, 256, 0, stream>>>(w16, NN, conv0_att_s, asb, conv0_att_d, adb, nullptr);
    hipMemsetAsync(mb, 0, NN * sizeof(unsigned), stream);
    edge_alpha_max<<<(EE + NN + 255) / 256, 256, 0, stream>>>(src, dst, EE, EE + NN, asb, adb,
                                                              eattr, ve, aloop, 0.2f, abuf, mb);
    hipMemsetAsync(sb, 0, NN * sizeof(float), stream);
    edge_exp_sum<<<(EE + NN + 255) / 256, 256, 0, stream>>>(dst, EE, EE + NN, abuf, mb, sb);
    csr_aggregate<<<(NN + 3) / 4, 256, 0, stream>>>(rowptr, csr_src, csr_eid, NN, NN, EE + NN,
                                                    1, EE, abuf, sb, w16, conv0_b, hbuf);
    gru_mfma<<<(NN + 15) / 16, 256, 0, stream>>>(hbuf, x16, gruWih16, gruWhh16, gru_bih, gru_bhh, NN);

    // ---- remaining atom convs (no self loops, slope 0.01) ----
    for (int l = 0; l < 2; l++) {
        gemm_mfma<<<gemmGrid, 256, 0, stream>>>(x16, convsW16 + (size_t)l * HH * HH,
                                                nullptr, nullptr, w16, NN, HH, HH, 0);
        row_dots_h<<<(NN + 3) / 4, 256, 0, stream>>>(w16, NN, convs_att_s + l * HH, asb,
                                                     convs_att_d + l * HH, adb, nullptr);
        hipMemsetAsync(mb, 0, NN * sizeof(unsigned), stream);
        edge_alpha_max<<<(EE + 255) / 256, 256, 0, stream>>>(src, dst, EE, EE, asb, adb,
                                                             nullptr, nullptr, nullptr, 0.01f, abuf, mb);
        hipMemsetAsync(sb, 0, NN * sizeof(float), stream);
        edge_exp_sum<<<(EE + 255) / 256, 256, 0, stream>>>(dst, EE, EE, abuf, mb, sb);
        csr_aggregate<<<(NN + 3) / 4, 256, 0, stream>>>(rowptr, csr_src, csr_eid, NN, NN, EE,
                                                        0, 0, abuf, sb, w16, convs_b + l * HH, hbuf);
        gru_mfma<<<(NN + 15) / 16, 256, 0, stream>>>(hbuf, x16,
                                                     gruWih16 + (size_t)(l + 1) * H3 * HH,
                                                     gruWhh16 + (size_t)(l + 1) * H3 * HH,
                                                     gru_bih + (size_t)(l + 1) * H3,
                                                     gru_bhh + (size_t)(l + 1) * H3, NN);
    }

    // ---- molecule readout ----
    pool_csr<<<(GG + 3) / 4, 256, 0, stream>>>(brow, x16, outg16, GG);
    gemm_mfma<<<gemmGrid, 256, 0, stream>>>(x16, molWs16, nullptr, nullptr, w16, NN, HH, HH, 0);
    row_dots_h<<<(NN + 3) / 4, 256, 0, stream>>>(w16, NN, mol_att_s, asb, nullptr, nullptr, nullptr);
    compose_vec<<<1, 256, 0, stream>>>(mol_Wdst, mol_att_d, vd, HH, HH);

    for (int t = 0; t < 2; t++) {
        row_dots_h<<<(GG + 3) / 4, 256, 0, stream>>>(outg16, GG, vd, adg, nullptr, nullptr, nullptr);
        hipMemsetAsync(mg, 0, GG * sizeof(unsigned), stream);
        edge_alpha_max<<<(NN + 255) / 256, 256, 0, stream>>>(nullptr, batch, NN, NN, asb, adg,
                                                             nullptr, nullptr, nullptr, 0.01f, abuf, mg);
        hipMemsetAsync(sg, 0, GG * sizeof(float), stream);
        edge_exp_sum<<<(NN + 255) / 256, 256, 0, stream>>>(batch, NN, NN, abuf, mg, sg);
        csr_aggregate<<<(GG + 3) / 4, 256, 0, stream>>>(brow, nullptr, nullptr, GG, NN, NN,
                                                        0, 0, abuf, sg, w16, mol_b, hg);
        gru_mfma<<<(GG + 15) / 16, 256, 0, stream>>>(hg, outg16, mgruWih16, mgruWhh16,
                                                     mgru_bih, mgru_bhh, GG);
    }

    // ---- final linear ----
    row_dots_h<<<(GG + 3) / 4, 256, 0, stream>>>(outg16, GG, lin2_W, (float*)d_out,
                                                 nullptr, nullptr, lin2_b);
}

// Round 7
// 1792.857 us; speedup vs baseline: 3.6457x; 1.1036x over previous
//
#include <hip/hip_runtime.h>
#include <math.h>

// ---------------- problem constants ----------------
#define NN    50000
#define EE    800000
#define CIN   64
#define HH    192
#define EDIM  16
#define GG    2048
#define H3    576   // 3*H
#define EA_BLOCKS 256

typedef _Float16 f16;
typedef _Float16 half8 __attribute__((ext_vector_type(8)));
typedef float f32x4 __attribute__((ext_vector_type(4)));

// ---------------- helpers ----------------
__device__ __forceinline__ unsigned fmap(float f) {
    unsigned u = __float_as_uint(f);
    return (u & 0x80000000u) ? ~u : (u | 0x80000000u);
}
__device__ __forceinline__ float funmap(unsigned u) {
    if (u == 0u) return 0.0f;
    return (u & 0x80000000u) ? __uint_as_float(u ^ 0x80000000u)
                             : __uint_as_float(~u);
}

// ---------------- fp32 -> fp16 converts ----------------
__global__ void cvt_f2h(const float* __restrict__ s, f16* __restrict__ d, int n)
{
    int i = blockIdx.x * blockDim.x + threadIdx.x;
    if (i < n) d[i] = (f16)s[i];
}

struct Cvt8 { const float* s[8]; f16* d[8]; int n[8]; };
__global__ void cvt_multi(Cvt8 c)
{
    int slot = blockIdx.y;
    int i = blockIdx.x * blockDim.x + threadIdx.x;
    if (i < c.n[slot]) c.d[slot][i] = (f16)c.s[slot][i];
}

// ---------------- CSR build ----------------
__global__ void hist_kernel(const int* __restrict__ idx, int* __restrict__ deg, int n, int nbins)
{
    int i = blockIdx.x * blockDim.x + threadIdx.x;
    if (i < n) {
        unsigned b = (unsigned)idx[i];
        if (b < (unsigned)nbins) atomicAdd(&deg[b], 1);
    }
}

// single-WAVE exclusive scan (serial over 64-chunks) — used only for small arrays
__global__ void scan_wave(const int* __restrict__ deg, int* __restrict__ rowptr,
                          unsigned* __restrict__ cursor, int n)
{
    int lane = threadIdx.x & 63;
    int carry = 0;
    for (int base = 0; base < n; base += 64) {
        int i = base + lane;
        int v = (i < n) ? deg[i] : 0;
        int x = v;
        #pragma unroll
        for (int off = 1; off < 64; off <<= 1) {
            int t = __shfl_up(x, off);
            if (lane >= off) x += t;
        }
        int ex = carry + x - v;
        if (i < n) {
            rowptr[i] = ex;
            if (cursor) cursor[i] = (unsigned)ex;
        }
        carry += __shfl(x, 63);
    }
    if (lane == 0) rowptr[n] = carry;
}

// hierarchical scan, level 1: per-1024-chunk sums (256 thr, 4 elems/thr)
__global__ __launch_bounds__(256) void chunk_sum(const int* __restrict__ deg,
                                                 int* __restrict__ csum, int n)
{
    int base = blockIdx.x * 1024;
    int tid = threadIdx.x;
    int i0 = base + tid * 4;
    int s = 0;
    #pragma unroll
    for (int k = 0; k < 4; k++) { int i = i0 + k; if (i < n) s += deg[i]; }
    #pragma unroll
    for (int off = 32; off > 0; off >>= 1) s += __shfl_down(s, off);
    __shared__ int ws[4];
    int lane = tid & 63, w = tid >> 6;
    if (lane == 0) ws[w] = s;
    __syncthreads();
    if (tid == 0) csum[blockIdx.x] = ws[0] + ws[1] + ws[2] + ws[3];
}

// hierarchical scan, level 3: local exclusive scan + chunk offset
__global__ __launch_bounds__(256) void local_scan(const int* __restrict__ deg,
                                                  const int* __restrict__ choff,
                                                  int* __restrict__ rowptr,
                                                  unsigned* __restrict__ cursor,
                                                  int n, int nchunks)
{
    int base = blockIdx.x * 1024;
    int tid = threadIdx.x;
    int lane = tid & 63, w = tid >> 6;
    int i0 = base + tid * 4;
    int v[4];
    #pragma unroll
    for (int k = 0; k < 4; k++) { int i = i0 + k; v[k] = (i < n) ? deg[i] : 0; }
    int tsum = v[0] + v[1] + v[2] + v[3];
    int x = tsum;
    #pragma unroll
    for (int off = 1; off < 64; off <<= 1) {
        int t = __shfl_up(x, off);
        if (lane >= off) x += t;
    }
    __shared__ int wtot[4];
    if (lane == 63) wtot[w] = x;
    __syncthreads();
    int woff = 0;
    #pragma unroll
    for (int j = 0; j < 4; j++) if (j < w) woff += wtot[j];
    int ex = choff[blockIdx.x] + woff + x - tsum;
    #pragma unroll
    for (int k = 0; k < 4; k++) {
        int i = i0 + k;
        if (i < n) {
            rowptr[i] = ex;
            if (cursor) cursor[i] = (unsigned)ex;
        }
        ex += v[k];
    }
    if (blockIdx.x == 0 && tid == 0) rowptr[n] = choff[nchunks];
}

__global__ void scatter_kernel(const int* __restrict__ src, const int* __restrict__ dst,
                               unsigned* __restrict__ cursor,
                               int* __restrict__ csr_src, int* __restrict__ csr_eid, int E)
{
    int e = blockIdx.x * blockDim.x + threadIdx.x;
    if (e >= E) return;
    unsigned d = (unsigned)dst[e];
    if (d >= (unsigned)NN) return;
    unsigned p = atomicAdd(&cursor[d], 1u);
    if (p < (unsigned)E) {
        csr_src[p] = src[e];
        csr_eid[p] = e;
    }
}

// ---------------- MFMA GEMM: C[M,N] = act(A16[M,K] @ W16[N,K]^T + bias) ----------------
__global__ __launch_bounds__(256) void gemm_mfma(const f16* __restrict__ A,
                                                 const f16* __restrict__ W,
                                                 const float* __restrict__ bias,
                                                 float* __restrict__ Cf,
                                                 f16* __restrict__ Ch,
                                                 int M, int N, int K, int act)
{
    __shared__ __align__(16) f16 sA[64 * 40];
    const int tid  = threadIdx.x;
    const int lane = tid & 63;
    const int wid  = tid >> 6;
    const int wy = wid >> 1, wx = wid & 1;
    const int m0 = blockIdx.x << 6, n0 = blockIdx.y << 6;
    const int n_ = lane & 15, quad = lane >> 4;

    f32x4 acc[2][2] = {};
    int boff0 = (n0 + wx * 32 + n_) * K + quad * 8;
    int boff1 = boff0 + 16 * K;

    const int srow = tid >> 2;
    const int skc  = (tid & 3) << 3;

    for (int k0 = 0; k0 < K; k0 += 32) {
        half8 av = {};
        int gm = m0 + srow;
        if (gm < M) av = *(const half8*)(A + (size_t)gm * K + k0 + skc);
        *(half8*)(sA + srow * 40 + skc) = av;
        __syncthreads();
        half8 a0 = *(const half8*)(sA + (wy * 32 + n_) * 40 + quad * 8);
        half8 a1 = *(const half8*)(sA + (wy * 32 + 16 + n_) * 40 + quad * 8);
        half8 b0 = *(const half8*)(W + boff0 + k0);
        half8 b1 = *(const half8*)(W + boff1 + k0);
        acc[0][0] = __builtin_amdgcn_mfma_f32_16x16x32_f16(a0, b0, acc[0][0], 0, 0, 0);
        acc[0][1] = __builtin_amdgcn_mfma_f32_16x16x32_f16(a0, b1, acc[0][1], 0, 0, 0);
        acc[1][0] = __builtin_amdgcn_mfma_f32_16x16x32_f16(a1, b0, acc[1][0], 0, 0, 0);
        acc[1][1] = __builtin_amdgcn_mfma_f32_16x16x32_f16(a1, b1, acc[1][1], 0, 0, 0);
        __syncthreads();
    }
    #pragma unroll
    for (int i = 0; i < 2; i++)
        #pragma unroll
        for (int j = 0; j < 2; j++) {
            int col = n0 + wx * 32 + j * 16 + n_;
            float bv = bias ? bias[col] : 0.f;
            #pragma unroll
            for (int reg = 0; reg < 4; reg++) {
                int row = m0 + wy * 32 + i * 16 + quad * 4 + reg;
                if (row >= M) continue;
                float v = acc[i][j][reg] + bv;
                if (act == 1) v = v >= 0.f ? v : 0.01f * v;
                if (Cf) Cf[(size_t)row * N + col] = v;
                if (Ch) Ch[(size_t)row * N + col] = (f16)v;
            }
        }
}

// ---------------- fused MFMA GRU: X16 = relu(GRU(Hf, X16)) in place ----------------
__global__ __launch_bounds__(256) void gru_mfma(const float* __restrict__ Hf,
                                                f16* __restrict__ X16,
                                                const f16* __restrict__ Wih,
                                                const f16* __restrict__ Whh,
                                                const float* __restrict__ bih,
                                                const float* __restrict__ bhh,
                                                int M)
{
    __shared__ __align__(16) f16 sH[16 * 40];
    __shared__ __align__(16) f16 sX[16 * 40];
    const int tid  = threadIdx.x;
    const int lane = tid & 63;
    const int w    = tid >> 6;
    const int n_ = lane & 15, quad = lane >> 4;
    const int node0 = blockIdx.x << 4;

    f32x4 aI[3][3] = {};
    f32x4 aH[3][3] = {};
    int boff[3][3];
    #pragma unroll
    for (int g = 0; g < 3; g++)
        #pragma unroll
        for (int t = 0; t < 3; t++)
            boff[g][t] = (g * 192 + w * 48 + t * 16 + n_) * 192 + quad * 8;

    const int sr  = (tid >> 2) & 15;
    const int skc = (tid & 3) << 3;

    #pragma unroll 1
    for (int k0 = 0; k0 < 192; k0 += 32) {
        if (tid < 64) {
            const float* p = Hf + (size_t)(node0 + sr) * 192 + k0 + skc;
            if (node0 + sr < M) {
                float4 f0 = *(const float4*)p;
                float4 f1 = *(const float4*)(p + 4);
                half8 h;
                h[0] = (f16)f0.x; h[1] = (f16)f0.y; h[2] = (f16)f0.z; h[3] = (f16)f0.w;
                h[4] = (f16)f1.x; h[5] = (f16)f1.y; h[6] = (f16)f1.z; h[7] = (f16)f1.w;
                *(half8*)(sH + sr * 40 + skc) = h;
            } else {
                half8 h = {};
                *(half8*)(sH + sr * 40 + skc) = h;
            }
        } else if (tid < 128) {
            half8 v = {};
            if (node0 + sr < M)
                v = *(const half8*)(X16 + (size_t)(node0 + sr) * 192 + k0 + skc);
            *(half8*)(sX + sr * 40 + skc) = v;
        }
        __syncthreads();
        half8 ah = *(const half8*)(sH + n_ * 40 + quad * 8);
        half8 ax = *(const half8*)(sX + n_ * 40 + quad * 8);
        #pragma unroll
        for (int g = 0; g < 3; g++)
            #pragma unroll
            for (int t = 0; t < 3; t++) {
                half8 bI = *(const half8*)(Wih + boff[g][t] + k0);
                half8 bH = *(const half8*)(Whh + boff[g][t] + k0);
                aI[g][t] = __builtin_amdgcn_mfma_f32_16x16x32_f16(ah, bI, aI[g][t], 0, 0, 0);
                aH[g][t] = __builtin_amdgcn_mfma_f32_16x16x32_f16(ax, bH, aH[g][t], 0, 0, 0);
            }
        __syncthreads();
    }
    #pragma unroll
    for (int t = 0; t < 3; t++) {
        int c0 = w * 48 + t * 16 + n_;
        float bir = bih[c0], biz = bih[c0 + 192], bin = bih[c0 + 384];
        float bhr = bhh[c0], bhz = bhh[c0 + 192], bhn = bhh[c0 + 384];
        #pragma unroll
        for (int reg = 0; reg < 4; reg++) {
            int node = node0 + quad * 4 + reg;
            if (node >= M) continue;
            float hx = (float)X16[(size_t)node * 192 + c0];
            float ir = aI[0][t][reg] + bir;
            float iz = aI[1][t][reg] + biz;
            float in = aI[2][t][reg] + bin;
            float hr = aH[0][t][reg] + bhr;
            float hz = aH[1][t][reg] + bhz;
            float hn = aH[2][t][reg] + bhn;
            float r  = 1.f / (1.f + expf(-(ir + hr)));
            float z  = 1.f / (1.f + expf(-(iz + hz)));
            float nn = tanhf(in + r * hn);
            float o  = (1.f - z) * nn + z * hx;
            X16[(size_t)node * 192 + c0] = (f16)(o > 0.f ? o : 0.f);
        }
    }
}

// ---------------- small vector compose ----------------
__global__ void compose_vec(const float* __restrict__ W, const float* __restrict__ v,
                            float* __restrict__ out, int rows, int cols)
{
    int j = threadIdx.x;
    if (j >= cols) return;
    float acc = 0.f;
    for (int i = 0; i < rows; i++) acc += v[i] * W[(size_t)i * cols + j];
    out[j] = acc;
}

// ---------------- edge_attr column sums -> per-block partials (no atomics) ----------------
__global__ __launch_bounds__(256) void ea_sum_kernel(const float* __restrict__ ea,
                                                     float* __restrict__ partials, int E)
{
    __shared__ float ws[4][16];
    int tid = threadIdx.x;
    int lane = tid & 63, w = tid >> 6;
    float acc[16];
    #pragma unroll
    for (int f = 0; f < 16; f++) acc[f] = 0.f;
    for (int e = blockIdx.x * blockDim.x + tid; e < E; e += gridDim.x * blockDim.x) {
        const float4* p = (const float4*)(ea + (size_t)e * 16);
        float4 v0 = p[0], v1 = p[1], v2 = p[2], v3 = p[3];
        acc[0] += v0.x; acc[1] += v0.y; acc[2] += v0.z; acc[3] += v0.w;
        acc[4] += v1.x; acc[5] += v1.y; acc[6] += v1.z; acc[7] += v1.w;
        acc[8] += v2.x; acc[9] += v2.y; acc[10] += v2.z; acc[11] += v2.w;
        acc[12] += v3.x; acc[13] += v3.y; acc[14] += v3.z; acc[15] += v3.w;
    }
    #pragma unroll
    for (int off = 32; off > 0; off >>= 1)
        #pragma unroll
        for (int f = 0; f < 16; f++) acc[f] += __shfl_down(acc[f], off);
    if (lane == 0)
        #pragma unroll
        for (int f = 0; f < 16; f++) ws[w][f] = acc[f];
    __syncthreads();
    if (tid < 16)
        partials[blockIdx.x * 16 + tid] = ws[0][tid] + ws[1][tid] + ws[2][tid] + ws[3][tid];
}

// one wave: aloop = (sum over blocks of partials)·ve / E
__global__ void finalize_aloop(const float* __restrict__ partials, const float* __restrict__ ve,
                               float* __restrict__ aloop, float invE, int nblk)
{
    int lane = threadIdx.x & 63;
    float s = 0.f;
    if (lane < 16) {
        for (int b = 0; b < nblk; b += 4) {
            s += partials[b * 16 + lane]
               + partials[(b + 1) * 16 + lane]
               + partials[(b + 2) * 16 + lane]
               + partials[(b + 3) * 16 + lane];
        }
        s *= invE * ve[lane];
    }
    #pragma unroll
    for (int off = 8; off > 0; off >>= 1) s += __shfl_down(s, off);
    if (lane == 0) *aloop = s;
}

// ---------------- per-row dots on fp16 matrix (1-2 vectors) ----------------
__global__ void row_dots_h(const f16* __restrict__ Mat, int M,
                           const float* __restrict__ v1, float* __restrict__ o1,
                           const float* __restrict__ v2, float* __restrict__ o2,
                           const float* __restrict__ bias)
{
    int row = blockIdx.x * 4 + (threadIdx.x >> 6);
    if (row >= M) return;
    int lane = threadIdx.x & 63;
    const f16* rp = Mat + (size_t)row * 192;
    float a1 = 0.f, a2 = 0.f;
    #pragma unroll
    for (int k = 0; k < 3; k++) {
        int f = lane + 64 * k;
        float x = (float)rp[f];
        a1 += x * v1[f];
        if (o2) a2 += x * v2[f];
    }
    #pragma unroll
    for (int off = 32; off > 0; off >>= 1) {
        a1 += __shfl_down(a1, off);
        a2 += __shfl_down(a2, off);
    }
    if (lane == 0) {
        o1[row] = a1 + (bias ? bias[0] : 0.f);
        if (o2) o2[row] = a2;
    }
}

// ---------------- alpha + segment max ----------------
__global__ void edge_alpha_max(const int* __restrict__ srcp, const int* __restrict__ dstp,
                               int E_real, int Etot,
                               const float* __restrict__ as_, const float* __restrict__ ad_,
                               const float* __restrict__ ea, const float* __restrict__ ve,
                               const float* __restrict__ aloop, float slope,
                               float* __restrict__ ab, unsigned* __restrict__ mb)
{
    int i = blockIdx.x * blockDim.x + threadIdx.x;
    if (i >= Etot) return;
    int s_, d_;
    float aext = 0.f;
    if (i < E_real) {
        s_ = srcp ? srcp[i] : i;
        d_ = dstp[i];
        if (ea) {
            const float4* p = (const float4*)(ea + (size_t)i * 16);
            const float4* q = (const float4*)ve;
            float4 e0 = p[0], e1 = p[1], e2 = p[2], e3 = p[3];
            float4 w0 = q[0], w1 = q[1], w2 = q[2], w3 = q[3];
            aext = e0.x * w0.x + e0.y * w0.y + e0.z * w0.z + e0.w * w0.w
                 + e1.x * w1.x + e1.y * w1.y + e1.z * w1.z + e1.w * w1.w
                 + e2.x * w2.x + e2.y * w2.y + e2.z * w2.z + e2.w * w2.w
                 + e3.x * w3.x + e3.y * w3.y + e3.z * w3.z + e3.w * w3.w;
        }
    } else {
        s_ = d_ = i - E_real;
        aext = *aloop;
    }
    float a = as_[s_] + ad_[d_] + aext;
    a = a >= 0.f ? a : slope * a;
    ab[i] = a;
    atomicMax(&mb[d_], fmap(a));
}

// ---------------- exp(alpha - max) + segment sum ----------------
__global__ void edge_exp_sum(const int* __restrict__ dstp, int E_real, int Etot,
                             float* __restrict__ ab, const unsigned* __restrict__ mb,
                             float* __restrict__ sb)
{
    int i = blockIdx.x * blockDim.x + threadIdx.x;
    if (i >= Etot) return;
    int d_ = (i < E_real) ? dstp[i] : i - E_real;
    float m = funmap(mb[d_]);
    float e = expf(ab[i] - m);
    ab[i] = e;
    atomicAdd(&sb[d_], e);
}

// ---------------- CSR aggregate: Hout[dst] = elu(sum_e w_e*F[src_e]/sum + bias), fp32 out ----------------
__global__ __launch_bounds__(256) void csr_aggregate(const int* __restrict__ rowptr,
                                                     const int* __restrict__ csr_src,
                                                     const int* __restrict__ csr_eid,
                                                     int Ndst, int nF, int nAb,
                                                     int selfloop, int selfAb,
                                                     const float* __restrict__ ab,
                                                     const float* __restrict__ sb,
                                                     const f16* __restrict__ F,
                                                     const float* __restrict__ bias,
                                                     float* __restrict__ Hout)
{
    int node = blockIdx.x * 4 + (threadIdx.x >> 6);
    if (node >= Ndst) return;
    int lane = threadIdx.x & 63;
    int start = rowptr[node];
    int deg = rowptr[node + 1] - start;
    deg = min(max(deg, 0), 1 << 20);
    float inv = 1.f / (sb[node] + 1e-16f);

    float acc0 = 0.f, acc1 = 0.f, acc2 = 0.f;
    for (int base = 0; base < deg; base += 64) {
        int i = base + lane;
        float wv = 0.f;
        int s = 0;
        if (i < deg) {
            int pos = start + i;
            s = csr_src ? csr_src[pos] : pos;
            if ((unsigned)s >= (unsigned)nF) s = 0;
            unsigned eid = csr_eid ? (unsigned)csr_eid[pos] : (unsigned)pos;
            if (eid >= (unsigned)nAb) eid = 0;
            wv = ab[eid];
        }
        int cnt = min(64, deg - base);
        for (int j = 0; j < cnt; j++) {
            float wj = __shfl(wv, j);
            int   sj = __shfl(s, j);
            const f16* fr = F + (size_t)sj * 192;
            acc0 += wj * (float)fr[lane];
            acc1 += wj * (float)fr[lane + 64];
            acc2 += wj * (float)fr[lane + 128];
        }
    }
    if (selfloop) {
        unsigned eid = (unsigned)(selfAb + node);
        float wv = (eid < (unsigned)nAb) ? ab[eid] : 0.f;
        int s = min(node, nF - 1);
        const f16* fr = F + (size_t)s * 192;
        acc0 += wv * (float)fr[lane];
        acc1 += wv * (float)fr[lane + 64];
        acc2 += wv * (float)fr[lane + 128];
    }
    float h0 = acc0 * inv + bias[lane];
    float h1 = acc1 * inv + bias[lane + 64];
    float h2 = acc2 * inv + bias[lane + 128];
    float* orow = Hout + (size_t)node * 192;
    orow[lane]       = h0 > 0.f ? h0 : expm1f(h0);
    orow[lane + 64]  = h1 > 0.f ? h1 : expm1f(h1);
    orow[lane + 128] = h2 > 0.f ? h2 : expm1f(h2);
}

// ---------------- pool: per-graph wave sum over contiguous node range, relu, fp16 ----------------
__global__ void pool_csr(const int* __restrict__ brow, const f16* __restrict__ X,
                         f16* __restrict__ outg16, int G)
{
    int g = blockIdx.x * 4 + (threadIdx.x >> 6);
    if (g >= G) return;
    int lane = threadIdx.x & 63;
    float a0 = 0.f, a1 = 0.f, a2 = 0.f;
    int s = max(brow[g], 0);
    int e = min(brow[g + 1], NN);
    for (int n = s; n < e; n++) {
        const f16* xr = X + (size_t)n * 192;
        a0 += (float)xr[lane];
        a1 += (float)xr[lane + 64];
        a2 += (float)xr[lane + 128];
    }
    f16* o = outg16 + (size_t)g * 192;
    o[lane]       = (f16)(a0 > 0.f ? a0 : 0.f);
    o[lane + 64]  = (f16)(a1 > 0.f ? a1 : 0.f);
    o[lane + 128] = (f16)(a2 > 0.f ? a2 : 0.f);
}

// ---------------- launch ----------------
extern "C" void kernel_launch(void* const* d_in, const int* in_sizes, int n_in,
                              void* d_out, int out_size, void* d_ws, size_t ws_size,
                              hipStream_t stream)
{
    const float* x_in        = (const float*)d_in[0];
    const int*   ei          = (const int*)  d_in[1];
    const float* eattr       = (const float*)d_in[2];
    const int*   batch       = (const int*)  d_in[3];
    const float* lin1_W      = (const float*)d_in[4];
    const float* lin1_b      = (const float*)d_in[5];
    const float* conv0_W     = (const float*)d_in[6];
    const float* conv0_att_s = (const float*)d_in[7];
    const float* conv0_att_d = (const float*)d_in[8];
    const float* conv0_We    = (const float*)d_in[9];
    const float* conv0_att_e = (const float*)d_in[10];
    const float* conv0_b     = (const float*)d_in[11];
    const float* convs_W     = (const float*)d_in[12];
    const float* convs_att_s = (const float*)d_in[13];
    const float* convs_att_d = (const float*)d_in[14];
    const float* convs_b     = (const float*)d_in[15];
    const float* gru_Wih     = (const float*)d_in[16];
    const float* gru_Whh     = (const float*)d_in[17];
    const float* gru_bih     = (const float*)d_in[18];
    const float* gru_bhh     = (const float*)d_in[19];
    const float* mol_Wsrc    = (const float*)d_in[20];
    const float* mol_Wdst    = (const float*)d_in[21];
    const float* mol_att_s   = (const float*)d_in[22];
    const float* mol_att_d   = (const float*)d_in[23];
    const float* mol_b       = (const float*)d_in[24];
    const float* mgru_Wih    = (const float*)d_in[25];
    const float* mgru_Whh    = (const float*)d_in[26];
    const float* mgru_bih    = (const float*)d_in[27];
    const float* mgru_bhh    = (const float*)d_in[28];
    const float* lin2_W      = (const float*)d_in[29];
    const float* lin2_b      = (const float*)d_in[30];

    const int* src = ei;
    const int* dst = ei + EE;

    // ---- workspace layout ----
    char* base = (char*)d_ws;
    size_t off = 0;
    auto alloc = [&](size_t bytes) -> void* {
        void* p = base + off;
        off = (off + bytes + 63) & ~(size_t)63;
        return p;
    };
    f16*      w16    = (f16*)alloc((size_t)NN * HH * 2);
    float*    hbuf   = (float*)alloc((size_t)NN * HH * 4);
    f16*      x16    = (f16*)alloc((size_t)NN * HH * 2);
    f16*      xin16  = (f16*)alloc((size_t)NN * CIN * 2);
    float*    abuf   = (float*)alloc((size_t)(EE + NN) * 4);
    float*    asb    = (float*)alloc((size_t)NN * 4);
    float*    adb    = (float*)alloc((size_t)NN * 4);
    float*    sb     = (float*)alloc((size_t)NN * 4);
    unsigned* mb     = (unsigned*)alloc((size_t)NN * 4);
    float*    hg     = (float*)alloc((size_t)GG * HH * 4);
    f16*      outg16 = (f16*)alloc((size_t)GG * HH * 2);
    float*    adg    = (float*)alloc((size_t)GG * 4);
    float*    sg     = (float*)alloc((size_t)GG * 4);
    unsigned* mg     = (unsigned*)alloc((size_t)GG * 4);
    int*      degb   = (int*)alloc((size_t)NN * 4);
    int*      rowptr = (int*)alloc((size_t)(NN + 1) * 4);
    unsigned* cursor = (unsigned*)alloc((size_t)NN * 4);
    int*      csr_src = (int*)alloc((size_t)EE * 4);
    int*      csr_eid = (int*)alloc((size_t)EE * 4);
    int*      bdeg   = (int*)alloc((size_t)GG * 4);
    int*      brow   = (int*)alloc((size_t)(GG + 1) * 4);
    int*      csum   = (int*)alloc(64 * 4);
    int*      choff  = (int*)alloc(65 * 4);
    float*    ve     = (float*)alloc(64);
    float*    eapart = (float*)alloc((size_t)EA_BLOCKS * 16 * 4);
    float*    vd     = (float*)alloc(HH * 4);
    float*    aloop  = (float*)alloc(64);
    f16*      lin1W16   = (f16*)alloc((size_t)HH * CIN * 2);
    f16*      conv0W16  = (f16*)alloc((size_t)HH * HH * 2);
    f16*      convsW16  = (f16*)alloc((size_t)2 * HH * HH * 2);
    f16*      gruWih16  = (f16*)alloc((size_t)3 * H3 * HH * 2);
    f16*      gruWhh16  = (f16*)alloc((size_t)3 * H3 * HH * 2);
    f16*      molWs16   = (f16*)alloc((size_t)HH * HH * 2);
    f16*      mgruWih16 = (f16*)alloc((size_t)H3 * HH * 2);
    f16*      mgruWhh16 = (f16*)alloc((size_t)H3 * HH * 2);
    if (off > ws_size) return;

    // ---- weight + input converts ----
    cvt_f2h<<<(NN * CIN + 255) / 256, 256, 0, stream>>>(x_in, xin16, NN * CIN);
    Cvt8 cv;
    cv.s[0] = lin1_W;   cv.d[0] = lin1W16;   cv.n[0] = HH * CIN;
    cv.s[1] = conv0_W;  cv.d[1] = conv0W16;  cv.n[1] = HH * HH;
    cv.s[2] = convs_W;  cv.d[2] = convsW16;  cv.n[2] = 2 * HH * HH;
    cv.s[3] = gru_Wih;  cv.d[3] = gruWih16;  cv.n[3] = 3 * H3 * HH;
    cv.s[4] = gru_Whh;  cv.d[4] = gruWhh16;  cv.n[4] = 3 * H3 * HH;
    cv.s[5] = mol_Wsrc; cv.d[5] = molWs16;   cv.n[5] = HH * HH;
    cv.s[6] = mgru_Wih; cv.d[6] = mgruWih16; cv.n[6] = H3 * HH;
    cv.s[7] = mgru_Whh; cv.d[7] = mgruWhh16; cv.n[7] = H3 * HH;
    cvt_multi<<<dim3((3 * H3 * HH + 255) / 256, 8), 256, 0, stream>>>(cv);

    // ---- CSR build (hierarchical scan for NN; single-wave scan for GG) ----
    const int nchunks = (NN + 1023) / 1024;   // 49
    hipMemsetAsync(degb, 0, NN * sizeof(int), stream);
    hist_kernel<<<(EE + 255) / 256, 256, 0, stream>>>(dst, degb, EE, NN);
    chunk_sum<<<nchunks, 256, 0, stream>>>(degb, csum, NN);
    scan_wave<<<1, 64, 0, stream>>>(csum, choff, nullptr, nchunks);
    local_scan<<<nchunks, 256, 0, stream>>>(degb, choff, rowptr, cursor, NN, nchunks);
    scatter_kernel<<<(EE + 255) / 256, 256, 0, stream>>>(src, dst, cursor, csr_src, csr_eid, EE);
    hipMemsetAsync(bdeg, 0, GG * sizeof(int), stream);
    hist_kernel<<<(NN + 255) / 256, 256, 0, stream>>>(batch, bdeg, NN, GG);
    scan_wave<<<1, 64, 0, stream>>>(bdeg, brow, nullptr, GG);

    // ---- conv0 prep (contention-free ea mean) ----
    compose_vec<<<1, 256, 0, stream>>>(conv0_We, conv0_att_e, ve, HH, EDIM);
    ea_sum_kernel<<<EA_BLOCKS, 256, 0, stream>>>(eattr, eapart, EE);
    finalize_aloop<<<1, 64, 0, stream>>>(eapart, ve, aloop, 1.0f / EE, EA_BLOCKS);

    const dim3 gemmGrid((NN + 63) / 64, HH / 64);

    // ---- lin1 ----
    gemm_mfma<<<gemmGrid, 256, 0, stream>>>(xin16, lin1W16, lin1_b, nullptr, x16, NN, HH, CIN, 1);

    // ---- conv0 (edge feats + self loops, slope 0.2) ----
    gemm_mfma<<<gemmGrid, 256, 0, stream>>>(x16, conv0W16, nullptr, nullptr, w16, NN, HH, HH, 0);
    row_dots_h<<<(NN + 3) / 4, 256, 0, stream>>>(w16, NN, conv0_att_s, asb, conv0_att_d, adb, nullptr);
    hipMemsetAsync(mb, 0, NN * sizeof(unsigned), stream);
    edge_alpha_max<<<(EE + NN + 255) / 256, 256, 0, stream>>>(src, dst, EE, EE + NN, asb, adb,
                                                              eattr, ve, aloop, 0.2f, abuf, mb);
    hipMemsetAsync(sb, 0, NN * sizeof(float), stream);
    edge_exp_sum<<<(EE + NN + 255) / 256, 256, 0, stream>>>(dst, EE, EE + NN, abuf, mb, sb);
    csr_aggregate<<<(NN + 3) / 4, 256, 0, stream>>>(rowptr, csr_src, csr_eid, NN, NN, EE + NN,
                                                    1, EE, abuf, sb, w16, conv0_b, hbuf);
    gru_mfma<<<(NN + 15) / 16, 256, 0, stream>>>(hbuf, x16, gruWih16, gruWhh16, gru_bih, gru_bhh, NN);

    // ---- remaining atom convs (no self loops, slope 0.01) ----
    for (int l = 0; l < 2; l++) {
        gemm_mfma<<<gemmGrid, 256, 0, stream>>>(x16, convsW16 + (size_t)l * HH * HH,
                                                nullptr, nullptr, w16, NN, HH, HH, 0);
        row_dots_h<<<(NN + 3) / 4, 256, 0, stream>>>(w16, NN, convs_att_s + l * HH, asb,
                                                     convs_att_d + l * HH, adb, nullptr);
        hipMemsetAsync(mb, 0, NN * sizeof(unsigned), stream);
        edge_alpha_max<<<(EE + 255) / 256, 256, 0, stream>>>(src, dst, EE, EE, asb, adb,
                                                             nullptr, nullptr, nullptr, 0.01f, abuf, mb);
        hipMemsetAsync(sb, 0, NN * sizeof(float), stream);
        edge_exp_sum<<<(EE + 255) / 256, 256, 0, stream>>>(dst, EE, EE, abuf, mb, sb);
        csr_aggregate<<<(NN + 3) / 4, 256, 0, stream>>>(rowptr, csr_src, csr_eid, NN, NN, EE,
                                                        0, 0, abuf, sb, w16, convs_b + l * HH, hbuf);
        gru_mfma<<<(NN + 15) / 16, 256, 0, stream>>>(hbuf, x16,
                                                     gruWih16 + (size_t)(l + 1) * H3 * HH,
                                                     gruWhh16 + (size_t)(l + 1) * H3 * HH,
                                                     gru_bih + (size_t)(l + 1) * H3,
                                                     gru_bhh + (size_t)(l + 1) * H3, NN);
    }

    // ---- molecule readout ----
    pool_csr<<<(GG + 3) / 4, 256, 0, stream>>>(brow, x16, outg16, GG);
    gemm_mfma<<<gemmGrid, 256, 0, stream>>>(x16, molWs16, nullptr, nullptr, w16, NN, HH, HH, 0);
    row_dots_h<<<(NN + 3) / 4, 256, 0, stream>>>(w16, NN, mol_att_s, asb, nullptr, nullptr, nullptr);
    compose_vec<<<1, 256, 0, stream>>>(mol_Wdst, mol_att_d, vd, HH, HH);

    for (int t = 0; t < 2; t++) {
        row_dots_h<<<(GG + 3) / 4, 256, 0, stream>>>(outg16, GG, vd, adg, nullptr, nullptr, nullptr);
        hipMemsetAsync(mg, 0, GG * sizeof(unsigned), stream);
        edge_alpha_max<<<(NN + 255) / 256, 256, 0, stream>>>(nullptr, batch, NN, NN, asb, adg,
                                                             nullptr, nullptr, nullptr, 0.01f, abuf, mg);
        hipMemsetAsync(sg, 0, GG * sizeof(float), stream);
        edge_exp_sum<<<(NN + 255) / 256, 256, 0, stream>>>(batch, NN, NN, abuf, mg, sg);
        csr_aggregate<<<(GG + 3) / 4, 256, 0, stream>>>(brow, nullptr, nullptr, GG, NN, NN,
                                                        0, 0, abuf, sg, w16, mol_b, hg);
        gru_mfma<<<(GG + 15) / 16, 256, 0, stream>>>(hg, outg16, mgruWih16, mgruWhh16,
                                                     mgru_bih, mgru_bhh, GG);
    }

    // ---- final linear ----
    row_dots_h<<<(GG + 3) / 4, 256, 0, stream>>>(outg16, GG, lin2_W, (float*)d_out,
                                                 nullptr, nullptr, lin2_b);
}

// Round 8
// 1615.460 us; speedup vs baseline: 4.0461x; 1.1098x over previous
//
#include <hip/hip_runtime.h>
#include <math.h>

// ---------------- problem constants ----------------
#define NN    50000
#define EE    800000
#define CIN   64
#define HH    192
#define EDIM  16
#define GG    2048
#define H3    576   // 3*H
#define EA_BLOCKS 256

typedef _Float16 f16;
typedef _Float16 half8 __attribute__((ext_vector_type(8)));
typedef float f32x4 __attribute__((ext_vector_type(4)));

// ---------------- helpers ----------------
__device__ __forceinline__ unsigned fmap(float f) {
    unsigned u = __float_as_uint(f);
    return (u & 0x80000000u) ? ~u : (u | 0x80000000u);
}
__device__ __forceinline__ float funmap(unsigned u) {
    if (u == 0u) return 0.0f;
    return (u & 0x80000000u) ? __uint_as_float(u ^ 0x80000000u)
                             : __uint_as_float(~u);
}

// ---------------- fp32 -> fp16 converts ----------------
__global__ void cvt_f2h(const float* __restrict__ s, f16* __restrict__ d, int n)
{
    int i = blockIdx.x * blockDim.x + threadIdx.x;
    if (i < n) d[i] = (f16)s[i];
}

struct Cvt8 { const float* s[8]; f16* d[8]; int n[8]; };
__global__ void cvt_multi(Cvt8 c)
{
    int slot = blockIdx.y;
    int i = blockIdx.x * blockDim.x + threadIdx.x;
    if (i < c.n[slot]) c.d[slot][i] = (f16)c.s[slot][i];
}

// ---------------- CSR build ----------------
__global__ void hist_kernel(const int* __restrict__ idx, int* __restrict__ deg, int n, int nbins)
{
    int i = blockIdx.x * blockDim.x + threadIdx.x;
    if (i < n) {
        unsigned b = (unsigned)idx[i];
        if (b < (unsigned)nbins) atomicAdd(&deg[b], 1);
    }
}

// single-WAVE exclusive scan (serial over 64-chunks) — used only for small arrays
__global__ void scan_wave(const int* __restrict__ deg, int* __restrict__ rowptr,
                          unsigned* __restrict__ cursor, int n)
{
    int lane = threadIdx.x & 63;
    int carry = 0;
    for (int base = 0; base < n; base += 64) {
        int i = base + lane;
        int v = (i < n) ? deg[i] : 0;
        int x = v;
        #pragma unroll
        for (int off = 1; off < 64; off <<= 1) {
            int t = __shfl_up(x, off);
            if (lane >= off) x += t;
        }
        int ex = carry + x - v;
        if (i < n) {
            rowptr[i] = ex;
            if (cursor) cursor[i] = (unsigned)ex;
        }
        carry += __shfl(x, 63);
    }
    if (lane == 0) rowptr[n] = carry;
}

// hierarchical scan, level 1: per-1024-chunk sums (256 thr, 4 elems/thr)
__global__ __launch_bounds__(256) void chunk_sum(const int* __restrict__ deg,
                                                 int* __restrict__ csum, int n)
{
    int base = blockIdx.x * 1024;
    int tid = threadIdx.x;
    int i0 = base + tid * 4;
    int s = 0;
    #pragma unroll
    for (int k = 0; k < 4; k++) { int i = i0 + k; if (i < n) s += deg[i]; }
    #pragma unroll
    for (int off = 32; off > 0; off >>= 1) s += __shfl_down(s, off);
    __shared__ int ws[4];
    int lane = tid & 63, w = tid >> 6;
    if (lane == 0) ws[w] = s;
    __syncthreads();
    if (tid == 0) csum[blockIdx.x] = ws[0] + ws[1] + ws[2] + ws[3];
}

// hierarchical scan, level 3: local exclusive scan + chunk offset
__global__ __launch_bounds__(256) void local_scan(const int* __restrict__ deg,
                                                  const int* __restrict__ choff,
                                                  int* __restrict__ rowptr,
                                                  unsigned* __restrict__ cursor,
                                                  int n, int nchunks)
{
    int base = blockIdx.x * 1024;
    int tid = threadIdx.x;
    int lane = tid & 63, w = tid >> 6;
    int i0 = base + tid * 4;
    int v[4];
    #pragma unroll
    for (int k = 0; k < 4; k++) { int i = i0 + k; v[k] = (i < n) ? deg[i] : 0; }
    int tsum = v[0] + v[1] + v[2] + v[3];
    int x = tsum;
    #pragma unroll
    for (int off = 1; off < 64; off <<= 1) {
        int t = __shfl_up(x, off);
        if (lane >= off) x += t;
    }
    __shared__ int wtot[4];
    if (lane == 63) wtot[w] = x;
    __syncthreads();
    int woff = 0;
    #pragma unroll
    for (int j = 0; j < 4; j++) if (j < w) woff += wtot[j];
    int ex = choff[blockIdx.x] + woff + x - tsum;
    #pragma unroll
    for (int k = 0; k < 4; k++) {
        int i = i0 + k;
        if (i < n) {
            rowptr[i] = ex;
            if (cursor) cursor[i] = (unsigned)ex;
        }
        ex += v[k];
    }
    if (blockIdx.x == 0 && tid == 0) rowptr[n] = choff[nchunks];
}

__global__ void scatter_kernel(const int* __restrict__ src, const int* __restrict__ dst,
                               unsigned* __restrict__ cursor,
                               int* __restrict__ csr_src, int* __restrict__ csr_eid, int E)
{
    int e = blockIdx.x * blockDim.x + threadIdx.x;
    if (e >= E) return;
    unsigned d = (unsigned)dst[e];
    if (d >= (unsigned)NN) return;
    unsigned p = atomicAdd(&cursor[d], 1u);
    if (p < (unsigned)E) {
        csr_src[p] = src[e];
        csr_eid[p] = e;
    }
}

// ---------------- MFMA GEMM: C[M,N] = act(A16[M,K] @ W16[N,K]^T + bias) ----------------
__global__ __launch_bounds__(256) void gemm_mfma(const f16* __restrict__ A,
                                                 const f16* __restrict__ W,
                                                 const float* __restrict__ bias,
                                                 float* __restrict__ Cf,
                                                 f16* __restrict__ Ch,
                                                 int M, int N, int K, int act)
{
    __shared__ __align__(16) f16 sA[64 * 40];
    const int tid  = threadIdx.x;
    const int lane = tid & 63;
    const int wid  = tid >> 6;
    const int wy = wid >> 1, wx = wid & 1;
    const int m0 = blockIdx.x << 6, n0 = blockIdx.y << 6;
    const int n_ = lane & 15, quad = lane >> 4;

    f32x4 acc[2][2] = {};
    int boff0 = (n0 + wx * 32 + n_) * K + quad * 8;
    int boff1 = boff0 + 16 * K;

    const int srow = tid >> 2;
    const int skc  = (tid & 3) << 3;

    for (int k0 = 0; k0 < K; k0 += 32) {
        half8 av = {};
        int gm = m0 + srow;
        if (gm < M) av = *(const half8*)(A + (size_t)gm * K + k0 + skc);
        *(half8*)(sA + srow * 40 + skc) = av;
        __syncthreads();
        half8 a0 = *(const half8*)(sA + (wy * 32 + n_) * 40 + quad * 8);
        half8 a1 = *(const half8*)(sA + (wy * 32 + 16 + n_) * 40 + quad * 8);
        half8 b0 = *(const half8*)(W + boff0 + k0);
        half8 b1 = *(const half8*)(W + boff1 + k0);
        acc[0][0] = __builtin_amdgcn_mfma_f32_16x16x32_f16(a0, b0, acc[0][0], 0, 0, 0);
        acc[0][1] = __builtin_amdgcn_mfma_f32_16x16x32_f16(a0, b1, acc[0][1], 0, 0, 0);
        acc[1][0] = __builtin_amdgcn_mfma_f32_16x16x32_f16(a1, b0, acc[1][0], 0, 0, 0);
        acc[1][1] = __builtin_amdgcn_mfma_f32_16x16x32_f16(a1, b1, acc[1][1], 0, 0, 0);
        __syncthreads();
    }
    #pragma unroll
    for (int i = 0; i < 2; i++)
        #pragma unroll
        for (int j = 0; j < 2; j++) {
            int col = n0 + wx * 32 + j * 16 + n_;
            float bv = bias ? bias[col] : 0.f;
            #pragma unroll
            for (int reg = 0; reg < 4; reg++) {
                int row = m0 + wy * 32 + i * 16 + quad * 4 + reg;
                if (row >= M) continue;
                float v = acc[i][j][reg] + bv;
                if (act == 1) v = v >= 0.f ? v : 0.01f * v;
                if (Cf) Cf[(size_t)row * N + col] = v;
                if (Ch) Ch[(size_t)row * N + col] = (f16)v;
            }
        }
}

// ---------------- fused MFMA GRU: X16 = relu(GRU(Hf, X16)) in place, 32 rows/block ----------------
// Stage all 32x192 of h (fp32->f16) and x to LDS once; then barrier-free 6x9 tile loop.
// Wave w owns gate-cols [w*48,(w+1)*48) of all 3 gates for both gi and gh, both 16-row halves.
#define GRU_LDP 208   // LDS row pitch (halves), 416 B: 16B-aligned, breaks pow2 conflicts
__global__ __launch_bounds__(256, 2) void gru_mfma(const float* __restrict__ Hf,
                                                   f16* __restrict__ X16,
                                                   const f16* __restrict__ Wih,
                                                   const f16* __restrict__ Whh,
                                                   const float* __restrict__ bih,
                                                   const float* __restrict__ bhh,
                                                   int M)
{
    __shared__ __align__(16) f16 sH[32 * GRU_LDP];
    __shared__ __align__(16) f16 sX[32 * GRU_LDP];
    const int tid  = threadIdx.x;
    const int lane = tid & 63;
    const int w    = tid >> 6;
    const int n_ = lane & 15, quad = lane >> 4;
    const int node0 = blockIdx.x << 5;

    // ---- stage: 256 threads, each does row r=tid>>3, cols (tid&7)*24..+24 ----
    {
        const int r  = tid >> 3;
        const int cb = (tid & 7) * 24;
        const int gm = node0 + r;
        if (gm < M) {
            const float* hp = Hf + (size_t)gm * 192 + cb;
            #pragma unroll
            for (int q = 0; q < 3; q++) {
                float4 f0 = *(const float4*)(hp + q * 8);
                float4 f1 = *(const float4*)(hp + q * 8 + 4);
                half8 h;
                h[0] = (f16)f0.x; h[1] = (f16)f0.y; h[2] = (f16)f0.z; h[3] = (f16)f0.w;
                h[4] = (f16)f1.x; h[5] = (f16)f1.y; h[6] = (f16)f1.z; h[7] = (f16)f1.w;
                *(half8*)(sH + r * GRU_LDP + cb + q * 8) = h;
            }
            const f16* xp = X16 + (size_t)gm * 192 + cb;
            #pragma unroll
            for (int q = 0; q < 3; q++)
                *(half8*)(sX + r * GRU_LDP + cb + q * 8) = *(const half8*)(xp + q * 8);
        } else {
            half8 z = {};
            #pragma unroll
            for (int q = 0; q < 3; q++) {
                *(half8*)(sH + r * GRU_LDP + cb + q * 8) = z;
                *(half8*)(sX + r * GRU_LDP + cb + q * 8) = z;
            }
        }
    }
    __syncthreads();

    f32x4 aI[2][3][3] = {};
    f32x4 aH[2][3][3] = {};
    int boff[3][3];
    #pragma unroll
    for (int g = 0; g < 3; g++)
        #pragma unroll
        for (int t = 0; t < 3; t++)
            boff[g][t] = (g * 192 + w * 48 + t * 16 + n_) * 192 + quad * 8;

    // ---- main loop: no barriers ----
    #pragma unroll 1
    for (int c = 0; c < 6; c++) {
        int k0 = c * 32;
        half8 ah0 = *(const half8*)(sH + n_ * GRU_LDP + k0 + quad * 8);
        half8 ah1 = *(const half8*)(sH + (16 + n_) * GRU_LDP + k0 + quad * 8);
        half8 ax0 = *(const half8*)(sX + n_ * GRU_LDP + k0 + quad * 8);
        half8 ax1 = *(const half8*)(sX + (16 + n_) * GRU_LDP + k0 + quad * 8);
        #pragma unroll
        for (int g = 0; g < 3; g++)
            #pragma unroll
            for (int t = 0; t < 3; t++) {
                half8 bI = *(const half8*)(Wih + boff[g][t] + k0);
                half8 bH = *(const half8*)(Whh + boff[g][t] + k0);
                aI[0][g][t] = __builtin_amdgcn_mfma_f32_16x16x32_f16(ah0, bI, aI[0][g][t], 0, 0, 0);
                aI[1][g][t] = __builtin_amdgcn_mfma_f32_16x16x32_f16(ah1, bI, aI[1][g][t], 0, 0, 0);
                aH[0][g][t] = __builtin_amdgcn_mfma_f32_16x16x32_f16(ax0, bH, aH[0][g][t], 0, 0, 0);
                aH[1][g][t] = __builtin_amdgcn_mfma_f32_16x16x32_f16(ax1, bH, aH[1][g][t], 0, 0, 0);
            }
    }

    // ---- epilogue: gates in-lane, hx from staged LDS, relu, fp16 in-place write ----
    #pragma unroll
    for (int t = 0; t < 3; t++) {
        int c0 = w * 48 + t * 16 + n_;
        float bir = bih[c0], biz = bih[c0 + 192], bin = bih[c0 + 384];
        float bhr = bhh[c0], bhz = bhh[c0 + 192], bhn = bhh[c0 + 384];
        #pragma unroll
        for (int half = 0; half < 2; half++) {
            #pragma unroll
            for (int reg = 0; reg < 4; reg++) {
                int rl = half * 16 + quad * 4 + reg;
                int node = node0 + rl;
                if (node >= M) continue;
                float hx = (float)sX[rl * GRU_LDP + c0];
                float ir = aI[half][0][t][reg] + bir;
                float iz = aI[half][1][t][reg] + biz;
                float in = aI[half][2][t][reg] + bin;
                float hr = aH[half][0][t][reg] + bhr;
                float hz = aH[half][1][t][reg] + bhz;
                float hn = aH[half][2][t][reg] + bhn;
                float r  = 1.f / (1.f + expf(-(ir + hr)));
                float z  = 1.f / (1.f + expf(-(iz + hz)));
                float nn = tanhf(in + r * hn);
                float o  = (1.f - z) * nn + z * hx;
                X16[(size_t)node * 192 + c0] = (f16)(o > 0.f ? o : 0.f);
            }
        }
    }
}

// ---------------- small vector compose ----------------
__global__ void compose_vec(const float* __restrict__ W, const float* __restrict__ v,
                            float* __restrict__ out, int rows, int cols)
{
    int j = threadIdx.x;
    if (j >= cols) return;
    float acc = 0.f;
    for (int i = 0; i < rows; i++) acc += v[i] * W[(size_t)i * cols + j];
    out[j] = acc;
}

// ---------------- edge_attr column sums -> per-block partials (no atomics) ----------------
__global__ __launch_bounds__(256) void ea_sum_kernel(const float* __restrict__ ea,
                                                     float* __restrict__ partials, int E)
{
    __shared__ float ws[4][16];
    int tid = threadIdx.x;
    int lane = tid & 63, w = tid >> 6;
    float acc[16];
    #pragma unroll
    for (int f = 0; f < 16; f++) acc[f] = 0.f;
    for (int e = blockIdx.x * blockDim.x + tid; e < E; e += gridDim.x * blockDim.x) {
        const float4* p = (const float4*)(ea + (size_t)e * 16);
        float4 v0 = p[0], v1 = p[1], v2 = p[2], v3 = p[3];
        acc[0] += v0.x; acc[1] += v0.y; acc[2] += v0.z; acc[3] += v0.w;
        acc[4] += v1.x; acc[5] += v1.y; acc[6] += v1.z; acc[7] += v1.w;
        acc[8] += v2.x; acc[9] += v2.y; acc[10] += v2.z; acc[11] += v2.w;
        acc[12] += v3.x; acc[13] += v3.y; acc[14] += v3.z; acc[15] += v3.w;
    }
    #pragma unroll
    for (int off = 32; off > 0; off >>= 1)
        #pragma unroll
        for (int f = 0; f < 16; f++) acc[f] += __shfl_down(acc[f], off);
    if (lane == 0)
        #pragma unroll
        for (int f = 0; f < 16; f++) ws[w][f] = acc[f];
    __syncthreads();
    if (tid < 16)
        partials[blockIdx.x * 16 + tid] = ws[0][tid] + ws[1][tid] + ws[2][tid] + ws[3][tid];
}

// one wave: aloop = (sum over blocks of partials)·ve / E
__global__ void finalize_aloop(const float* __restrict__ partials, const float* __restrict__ ve,
                               float* __restrict__ aloop, float invE, int nblk)
{
    int lane = threadIdx.x & 63;
    float s = 0.f;
    if (lane < 16) {
        for (int b = 0; b < nblk; b += 4) {
            s += partials[b * 16 + lane]
               + partials[(b + 1) * 16 + lane]
               + partials[(b + 2) * 16 + lane]
               + partials[(b + 3) * 16 + lane];
        }
        s *= invE * ve[lane];
    }
    #pragma unroll
    for (int off = 8; off > 0; off >>= 1) s += __shfl_down(s, off);
    if (lane == 0) *aloop = s;
}

// ---------------- per-row dots on fp16 matrix (1-2 vectors) ----------------
__global__ void row_dots_h(const f16* __restrict__ Mat, int M,
                           const float* __restrict__ v1, float* __restrict__ o1,
                           const float* __restrict__ v2, float* __restrict__ o2,
                           const float* __restrict__ bias)
{
    int row = blockIdx.x * 4 + (threadIdx.x >> 6);
    if (row >= M) return;
    int lane = threadIdx.x & 63;
    const f16* rp = Mat + (size_t)row * 192;
    float a1 = 0.f, a2 = 0.f;
    #pragma unroll
    for (int k = 0; k < 3; k++) {
        int f = lane + 64 * k;
        float x = (float)rp[f];
        a1 += x * v1[f];
        if (o2) a2 += x * v2[f];
    }
    #pragma unroll
    for (int off = 32; off > 0; off >>= 1) {
        a1 += __shfl_down(a1, off);
        a2 += __shfl_down(a2, off);
    }
    if (lane == 0) {
        o1[row] = a1 + (bias ? bias[0] : 0.f);
        if (o2) o2[row] = a2;
    }
}

// ---------------- alpha + segment max ----------------
__global__ void edge_alpha_max(const int* __restrict__ srcp, const int* __restrict__ dstp,
                               int E_real, int Etot,
                               const float* __restrict__ as_, const float* __restrict__ ad_,
                               const float* __restrict__ ea, const float* __restrict__ ve,
                               const float* __restrict__ aloop, float slope,
                               float* __restrict__ ab, unsigned* __restrict__ mb)
{
    int i = blockIdx.x * blockDim.x + threadIdx.x;
    if (i >= Etot) return;
    int s_, d_;
    float aext = 0.f;
    if (i < E_real) {
        s_ = srcp ? srcp[i] : i;
        d_ = dstp[i];
        if (ea) {
            const float4* p = (const float4*)(ea + (size_t)i * 16);
            const float4* q = (const float4*)ve;
            float4 e0 = p[0], e1 = p[1], e2 = p[2], e3 = p[3];
            float4 w0 = q[0], w1 = q[1], w2 = q[2], w3 = q[3];
            aext = e0.x * w0.x + e0.y * w0.y + e0.z * w0.z + e0.w * w0.w
                 + e1.x * w1.x + e1.y * w1.y + e1.z * w1.z + e1.w * w1.w
                 + e2.x * w2.x + e2.y * w2.y + e2.z * w2.z + e2.w * w2.w
                 + e3.x * w3.x + e3.y * w3.y + e3.z * w3.z + e3.w * w3.w;
        }
    } else {
        s_ = d_ = i - E_real;
        aext = *aloop;
    }
    float a = as_[s_] + ad_[d_] + aext;
    a = a >= 0.f ? a : slope * a;
    ab[i] = a;
    atomicMax(&mb[d_], fmap(a));
}

// ---------------- exp(alpha - max) + segment sum ----------------
__global__ void edge_exp_sum(const int* __restrict__ dstp, int E_real, int Etot,
                             float* __restrict__ ab, const unsigned* __restrict__ mb,
                             float* __restrict__ sb)
{
    int i = blockIdx.x * blockDim.x + threadIdx.x;
    if (i >= Etot) return;
    int d_ = (i < E_real) ? dstp[i] : i - E_real;
    float m = funmap(mb[d_]);
    float e = expf(ab[i] - m);
    ab[i] = e;
    atomicAdd(&sb[d_], e);
}

// ---------------- CSR aggregate: Hout[dst] = elu(sum_e w_e*F[src_e]/sum + bias), fp32 out ----------------
__global__ __launch_bounds__(256) void csr_aggregate(const int* __restrict__ rowptr,
                                                     const int* __restrict__ csr_src,
                                                     const int* __restrict__ csr_eid,
                                                     int Ndst, int nF, int nAb,
                                                     int selfloop, int selfAb,
                                                     const float* __restrict__ ab,
                                                     const float* __restrict__ sb,
                                                     const f16* __restrict__ F,
                                                     const float* __restrict__ bias,
                                                     float* __restrict__ Hout)
{
    int node = blockIdx.x * 4 + (threadIdx.x >> 6);
    if (node >= Ndst) return;
    int lane = threadIdx.x & 63;
    int start = rowptr[node];
    int deg = rowptr[node + 1] - start;
    deg = min(max(deg, 0), 1 << 20);
    float inv = 1.f / (sb[node] + 1e-16f);

    float acc0 = 0.f, acc1 = 0.f, acc2 = 0.f;
    for (int base = 0; base < deg; base += 64) {
        int i = base + lane;
        float wv = 0.f;
        int s = 0;
        if (i < deg) {
            int pos = start + i;
            s = csr_src ? csr_src[pos] : pos;
            if ((unsigned)s >= (unsigned)nF) s = 0;
            unsigned eid = csr_eid ? (unsigned)csr_eid[pos] : (unsigned)pos;
            if (eid >= (unsigned)nAb) eid = 0;
            wv = ab[eid];
        }
        int cnt = min(64, deg - base);
        for (int j = 0; j < cnt; j++) {
            float wj = __shfl(wv, j);
            int   sj = __shfl(s, j);
            const f16* fr = F + (size_t)sj * 192;
            acc0 += wj * (float)fr[lane];
            acc1 += wj * (float)fr[lane + 64];
            acc2 += wj * (float)fr[lane + 128];
        }
    }
    if (selfloop) {
        unsigned eid = (unsigned)(selfAb + node);
        float wv = (eid < (unsigned)nAb) ? ab[eid] : 0.f;
        int s = min(node, nF - 1);
        const f16* fr = F + (size_t)s * 192;
        acc0 += wv * (float)fr[lane];
        acc1 += wv * (float)fr[lane + 64];
        acc2 += wv * (float)fr[lane + 128];
    }
    float h0 = acc0 * inv + bias[lane];
    float h1 = acc1 * inv + bias[lane + 64];
    float h2 = acc2 * inv + bias[lane + 128];
    float* orow = Hout + (size_t)node * 192;
    orow[lane]       = h0 > 0.f ? h0 : expm1f(h0);
    orow[lane + 64]  = h1 > 0.f ? h1 : expm1f(h1);
    orow[lane + 128] = h2 > 0.f ? h2 : expm1f(h2);
}

// ---------------- pool: per-graph wave sum over contiguous node range, relu, fp16 ----------------
__global__ void pool_csr(const int* __restrict__ brow, const f16* __restrict__ X,
                         f16* __restrict__ outg16, int G)
{
    int g = blockIdx.x * 4 + (threadIdx.x >> 6);
    if (g >= G) return;
    int lane = threadIdx.x & 63;
    float a0 = 0.f, a1 = 0.f, a2 = 0.f;
    int s = max(brow[g], 0);
    int e = min(brow[g + 1], NN);
    for (int n = s; n < e; n++) {
        const f16* xr = X + (size_t)n * 192;
        a0 += (float)xr[lane];
        a1 += (float)xr[lane + 64];
        a2 += (float)xr[lane + 128];
    }
    f16* o = outg16 + (size_t)g * 192;
    o[lane]       = (f16)(a0 > 0.f ? a0 : 0.f);
    o[lane + 64]  = (f16)(a1 > 0.f ? a1 : 0.f);
    o[lane + 128] = (f16)(a2 > 0.f ? a2 : 0.f);
}

// ---------------- launch ----------------
extern "C" void kernel_launch(void* const* d_in, const int* in_sizes, int n_in,
                              void* d_out, int out_size, void* d_ws, size_t ws_size,
                              hipStream_t stream)
{
    const float* x_in        = (const float*)d_in[0];
    const int*   ei          = (const int*)  d_in[1];
    const float* eattr       = (const float*)d_in[2];
    const int*   batch       = (const int*)  d_in[3];
    const float* lin1_W      = (const float*)d_in[4];
    const float* lin1_b      = (const float*)d_in[5];
    const float* conv0_W     = (const float*)d_in[6];
    const float* conv0_att_s = (const float*)d_in[7];
    const float* conv0_att_d = (const float*)d_in[8];
    const float* conv0_We    = (const float*)d_in[9];
    const float* conv0_att_e = (const float*)d_in[10];
    const float* conv0_b     = (const float*)d_in[11];
    const float* convs_W     = (const float*)d_in[12];
    const float* convs_att_s = (const float*)d_in[13];
    const float* convs_att_d = (const float*)d_in[14];
    const float* convs_b     = (const float*)d_in[15];
    const float* gru_Wih     = (const float*)d_in[16];
    const float* gru_Whh     = (const float*)d_in[17];
    const float* gru_bih     = (const float*)d_in[18];
    const float* gru_bhh     = (const float*)d_in[19];
    const float* mol_Wsrc    = (const float*)d_in[20];
    const float* mol_Wdst    = (const float*)d_in[21];
    const float* mol_att_s   = (const float*)d_in[22];
    const float* mol_att_d   = (const float*)d_in[23];
    const float* mol_b       = (const float*)d_in[24];
    const float* mgru_Wih    = (const float*)d_in[25];
    const float* mgru_Whh    = (const float*)d_in[26];
    const float* mgru_bih    = (const float*)d_in[27];
    const float* mgru_bhh    = (const float*)d_in[28];
    const float* lin2_W      = (const float*)d_in[29];
    const float* lin2_b      = (const float*)d_in[30];

    const int* src = ei;
    const int* dst = ei + EE;

    // ---- workspace layout ----
    char* base = (char*)d_ws;
    size_t off = 0;
    auto alloc = [&](size_t bytes) -> void* {
        void* p = base + off;
        off = (off + bytes + 63) & ~(size_t)63;
        return p;
    };
    f16*      w16    = (f16*)alloc((size_t)NN * HH * 2);
    float*    hbuf   = (float*)alloc((size_t)NN * HH * 4);
    f16*      x16    = (f16*)alloc((size_t)NN * HH * 2);
    f16*      xin16  = (f16*)alloc((size_t)NN * CIN * 2);
    float*    abuf   = (float*)alloc((size_t)(EE + NN) * 4);
    float*    asb    = (float*)alloc((size_t)NN * 4);
    float*    adb    = (float*)alloc((size_t)NN * 4);
    float*    sb     = (float*)alloc((size_t)NN * 4);
    unsigned* mb     = (unsigned*)alloc((size_t)NN * 4);
    float*    hg     = (float*)alloc((size_t)GG * HH * 4);
    f16*      outg16 = (f16*)alloc((size_t)GG * HH * 2);
    float*    adg    = (float*)alloc((size_t)GG * 4);
    float*    sg     = (float*)alloc((size_t)GG * 4);
    unsigned* mg     = (unsigned*)alloc((size_t)GG * 4);
    int*      degb   = (int*)alloc((size_t)NN * 4);
    int*      rowptr = (int*)alloc((size_t)(NN + 1) * 4);
    unsigned* cursor = (unsigned*)alloc((size_t)NN * 4);
    int*      csr_src = (int*)alloc((size_t)EE * 4);
    int*      csr_eid = (int*)alloc((size_t)EE * 4);
    int*      bdeg   = (int*)alloc((size_t)GG * 4);
    int*      brow   = (int*)alloc((size_t)(GG + 1) * 4);
    int*      csum   = (int*)alloc(64 * 4);
    int*      choff  = (int*)alloc(65 * 4);
    float*    ve     = (float*)alloc(64);
    float*    eapart = (float*)alloc((size_t)EA_BLOCKS * 16 * 4);
    float*    vd     = (float*)alloc(HH * 4);
    float*    aloop  = (float*)alloc(64);
    f16*      lin1W16   = (f16*)alloc((size_t)HH * CIN * 2);
    f16*      conv0W16  = (f16*)alloc((size_t)HH * HH * 2);
    f16*      convsW16  = (f16*)alloc((size_t)2 * HH * HH * 2);
    f16*      gruWih16  = (f16*)alloc((size_t)3 * H3 * HH * 2);
    f16*      gruWhh16  = (f16*)alloc((size_t)3 * H3 * HH * 2);
    f16*      molWs16   = (f16*)alloc((size_t)HH * HH * 2);
    f16*      mgruWih16 = (f16*)alloc((size_t)H3 * HH * 2);
    f16*      mgruWhh16 = (f16*)alloc((size_t)H3 * HH * 2);
    if (off > ws_size) return;

    // ---- weight + input converts ----
    cvt_f2h<<<(NN * CIN + 255) / 256, 256, 0, stream>>>(x_in, xin16, NN * CIN);
    Cvt8 cv;
    cv.s[0] = lin1_W;   cv.d[0] = lin1W16;   cv.n[0] = HH * CIN;
    cv.s[1] = conv0_W;  cv.d[1] = conv0W16;  cv.n[1] = HH * HH;
    cv.s[2] = convs_W;  cv.d[2] = convsW16;  cv.n[2] = 2 * HH * HH;
    cv.s[3] = gru_Wih;  cv.d[3] = gruWih16;  cv.n[3] = 3 * H3 * HH;
    cv.s[4] = gru_Whh;  cv.d[4] = gruWhh16;  cv.n[4] = 3 * H3 * HH;
    cv.s[5] = mol_Wsrc; cv.d[5] = molWs16;   cv.n[5] = HH * HH;
    cv.s[6] = mgru_Wih; cv.d[6] = mgruWih16; cv.n[6] = H3 * HH;
    cv.s[7] = mgru_Whh; cv.d[7] = mgruWhh16; cv.n[7] = H3 * HH;
    cvt_multi<<<dim3((3 * H3 * HH + 255) / 256, 8), 256, 0, stream>>>(cv);

    // ---- CSR build (hierarchical scan for NN; single-wave scan for GG) ----
    const int nchunks = (NN + 1023) / 1024;   // 49
    hipMemsetAsync(degb, 0, NN * sizeof(int), stream);
    hist_kernel<<<(EE + 255) / 256, 256, 0, stream>>>(dst, degb, EE, NN);
    chunk_sum<<<nchunks, 256, 0, stream>>>(degb, csum, NN);
    scan_wave<<<1, 64, 0, stream>>>(csum, choff, nullptr, nchunks);
    local_scan<<<nchunks, 256, 0, stream>>>(degb, choff, rowptr, cursor, NN, nchunks);
    scatter_kernel<<<(EE + 255) / 256, 256, 0, stream>>>(src, dst, cursor, csr_src, csr_eid, EE);
    hipMemsetAsync(bdeg, 0, GG * sizeof(int), stream);
    hist_kernel<<<(NN + 255) / 256, 256, 0, stream>>>(batch, bdeg, NN, GG);
    scan_wave<<<1, 64, 0, stream>>>(bdeg, brow, nullptr, GG);

    // ---- conv0 prep (contention-free ea mean) ----
    compose_vec<<<1, 256, 0, stream>>>(conv0_We, conv0_att_e, ve, HH, EDIM);
    ea_sum_kernel<<<EA_BLOCKS, 256, 0, stream>>>(eattr, eapart, EE);
    finalize_aloop<<<1, 64, 0, stream>>>(eapart, ve, aloop, 1.0f / EE, EA_BLOCKS);

    const dim3 gemmGrid((NN + 63) / 64, HH / 64);

    // ---- lin1 ----
    gemm_mfma<<<gemmGrid, 256, 0, stream>>>(xin16, lin1W16, lin1_b, nullptr, x16, NN, HH, CIN, 1);

    // ---- conv0 (edge feats + self loops, slope 0.2) ----
    gemm_mfma<<<gemmGrid, 256, 0, stream>>>(x16, conv0W16, nullptr, nullptr, w16, NN, HH, HH, 0);
    row_dots_h<<<(NN + 3) / 4, 256, 0, stream>>>(w16, NN, conv0_att_s, asb, conv0_att_d, adb, nullptr);
    hipMemsetAsync(mb, 0, NN * sizeof(unsigned), stream);
    edge_alpha_max<<<(EE + NN + 255) / 256, 256, 0, stream>>>(src, dst, EE, EE + NN, asb, adb,
                                                              eattr, ve, aloop, 0.2f, abuf, mb);
    hipMemsetAsync(sb, 0, NN * sizeof(float), stream);
    edge_exp_sum<<<(EE + NN + 255) / 256, 256, 0, stream>>>(dst, EE, EE + NN, abuf, mb, sb);
    csr_aggregate<<<(NN + 3) / 4, 256, 0, stream>>>(rowptr, csr_src, csr_eid, NN, NN, EE + NN,
                                                    1, EE, abuf, sb, w16, conv0_b, hbuf);
    gru_mfma<<<(NN + 31) / 32, 256, 0, stream>>>(hbuf, x16, gruWih16, gruWhh16, gru_bih, gru_bhh, NN);

    // ---- remaining atom convs (no self loops, slope 0.01) ----
    for (int l = 0; l < 2; l++) {
        gemm_mfma<<<gemmGrid, 256, 0, stream>>>(x16, convsW16 + (size_t)l * HH * HH,
                                                nullptr, nullptr, w16, NN, HH, HH, 0);
        row_dots_h<<<(NN + 3) / 4, 256, 0, stream>>>(w16, NN, convs_att_s + l * HH, asb,
                                                     convs_att_d + l * HH, adb, nullptr);
        hipMemsetAsync(mb, 0, NN * sizeof(unsigned), stream);
        edge_alpha_max<<<(EE + 255) / 256, 256, 0, stream>>>(src, dst, EE, EE, asb, adb,
                                                             nullptr, nullptr, nullptr, 0.01f, abuf, mb);
        hipMemsetAsync(sb, 0, NN * sizeof(float), stream);
        edge_exp_sum<<<(EE + 255) / 256, 256, 0, stream>>>(dst, EE, EE, abuf, mb, sb);
        csr_aggregate<<<(NN + 3) / 4, 256, 0, stream>>>(rowptr, csr_src, csr_eid, NN, NN, EE,
                                                        0, 0, abuf, sb, w16, convs_b + l * HH, hbuf);
        gru_mfma<<<(NN + 31) / 32, 256, 0, stream>>>(hbuf, x16,
                                                     gruWih16 + (size_t)(l + 1) * H3 * HH,
                                                     gruWhh16 + (size_t)(l + 1) * H3 * HH,
                                                     gru_bih + (size_t)(l + 1) * H3,
                                                     gru_bhh + (size_t)(l + 1) * H3, NN);
    }

    // ---- molecule readout ----
    pool_csr<<<(GG + 3) / 4, 256, 0, stream>>>(brow, x16, outg16, GG);
    gemm_mfma<<<gemmGrid, 256, 0, stream>>>(x16, molWs16, nullptr, nullptr, w16, NN, HH, HH, 0);
    row_dots_h<<<(NN + 3) / 4, 256, 0, stream>>>(w16, NN, mol_att_s, asb, nullptr, nullptr, nullptr);
    compose_vec<<<1, 256, 0, stream>>>(mol_Wdst, mol_att_d, vd, HH, HH);

    // mol GRU inputs are fp32 hg; mol phase reuses gru via hg (fp32)
    for (int t = 0; t < 2; t++) {
        row_dots_h<<<(GG + 3) / 4, 256, 0, stream>>>(outg16, GG, vd, adg, nullptr, nullptr, nullptr);
        hipMemsetAsync(mg, 0, GG * sizeof(unsigned), stream);
        edge_alpha_max<<<(NN + 255) / 256, 256, 0, stream>>>(nullptr, batch, NN, NN, asb, adg,
                                                             nullptr, nullptr, nullptr, 0.01f, abuf, mg);
        hipMemsetAsync(sg, 0, GG * sizeof(float), stream);
        edge_exp_sum<<<(NN + 255) / 256, 256, 0, stream>>>(batch, NN, NN, abuf, mg, sg);
        csr_aggregate<<<(GG + 3) / 4, 256, 0, stream>>>(brow, nullptr, nullptr, GG, NN, NN,
                                                        0, 0, abuf, sg, w16, mol_b, hg);
        gru_mfma<<<(GG + 31) / 32, 256, 0, stream>>>(hg, outg16, mgruWih16, mgruWhh16,
                                                     mgru_bih, mgru_bhh, GG);
    }

    // ---- final linear ----
    row_dots_h<<<(GG + 3) / 4, 256, 0, stream>>>(outg16, GG, lin2_W, (float*)d_out,
                                                 nullptr, nullptr, lin2_b);
}

// Round 9
// 1566.846 us; speedup vs baseline: 4.1716x; 1.0310x over previous
//
#include <hip/hip_runtime.h>
#include <math.h>

// ---------------- problem constants ----------------
#define NN    50000
#define EE    800000
#define CIN   64
#define HH    192
#define EDIM  16
#define GG    2048
#define H3    576   // 3*H
#define EA_BLOCKS 256

typedef _Float16 f16;
typedef _Float16 half8 __attribute__((ext_vector_type(8)));
typedef float f32x4 __attribute__((ext_vector_type(4)));

// ---------------- helpers ----------------
__device__ __forceinline__ unsigned fmap(float f) {
    unsigned u = __float_as_uint(f);
    return (u & 0x80000000u) ? ~u : (u | 0x80000000u);
}
__device__ __forceinline__ float funmap(unsigned u) {
    if (u == 0u) return 0.0f;
    return (u & 0x80000000u) ? __uint_as_float(u ^ 0x80000000u)
                             : __uint_as_float(~u);
}

// ---------------- fp32 -> fp16 converts ----------------
__global__ void cvt_f2h(const float* __restrict__ s, f16* __restrict__ d, int n)
{
    int i = blockIdx.x * blockDim.x + threadIdx.x;
    if (i < n) d[i] = (f16)s[i];
}

struct Cvt8 { const float* s[8]; f16* d[8]; int n[8]; };
__global__ void cvt_multi(Cvt8 c)
{
    int slot = blockIdx.y;
    int i = blockIdx.x * blockDim.x + threadIdx.x;
    if (i < c.n[slot]) c.d[slot][i] = (f16)c.s[slot][i];
}

// ---------------- CSR build ----------------
__global__ void hist_kernel(const int* __restrict__ idx, int* __restrict__ deg, int n, int nbins)
{
    int i = blockIdx.x * blockDim.x + threadIdx.x;
    if (i < n) {
        unsigned b = (unsigned)idx[i];
        if (b < (unsigned)nbins) atomicAdd(&deg[b], 1);
    }
}

// single-WAVE exclusive scan (serial over 64-chunks) — used only for small arrays
__global__ void scan_wave(const int* __restrict__ deg, int* __restrict__ rowptr,
                          unsigned* __restrict__ cursor, int n)
{
    int lane = threadIdx.x & 63;
    int carry = 0;
    for (int base = 0; base < n; base += 64) {
        int i = base + lane;
        int v = (i < n) ? deg[i] : 0;
        int x = v;
        #pragma unroll
        for (int off = 1; off < 64; off <<= 1) {
            int t = __shfl_up(x, off);
            if (lane >= off) x += t;
        }
        int ex = carry + x - v;
        if (i < n) {
            rowptr[i] = ex;
            if (cursor) cursor[i] = (unsigned)ex;
        }
        carry += __shfl(x, 63);
    }
    if (lane == 0) rowptr[n] = carry;
}

// hierarchical scan, level 1: per-1024-chunk sums (256 thr, 4 elems/thr)
__global__ __launch_bounds__(256) void chunk_sum(const int* __restrict__ deg,
                                                 int* __restrict__ csum, int n)
{
    int base = blockIdx.x * 1024;
    int tid = threadIdx.x;
    int i0 = base + tid * 4;
    int s = 0;
    #pragma unroll
    for (int k = 0; k < 4; k++) { int i = i0 + k; if (i < n) s += deg[i]; }
    #pragma unroll
    for (int off = 32; off > 0; off >>= 1) s += __shfl_down(s, off);
    __shared__ int ws[4];
    int lane = tid & 63, w = tid >> 6;
    if (lane == 0) ws[w] = s;
    __syncthreads();
    if (tid == 0) csum[blockIdx.x] = ws[0] + ws[1] + ws[2] + ws[3];
}

// hierarchical scan, level 3: local exclusive scan + chunk offset
__global__ __launch_bounds__(256) void local_scan(const int* __restrict__ deg,
                                                  const int* __restrict__ choff,
                                                  int* __restrict__ rowptr,
                                                  unsigned* __restrict__ cursor,
                                                  int n, int nchunks)
{
    int base = blockIdx.x * 1024;
    int tid = threadIdx.x;
    int lane = tid & 63, w = tid >> 6;
    int i0 = base + tid * 4;
    int v[4];
    #pragma unroll
    for (int k = 0; k < 4; k++) { int i = i0 + k; v[k] = (i < n) ? deg[i] : 0; }
    int tsum = v[0] + v[1] + v[2] + v[3];
    int x = tsum;
    #pragma unroll
    for (int off = 1; off < 64; off <<= 1) {
        int t = __shfl_up(x, off);
        if (lane >= off) x += t;
    }
    __shared__ int wtot[4];
    if (lane == 63) wtot[w] = x;
    __syncthreads();
    int woff = 0;
    #pragma unroll
    for (int j = 0; j < 4; j++) if (j < w) woff += wtot[j];
    int ex = choff[blockIdx.x] + woff + x - tsum;
    #pragma unroll
    for (int k = 0; k < 4; k++) {
        int i = i0 + k;
        if (i < n) {
            rowptr[i] = ex;
            if (cursor) cursor[i] = (unsigned)ex;
        }
        ex += v[k];
    }
    if (blockIdx.x == 0 && tid == 0) rowptr[n] = choff[nchunks];
}

__global__ void scatter_kernel(const int* __restrict__ src, const int* __restrict__ dst,
                               unsigned* __restrict__ cursor,
                               int* __restrict__ csr_src, int* __restrict__ csr_eid, int E)
{
    int e = blockIdx.x * blockDim.x + threadIdx.x;
    if (e >= E) return;
    unsigned d = (unsigned)dst[e];
    if (d >= (unsigned)NN) return;
    unsigned p = atomicAdd(&cursor[d], 1u);
    if (p < (unsigned)E) {
        csr_src[p] = src[e];
        csr_eid[p] = e;
    }
}

// ---------------- MFMA GEMM: C[M,N] = act(A16[M,K] @ W16[N,K]^T + bias) ----------------
__global__ __launch_bounds__(256) void gemm_mfma(const f16* __restrict__ A,
                                                 const f16* __restrict__ W,
                                                 const float* __restrict__ bias,
                                                 float* __restrict__ Cf,
                                                 f16* __restrict__ Ch,
                                                 int M, int N, int K, int act)
{
    __shared__ __align__(16) f16 sA[64 * 40];
    const int tid  = threadIdx.x;
    const int lane = tid & 63;
    const int wid  = tid >> 6;
    const int wy = wid >> 1, wx = wid & 1;
    const int m0 = blockIdx.x << 6, n0 = blockIdx.y << 6;
    const int n_ = lane & 15, quad = lane >> 4;

    f32x4 acc[2][2] = {};
    int boff0 = (n0 + wx * 32 + n_) * K + quad * 8;
    int boff1 = boff0 + 16 * K;

    const int srow = tid >> 2;
    const int skc  = (tid & 3) << 3;

    for (int k0 = 0; k0 < K; k0 += 32) {
        half8 av = {};
        int gm = m0 + srow;
        if (gm < M) av = *(const half8*)(A + (size_t)gm * K + k0 + skc);
        *(half8*)(sA + srow * 40 + skc) = av;
        __syncthreads();
        half8 a0 = *(const half8*)(sA + (wy * 32 + n_) * 40 + quad * 8);
        half8 a1 = *(const half8*)(sA + (wy * 32 + 16 + n_) * 40 + quad * 8);
        half8 b0 = *(const half8*)(W + boff0 + k0);
        half8 b1 = *(const half8*)(W + boff1 + k0);
        acc[0][0] = __builtin_amdgcn_mfma_f32_16x16x32_f16(a0, b0, acc[0][0], 0, 0, 0);
        acc[0][1] = __builtin_amdgcn_mfma_f32_16x16x32_f16(a0, b1, acc[0][1], 0, 0, 0);
        acc[1][0] = __builtin_amdgcn_mfma_f32_16x16x32_f16(a1, b0, acc[1][0], 0, 0, 0);
        acc[1][1] = __builtin_amdgcn_mfma_f32_16x16x32_f16(a1, b1, acc[1][1], 0, 0, 0);
        __syncthreads();
    }
    #pragma unroll
    for (int i = 0; i < 2; i++)
        #pragma unroll
        for (int j = 0; j < 2; j++) {
            int col = n0 + wx * 32 + j * 16 + n_;
            float bv = bias ? bias[col] : 0.f;
            #pragma unroll
            for (int reg = 0; reg < 4; reg++) {
                int row = m0 + wy * 32 + i * 16 + quad * 4 + reg;
                if (row >= M) continue;
                float v = acc[i][j][reg] + bv;
                if (act == 1) v = v >= 0.f ? v : 0.01f * v;
                if (Cf) Cf[(size_t)row * N + col] = v;
                if (Ch) Ch[(size_t)row * N + col] = (f16)v;
            }
        }
}

// ---------------- fused MFMA GRU: X16 = relu(GRU(H16, X16)) in place, 32 rows/block ----------------
// Merged r/z accumulators (gi+gh summed by MFMA) -> 24 f32x4 accs; n gate kept separate.
// Stage all 32x192 of h and x to LDS once; barrier-free 6-chunk main loop.
#define GRU_LDP 208   // LDS row pitch (halves), 416 B: 16B-aligned, breaks pow2 conflicts
__global__ __launch_bounds__(256, 2) void gru_mfma(const f16* __restrict__ H16,
                                                   f16* __restrict__ X16,
                                                   const f16* __restrict__ Wih,
                                                   const f16* __restrict__ Whh,
                                                   const float* __restrict__ bih,
                                                   const float* __restrict__ bhh,
                                                   int M)
{
    __shared__ __align__(16) f16 sH[32 * GRU_LDP];
    __shared__ __align__(16) f16 sX[32 * GRU_LDP];
    const int tid  = threadIdx.x;
    const int lane = tid & 63;
    const int w    = tid >> 6;
    const int n_ = lane & 15, quad = lane >> 4;
    const int node0 = blockIdx.x << 5;

    // ---- stage: 256 threads, each does row r=tid>>3, cols (tid&7)*24..+24 ----
    {
        const int r  = tid >> 3;
        const int cb = (tid & 7) * 24;
        const int gm = node0 + r;
        if (gm < M) {
            const f16* hp = H16 + (size_t)gm * 192 + cb;
            const f16* xp = X16 + (size_t)gm * 192 + cb;
            #pragma unroll
            for (int q = 0; q < 3; q++) {
                *(half8*)(sH + r * GRU_LDP + cb + q * 8) = *(const half8*)(hp + q * 8);
                *(half8*)(sX + r * GRU_LDP + cb + q * 8) = *(const half8*)(xp + q * 8);
            }
        } else {
            half8 z = {};
            #pragma unroll
            for (int q = 0; q < 3; q++) {
                *(half8*)(sH + r * GRU_LDP + cb + q * 8) = z;
                *(half8*)(sX + r * GRU_LDP + cb + q * 8) = z;
            }
        }
    }
    __syncthreads();

    f32x4 aRZ[2][2][3] = {};   // [row-half][gate r/z][tile]  (gi+gh merged)
    f32x4 aIN[2][3] = {};      // n gate, gi part
    f32x4 aHN[2][3] = {};      // n gate, gh part
    int boff[3][3];
    #pragma unroll
    for (int g = 0; g < 3; g++)
        #pragma unroll
        for (int t = 0; t < 3; t++)
            boff[g][t] = (g * 192 + w * 48 + t * 16 + n_) * 192 + quad * 8;

    // ---- main loop: no barriers ----
    #pragma unroll 1
    for (int c = 0; c < 6; c++) {
        int k0 = c * 32;
        half8 ah0 = *(const half8*)(sH + n_ * GRU_LDP + k0 + quad * 8);
        half8 ah1 = *(const half8*)(sH + (16 + n_) * GRU_LDP + k0 + quad * 8);
        half8 ax0 = *(const half8*)(sX + n_ * GRU_LDP + k0 + quad * 8);
        half8 ax1 = *(const half8*)(sX + (16 + n_) * GRU_LDP + k0 + quad * 8);
        // r,z gates: both operands accumulate into the same acc
        #pragma unroll
        for (int g = 0; g < 2; g++)
            #pragma unroll
            for (int t = 0; t < 3; t++) {
                half8 bI = *(const half8*)(Wih + boff[g][t] + k0);
                half8 bH = *(const half8*)(Whh + boff[g][t] + k0);
                aRZ[0][g][t] = __builtin_amdgcn_mfma_f32_16x16x32_f16(ah0, bI, aRZ[0][g][t], 0, 0, 0);
                aRZ[1][g][t] = __builtin_amdgcn_mfma_f32_16x16x32_f16(ah1, bI, aRZ[1][g][t], 0, 0, 0);
                aRZ[0][g][t] = __builtin_amdgcn_mfma_f32_16x16x32_f16(ax0, bH, aRZ[0][g][t], 0, 0, 0);
                aRZ[1][g][t] = __builtin_amdgcn_mfma_f32_16x16x32_f16(ax1, bH, aRZ[1][g][t], 0, 0, 0);
            }
        // n gate: gi and gh kept separate
        #pragma unroll
        for (int t = 0; t < 3; t++) {
            half8 bI = *(const half8*)(Wih + boff[2][t] + k0);
            half8 bH = *(const half8*)(Whh + boff[2][t] + k0);
            aIN[0][t] = __builtin_amdgcn_mfma_f32_16x16x32_f16(ah0, bI, aIN[0][t], 0, 0, 0);
            aIN[1][t] = __builtin_amdgcn_mfma_f32_16x16x32_f16(ah1, bI, aIN[1][t], 0, 0, 0);
            aHN[0][t] = __builtin_amdgcn_mfma_f32_16x16x32_f16(ax0, bH, aHN[0][t], 0, 0, 0);
            aHN[1][t] = __builtin_amdgcn_mfma_f32_16x16x32_f16(ax1, bH, aHN[1][t], 0, 0, 0);
        }
    }

    // ---- epilogue: gates in-lane, hx from staged LDS, relu, fp16 in-place write ----
    #pragma unroll
    for (int t = 0; t < 3; t++) {
        int c0 = w * 48 + t * 16 + n_;
        float brz = bih[c0] + bhh[c0];
        float bzz = bih[c0 + 192] + bhh[c0 + 192];
        float bin = bih[c0 + 384], bhn = bhh[c0 + 384];
        #pragma unroll
        for (int half = 0; half < 2; half++) {
            #pragma unroll
            for (int reg = 0; reg < 4; reg++) {
                int rl = half * 16 + quad * 4 + reg;
                int node = node0 + rl;
                if (node >= M) continue;
                float hx = (float)sX[rl * GRU_LDP + c0];
                float r  = 1.f / (1.f + expf(-(aRZ[half][0][t][reg] + brz)));
                float z  = 1.f / (1.f + expf(-(aRZ[half][1][t][reg] + bzz)));
                float nn = tanhf(aIN[half][t][reg] + bin + r * (aHN[half][t][reg] + bhn));
                float o  = (1.f - z) * nn + z * hx;
                X16[(size_t)node * 192 + c0] = (f16)(o > 0.f ? o : 0.f);
            }
        }
    }
}

// ---------------- small vector compose ----------------
__global__ void compose_vec(const float* __restrict__ W, const float* __restrict__ v,
                            float* __restrict__ out, int rows, int cols)
{
    int j = threadIdx.x;
    if (j >= cols) return;
    float acc = 0.f;
    for (int i = 0; i < rows; i++) acc += v[i] * W[(size_t)i * cols + j];
    out[j] = acc;
}

// ---------------- edge_attr column sums -> per-block partials (no atomics) ----------------
__global__ __launch_bounds__(256) void ea_sum_kernel(const float* __restrict__ ea,
                                                     float* __restrict__ partials, int E)
{
    __shared__ float ws[4][16];
    int tid = threadIdx.x;
    int lane = tid & 63, w = tid >> 6;
    float acc[16];
    #pragma unroll
    for (int f = 0; f < 16; f++) acc[f] = 0.f;
    for (int e = blockIdx.x * blockDim.x + tid; e < E; e += gridDim.x * blockDim.x) {
        const float4* p = (const float4*)(ea + (size_t)e * 16);
        float4 v0 = p[0], v1 = p[1], v2 = p[2], v3 = p[3];
        acc[0] += v0.x; acc[1] += v0.y; acc[2] += v0.z; acc[3] += v0.w;
        acc[4] += v1.x; acc[5] += v1.y; acc[6] += v1.z; acc[7] += v1.w;
        acc[8] += v2.x; acc[9] += v2.y; acc[10] += v2.z; acc[11] += v2.w;
        acc[12] += v3.x; acc[13] += v3.y; acc[14] += v3.z; acc[15] += v3.w;
    }
    #pragma unroll
    for (int off = 32; off > 0; off >>= 1)
        #pragma unroll
        for (int f = 0; f < 16; f++) acc[f] += __shfl_down(acc[f], off);
    if (lane == 0)
        #pragma unroll
        for (int f = 0; f < 16; f++) ws[w][f] = acc[f];
    __syncthreads();
    if (tid < 16)
        partials[blockIdx.x * 16 + tid] = ws[0][tid] + ws[1][tid] + ws[2][tid] + ws[3][tid];
}

// one wave: aloop = (sum over blocks of partials)·ve / E
__global__ void finalize_aloop(const float* __restrict__ partials, const float* __restrict__ ve,
                               float* __restrict__ aloop, float invE, int nblk)
{
    int lane = threadIdx.x & 63;
    float s = 0.f;
    if (lane < 16) {
        for (int b = 0; b < nblk; b += 4) {
            s += partials[b * 16 + lane]
               + partials[(b + 1) * 16 + lane]
               + partials[(b + 2) * 16 + lane]
               + partials[(b + 3) * 16 + lane];
        }
        s *= invE * ve[lane];
    }
    #pragma unroll
    for (int off = 8; off > 0; off >>= 1) s += __shfl_down(s, off);
    if (lane == 0) *aloop = s;
}

// ---------------- per-row dots on fp16 matrix (1-2 vectors) ----------------
__global__ void row_dots_h(const f16* __restrict__ Mat, int M,
                           const float* __restrict__ v1, float* __restrict__ o1,
                           const float* __restrict__ v2, float* __restrict__ o2,
                           const float* __restrict__ bias)
{
    int row = blockIdx.x * 4 + (threadIdx.x >> 6);
    if (row >= M) return;
    int lane = threadIdx.x & 63;
    const f16* rp = Mat + (size_t)row * 192;
    float a1 = 0.f, a2 = 0.f;
    #pragma unroll
    for (int k = 0; k < 3; k++) {
        int f = lane + 64 * k;
        float x = (float)rp[f];
        a1 += x * v1[f];
        if (o2) a2 += x * v2[f];
    }
    #pragma unroll
    for (int off = 32; off > 0; off >>= 1) {
        a1 += __shfl_down(a1, off);
        a2 += __shfl_down(a2, off);
    }
    if (lane == 0) {
        o1[row] = a1 + (bias ? bias[0] : 0.f);
        if (o2) o2[row] = a2;
    }
}

// ---------------- alpha + segment max ----------------
__global__ void edge_alpha_max(const int* __restrict__ srcp, const int* __restrict__ dstp,
                               int E_real, int Etot,
                               const float* __restrict__ as_, const float* __restrict__ ad_,
                               const float* __restrict__ ea, const float* __restrict__ ve,
                               const float* __restrict__ aloop, float slope,
                               float* __restrict__ ab, unsigned* __restrict__ mb)
{
    int i = blockIdx.x * blockDim.x + threadIdx.x;
    if (i >= Etot) return;
    int s_, d_;
    float aext = 0.f;
    if (i < E_real) {
        s_ = srcp ? srcp[i] : i;
        d_ = dstp[i];
        if (ea) {
            const float4* p = (const float4*)(ea + (size_t)i * 16);
            const float4* q = (const float4*)ve;
            float4 e0 = p[0], e1 = p[1], e2 = p[2], e3 = p[3];
            float4 w0 = q[0], w1 = q[1], w2 = q[2], w3 = q[3];
            aext = e0.x * w0.x + e0.y * w0.y + e0.z * w0.z + e0.w * w0.w
                 + e1.x * w1.x + e1.y * w1.y + e1.z * w1.z + e1.w * w1.w
                 + e2.x * w2.x + e2.y * w2.y + e2.z * w2.z + e2.w * w2.w
                 + e3.x * w3.x + e3.y * w3.y + e3.z * w3.z + e3.w * w3.w;
        }
    } else {
        s_ = d_ = i - E_real;
        aext = *aloop;
    }
    float a = as_[s_] + ad_[d_] + aext;
    a = a >= 0.f ? a : slope * a;
    ab[i] = a;
    atomicMax(&mb[d_], fmap(a));
}

// ---------------- exp(alpha - max) + segment sum ----------------
__global__ void edge_exp_sum(const int* __restrict__ dstp, int E_real, int Etot,
                             float* __restrict__ ab, const unsigned* __restrict__ mb,
                             float* __restrict__ sb)
{
    int i = blockIdx.x * blockDim.x + threadIdx.x;
    if (i >= Etot) return;
    int d_ = (i < E_real) ? dstp[i] : i - E_real;
    float m = funmap(mb[d_]);
    float e = expf(ab[i] - m);
    ab[i] = e;
    atomicAdd(&sb[d_], e);
}

// ---------------- CSR aggregate: Hout16[dst] = elu(sum_e w_e*F[src_e]/sum + bias), fp16 out ----------------
__global__ __launch_bounds__(256) void csr_aggregate(const int* __restrict__ rowptr,
                                                     const int* __restrict__ csr_src,
                                                     const int* __restrict__ csr_eid,
                                                     int Ndst, int nF, int nAb,
                                                     int selfloop, int selfAb,
                                                     const float* __restrict__ ab,
                                                     const float* __restrict__ sb,
                                                     const f16* __restrict__ F,
                                                     const float* __restrict__ bias,
                                                     f16* __restrict__ Hout16)
{
    int node = blockIdx.x * 4 + (threadIdx.x >> 6);
    if (node >= Ndst) return;
    int lane = threadIdx.x & 63;
    int start = rowptr[node];
    int deg = rowptr[node + 1] - start;
    deg = min(max(deg, 0), 1 << 20);
    float inv = 1.f / (sb[node] + 1e-16f);

    float acc0 = 0.f, acc1 = 0.f, acc2 = 0.f;
    for (int base = 0; base < deg; base += 64) {
        int i = base + lane;
        float wv = 0.f;
        int s = 0;
        if (i < deg) {
            int pos = start + i;
            s = csr_src ? csr_src[pos] : pos;
            if ((unsigned)s >= (unsigned)nF) s = 0;
            unsigned eid = csr_eid ? (unsigned)csr_eid[pos] : (unsigned)pos;
            if (eid >= (unsigned)nAb) eid = 0;
            wv = ab[eid];
        }
        int cnt = min(64, deg - base);
        for (int j = 0; j < cnt; j++) {
            float wj = __shfl(wv, j);
            int   sj = __shfl(s, j);
            const f16* fr = F + (size_t)sj * 192;
            acc0 += wj * (float)fr[lane];
            acc1 += wj * (float)fr[lane + 64];
            acc2 += wj * (float)fr[lane + 128];
        }
    }
    if (selfloop) {
        unsigned eid = (unsigned)(selfAb + node);
        float wv = (eid < (unsigned)nAb) ? ab[eid] : 0.f;
        int s = min(node, nF - 1);
        const f16* fr = F + (size_t)s * 192;
        acc0 += wv * (float)fr[lane];
        acc1 += wv * (float)fr[lane + 64];
        acc2 += wv * (float)fr[lane + 128];
    }
    float h0 = acc0 * inv + bias[lane];
    float h1 = acc1 * inv + bias[lane + 64];
    float h2 = acc2 * inv + bias[lane + 128];
    f16* orow = Hout16 + (size_t)node * 192;
    orow[lane]       = (f16)(h0 > 0.f ? h0 : expm1f(h0));
    orow[lane + 64]  = (f16)(h1 > 0.f ? h1 : expm1f(h1));
    orow[lane + 128] = (f16)(h2 > 0.f ? h2 : expm1f(h2));
}

// ---------------- pool: per-graph wave sum over contiguous node range, relu, fp16 ----------------
__global__ void pool_csr(const int* __restrict__ brow, const f16* __restrict__ X,
                         f16* __restrict__ outg16, int G)
{
    int g = blockIdx.x * 4 + (threadIdx.x >> 6);
    if (g >= G) return;
    int lane = threadIdx.x & 63;
    float a0 = 0.f, a1 = 0.f, a2 = 0.f;
    int s = max(brow[g], 0);
    int e = min(brow[g + 1], NN);
    for (int n = s; n < e; n++) {
        const f16* xr = X + (size_t)n * 192;
        a0 += (float)xr[lane];
        a1 += (float)xr[lane + 64];
        a2 += (float)xr[lane + 128];
    }
    f16* o = outg16 + (size_t)g * 192;
    o[lane]       = (f16)(a0 > 0.f ? a0 : 0.f);
    o[lane + 64]  = (f16)(a1 > 0.f ? a1 : 0.f);
    o[lane + 128] = (f16)(a2 > 0.f ? a2 : 0.f);
}

// ---------------- launch ----------------
extern "C" void kernel_launch(void* const* d_in, const int* in_sizes, int n_in,
                              void* d_out, int out_size, void* d_ws, size_t ws_size,
                              hipStream_t stream)
{
    const float* x_in        = (const float*)d_in[0];
    const int*   ei          = (const int*)  d_in[1];
    const float* eattr       = (const float*)d_in[2];
    const int*   batch       = (const int*)  d_in[3];
    const float* lin1_W      = (const float*)d_in[4];
    const float* lin1_b      = (const float*)d_in[5];
    const float* conv0_W     = (const float*)d_in[6];
    const float* conv0_att_s = (const float*)d_in[7];
    const float* conv0_att_d = (const float*)d_in[8];
    const float* conv0_We    = (const float*)d_in[9];
    const float* conv0_att_e = (const float*)d_in[10];
    const float* conv0_b     = (const float*)d_in[11];
    const float* convs_W     = (const float*)d_in[12];
    const float* convs_att_s = (const float*)d_in[13];
    const float* convs_att_d = (const float*)d_in[14];
    const float* convs_b     = (const float*)d_in[15];
    const float* gru_Wih     = (const float*)d_in[16];
    const float* gru_Whh     = (const float*)d_in[17];
    const float* gru_bih     = (const float*)d_in[18];
    const float* gru_bhh     = (const float*)d_in[19];
    const float* mol_Wsrc    = (const float*)d_in[20];
    const float* mol_Wdst    = (const float*)d_in[21];
    const float* mol_att_s   = (const float*)d_in[22];
    const float* mol_att_d   = (const float*)d_in[23];
    const float* mol_b       = (const float*)d_in[24];
    const float* mgru_Wih    = (const float*)d_in[25];
    const float* mgru_Whh    = (const float*)d_in[26];
    const float* mgru_bih    = (const float*)d_in[27];
    const float* mgru_bhh    = (const float*)d_in[28];
    const float* lin2_W      = (const float*)d_in[29];
    const float* lin2_b      = (const float*)d_in[30];

    const int* src = ei;
    const int* dst = ei + EE;

    // ---- workspace layout ----
    char* base = (char*)d_ws;
    size_t off = 0;
    auto alloc = [&](size_t bytes) -> void* {
        void* p = base + off;
        off = (off + bytes + 63) & ~(size_t)63;
        return p;
    };
    f16*      w16    = (f16*)alloc((size_t)NN * HH * 2);
    f16*      h16    = (f16*)alloc((size_t)NN * HH * 2);
    f16*      x16    = (f16*)alloc((size_t)NN * HH * 2);
    f16*      xin16  = (f16*)alloc((size_t)NN * CIN * 2);
    float*    abuf   = (float*)alloc((size_t)(EE + NN) * 4);
    float*    asb    = (float*)alloc((size_t)NN * 4);
    float*    adb    = (float*)alloc((size_t)NN * 4);
    float*    sb     = (float*)alloc((size_t)NN * 4);
    unsigned* mb     = (unsigned*)alloc((size_t)NN * 4);
    f16*      hg16   = (f16*)alloc((size_t)GG * HH * 2);
    f16*      outg16 = (f16*)alloc((size_t)GG * HH * 2);
    float*    adg    = (float*)alloc((size_t)GG * 4);
    float*    sg     = (float*)alloc((size_t)GG * 4);
    unsigned* mg     = (unsigned*)alloc((size_t)GG * 4);
    int*      degb   = (int*)alloc((size_t)NN * 4);
    int*      rowptr = (int*)alloc((size_t)(NN + 1) * 4);
    unsigned* cursor = (unsigned*)alloc((size_t)NN * 4);
    int*      csr_src = (int*)alloc((size_t)EE * 4);
    int*      csr_eid = (int*)alloc((size_t)EE * 4);
    int*      bdeg   = (int*)alloc((size_t)GG * 4);
    int*      brow   = (int*)alloc((size_t)(GG + 1) * 4);
    int*      csum   = (int*)alloc(64 * 4);
    int*      choff  = (int*)alloc(65 * 4);
    float*    ve     = (float*)alloc(64);
    float*    eapart = (float*)alloc((size_t)EA_BLOCKS * 16 * 4);
    float*    vd     = (float*)alloc(HH * 4);
    float*    aloop  = (float*)alloc(64);
    f16*      lin1W16   = (f16*)alloc((size_t)HH * CIN * 2);
    f16*      conv0W16  = (f16*)alloc((size_t)HH * HH * 2);
    f16*      convsW16  = (f16*)alloc((size_t)2 * HH * HH * 2);
    f16*      gruWih16  = (f16*)alloc((size_t)3 * H3 * HH * 2);
    f16*      gruWhh16  = (f16*)alloc((size_t)3 * H3 * HH * 2);
    f16*      molWs16   = (f16*)alloc((size_t)HH * HH * 2);
    f16*      mgruWih16 = (f16*)alloc((size_t)H3 * HH * 2);
    f16*      mgruWhh16 = (f16*)alloc((size_t)H3 * HH * 2);
    if (off > ws_size) return;

    // ---- weight + input converts ----
    cvt_f2h<<<(NN * CIN + 255) / 256, 256, 0, stream>>>(x_in, xin16, NN * CIN);
    Cvt8 cv;
    cv.s[0] = lin1_W;   cv.d[0] = lin1W16;   cv.n[0] = HH * CIN;
    cv.s[1] = conv0_W;  cv.d[1] = conv0W16;  cv.n[1] = HH * HH;
    cv.s[2] = convs_W;  cv.d[2] = convsW16;  cv.n[2] = 2 * HH * HH;
    cv.s[3] = gru_Wih;  cv.d[3] = gruWih16;  cv.n[3] = 3 * H3 * HH;
    cv.s[4] = gru_Whh;  cv.d[4] = gruWhh16;  cv.n[4] = 3 * H3 * HH;
    cv.s[5] = mol_Wsrc; cv.d[5] = molWs16;   cv.n[5] = HH * HH;
    cv.s[6] = mgru_Wih; cv.d[6] = mgruWih16; cv.n[6] = H3 * HH;
    cv.s[7] = mgru_Whh; cv.d[7] = mgruWhh16; cv.n[7] = H3 * HH;
    cvt_multi<<<dim3((3 * H3 * HH + 255) / 256, 8), 256, 0, stream>>>(cv);

    // ---- CSR build (hierarchical scan for NN; single-wave scan for GG) ----
    const int nchunks = (NN + 1023) / 1024;   // 49
    hipMemsetAsync(degb, 0, NN * sizeof(int), stream);
    hist_kernel<<<(EE + 255) / 256, 256, 0, stream>>>(dst, degb, EE, NN);
    chunk_sum<<<nchunks, 256, 0, stream>>>(degb, csum, NN);
    scan_wave<<<1, 64, 0, stream>>>(csum, choff, nullptr, nchunks);
    local_scan<<<nchunks, 256, 0, stream>>>(degb, choff, rowptr, cursor, NN, nchunks);
    scatter_kernel<<<(EE + 255) / 256, 256, 0, stream>>>(src, dst, cursor, csr_src, csr_eid, EE);
    hipMemsetAsync(bdeg, 0, GG * sizeof(int), stream);
    hist_kernel<<<(NN + 255) / 256, 256, 0, stream>>>(batch, bdeg, NN, GG);
    scan_wave<<<1, 64, 0, stream>>>(bdeg, brow, nullptr, GG);

    // ---- conv0 prep (contention-free ea mean) ----
    compose_vec<<<1, 256, 0, stream>>>(conv0_We, conv0_att_e, ve, HH, EDIM);
    ea_sum_kernel<<<EA_BLOCKS, 256, 0, stream>>>(eattr, eapart, EE);
    finalize_aloop<<<1, 64, 0, stream>>>(eapart, ve, aloop, 1.0f / EE, EA_BLOCKS);

    const dim3 gemmGrid((NN + 63) / 64, HH / 64);

    // ---- lin1 ----
    gemm_mfma<<<gemmGrid, 256, 0, stream>>>(xin16, lin1W16, lin1_b, nullptr, x16, NN, HH, CIN, 1);

    // ---- conv0 (edge feats + self loops, slope 0.2) ----
    gemm_mfma<<<gemmGrid, 256, 0, stream>>>(x16, conv0W16, nullptr, nullptr, w16, NN, HH, HH, 0);
    row_dots_h<<<(NN + 3) / 4, 256, 0, stream>>>(w16, NN, conv0_att_s, asb, conv0_att_d, adb, nullptr);
    hipMemsetAsync(mb, 0, NN * sizeof(unsigned), stream);
    edge_alpha_max<<<(EE + NN + 255) / 256, 256, 0, stream>>>(src, dst, EE, EE + NN, asb, adb,
                                                              eattr, ve, aloop, 0.2f, abuf, mb);
    hipMemsetAsync(sb, 0, NN * sizeof(float), stream);
    edge_exp_sum<<<(EE + NN + 255) / 256, 256, 0, stream>>>(dst, EE, EE + NN, abuf, mb, sb);
    csr_aggregate<<<(NN + 3) / 4, 256, 0, stream>>>(rowptr, csr_src, csr_eid, NN, NN, EE + NN,
                                                    1, EE, abuf, sb, w16, conv0_b, h16);
    gru_mfma<<<(NN + 31) / 32, 256, 0, stream>>>(h16, x16, gruWih16, gruWhh16, gru_bih, gru_bhh, NN);

    // ---- remaining atom convs (no self loops, slope 0.01) ----
    for (int l = 0; l < 2; l++) {
        gemm_mfma<<<gemmGrid, 256, 0, stream>>>(x16, convsW16 + (size_t)l * HH * HH,
                                                nullptr, nullptr, w16, NN, HH, HH, 0);
        row_dots_h<<<(NN + 3) / 4, 256, 0, stream>>>(w16, NN, convs_att_s + l * HH, asb,
                                                     convs_att_d + l * HH, adb, nullptr);
        hipMemsetAsync(mb, 0, NN * sizeof(unsigned), stream);
        edge_alpha_max<<<(EE + 255) / 256, 256, 0, stream>>>(src, dst, EE, EE, asb, adb,
                                                             nullptr, nullptr, nullptr, 0.01f, abuf, mb);
        hipMemsetAsync(sb, 0, NN * sizeof(float), stream);
        edge_exp_sum<<<(EE + 255) / 256, 256, 0, stream>>>(dst, EE, EE, abuf, mb, sb);
        csr_aggregate<<<(NN + 3) / 4, 256, 0, stream>>>(rowptr, csr_src, csr_eid, NN, NN, EE,
                                                        0, 0, abuf, sb, w16, convs_b + l * HH, h16);
        gru_mfma<<<(NN + 31) / 32, 256, 0, stream>>>(h16, x16,
                                                     gruWih16 + (size_t)(l + 1) * H3 * HH,
                                                     gruWhh16 + (size_t)(l + 1) * H3 * HH,
                                                     gru_bih + (size_t)(l + 1) * H3,
                                                     gru_bhh + (size_t)(l + 1) * H3, NN);
    }

    // ---- molecule readout ----
    pool_csr<<<(GG + 3) / 4, 256, 0, stream>>>(brow, x16, outg16, GG);
    gemm_mfma<<<gemmGrid, 256, 0, stream>>>(x16, molWs16, nullptr, nullptr, w16, NN, HH, HH, 0);
    row_dots_h<<<(NN + 3) / 4, 256, 0, stream>>>(w16, NN, mol_att_s, asb, nullptr, nullptr, nullptr);
    compose_vec<<<1, 256, 0, stream>>>(mol_Wdst, mol_att_d, vd, HH, HH);

    for (int t = 0; t < 2; t++) {
        row_dots_h<<<(GG + 3) / 4, 256, 0, stream>>>(outg16, GG, vd, adg, nullptr, nullptr, nullptr);
        hipMemsetAsync(mg, 0, GG * sizeof(unsigned), stream);
        edge_alpha_max<<<(NN + 255) / 256, 256, 0, stream>>>(nullptr, batch, NN, NN, asb, adg,
                                                             nullptr, nullptr, nullptr, 0.01f, abuf, mg);
        hipMemsetAsync(sg, 0, GG * sizeof(float), stream);
        edge_exp_sum<<<(NN + 255) / 256, 256, 0, stream>>>(batch, NN, NN, abuf, mg, sg);
        csr_aggregate<<<(GG + 3) / 4, 256, 0, stream>>>(brow, nullptr, nullptr, GG, NN, NN,
                                                        0, 0, abuf, sg, w16, mol_b, hg16);
        gru_mfma<<<(GG + 31) / 32, 256, 0, stream>>>(hg16, outg16, mgruWih16, mgruWhh16,
                                                     mgru_bih, mgru_bhh, GG);
    }

    // ---- final linear ----
    row_dots_h<<<(GG + 3) / 4, 256, 0, stream>>>(outg16, GG, lin2_W, (float*)d_out,
                                                 nullptr, nullptr, lin2_b);
}

// Round 10
// 1486.935 us; speedup vs baseline: 4.3958x; 1.0537x over previous
//
#include <hip/hip_runtime.h>
#include <math.h>

// ---------------- problem constants ----------------
#define NN    50000
#define EE    800000
#define CIN   64
#define HH    192
#define EDIM  16
#define GG    2048
#define H3    576   // 3*H
#define EA_BLOCKS 256
#define FRAG_ELEMS (36 * 6 * 64)   // col-blocks * chunks * lanes, per 576x192 matrix

typedef _Float16 f16;
typedef _Float16 half8 __attribute__((ext_vector_type(8)));
typedef float f32x4 __attribute__((ext_vector_type(4)));

// ---------------- helpers ----------------
__device__ __forceinline__ unsigned fmap(float f) {
    unsigned u = __float_as_uint(f);
    return (u & 0x80000000u) ? ~u : (u | 0x80000000u);
}
__device__ __forceinline__ float funmap(unsigned u) {
    if (u == 0u) return 0.0f;
    return (u & 0x80000000u) ? __uint_as_float(u ^ 0x80000000u)
                             : __uint_as_float(~u);
}

// ---------------- fp32 -> fp16 converts ----------------
__global__ void cvt_f2h(const float* __restrict__ s, f16* __restrict__ d, int n)
{
    int i = blockIdx.x * blockDim.x + threadIdx.x;
    if (i < n) d[i] = (f16)s[i];
}

struct Cvt8 { const float* s[8]; f16* d[8]; int n[8]; };
__global__ void cvt_multi(Cvt8 c)
{
    int slot = blockIdx.y;
    int i = blockIdx.x * blockDim.x + threadIdx.x;
    if (i < c.n[slot]) c.d[slot][i] = (f16)c.s[slot][i];
}

// ---------------- GRU weight repack: fragment-major for coalesced B-loads ----------------
// src: [576 cols][192 k] f16. dst fragment idx = (cb*6 + c)*64 + lane, 8 halves each,
// where col = cb*16 + (lane&15), k = c*32 + (lane>>4)*8. One wave load = 1 KB contiguous.
struct Pack8 { const f16* s[8]; f16* d[8]; };
__global__ __launch_bounds__(256) void pack_frag(Pack8 p)
{
    int slot = blockIdx.y;
    int idx = blockIdx.x * 256 + threadIdx.x;
    if (idx >= FRAG_ELEMS) return;
    int cb   = idx / 384;          // 6*64
    int rem  = idx % 384;
    int c    = rem / 64;
    int lane = rem % 64;
    int col = cb * 16 + (lane & 15);
    int k   = c * 32 + (lane >> 4) * 8;
    *(half8*)(p.d[slot] + (size_t)idx * 8) =
        *(const half8*)(p.s[slot] + (size_t)col * 192 + k);
}

// ---------------- CSR build ----------------
__global__ void hist_kernel(const int* __restrict__ idx, int* __restrict__ deg, int n, int nbins)
{
    int i = blockIdx.x * blockDim.x + threadIdx.x;
    if (i < n) {
        unsigned b = (unsigned)idx[i];
        if (b < (unsigned)nbins) atomicAdd(&deg[b], 1);
    }
}

// single-WAVE exclusive scan (serial over 64-chunks) — small arrays only
__global__ void scan_wave(const int* __restrict__ deg, int* __restrict__ rowptr,
                          unsigned* __restrict__ cursor, int n)
{
    int lane = threadIdx.x & 63;
    int carry = 0;
    for (int base = 0; base < n; base += 64) {
        int i = base + lane;
        int v = (i < n) ? deg[i] : 0;
        int x = v;
        #pragma unroll
        for (int off = 1; off < 64; off <<= 1) {
            int t = __shfl_up(x, off);
            if (lane >= off) x += t;
        }
        int ex = carry + x - v;
        if (i < n) {
            rowptr[i] = ex;
            if (cursor) cursor[i] = (unsigned)ex;
        }
        carry += __shfl(x, 63);
    }
    if (lane == 0) rowptr[n] = carry;
}

// hierarchical scan, level 1: per-1024-chunk sums
__global__ __launch_bounds__(256) void chunk_sum(const int* __restrict__ deg,
                                                 int* __restrict__ csum, int n)
{
    int base = blockIdx.x * 1024;
    int tid = threadIdx.x;
    int i0 = base + tid * 4;
    int s = 0;
    #pragma unroll
    for (int k = 0; k < 4; k++) { int i = i0 + k; if (i < n) s += deg[i]; }
    #pragma unroll
    for (int off = 32; off > 0; off >>= 1) s += __shfl_down(s, off);
    __shared__ int ws[4];
    int lane = tid & 63, w = tid >> 6;
    if (lane == 0) ws[w] = s;
    __syncthreads();
    if (tid == 0) csum[blockIdx.x] = ws[0] + ws[1] + ws[2] + ws[3];
}

// hierarchical scan, level 3: local exclusive scan + chunk offset
__global__ __launch_bounds__(256) void local_scan(const int* __restrict__ deg,
                                                  const int* __restrict__ choff,
                                                  int* __restrict__ rowptr,
                                                  unsigned* __restrict__ cursor,
                                                  int n, int nchunks)
{
    int base = blockIdx.x * 1024;
    int tid = threadIdx.x;
    int lane = tid & 63, w = tid >> 6;
    int i0 = base + tid * 4;
    int v[4];
    #pragma unroll
    for (int k = 0; k < 4; k++) { int i = i0 + k; v[k] = (i < n) ? deg[i] : 0; }
    int tsum = v[0] + v[1] + v[2] + v[3];
    int x = tsum;
    #pragma unroll
    for (int off = 1; off < 64; off <<= 1) {
        int t = __shfl_up(x, off);
        if (lane >= off) x += t;
    }
    __shared__ int wtot[4];
    if (lane == 63) wtot[w] = x;
    __syncthreads();
    int woff = 0;
    #pragma unroll
    for (int j = 0; j < 4; j++) if (j < w) woff += wtot[j];
    int ex = choff[blockIdx.x] + woff + x - tsum;
    #pragma unroll
    for (int k = 0; k < 4; k++) {
        int i = i0 + k;
        if (i < n) {
            rowptr[i] = ex;
            if (cursor) cursor[i] = (unsigned)ex;
        }
        ex += v[k];
    }
    if (blockIdx.x == 0 && tid == 0) rowptr[n] = choff[nchunks];
}

__global__ void scatter_kernel(const int* __restrict__ src, const int* __restrict__ dst,
                               unsigned* __restrict__ cursor,
                               int* __restrict__ csr_src, int* __restrict__ csr_eid, int E)
{
    int e = blockIdx.x * blockDim.x + threadIdx.x;
    if (e >= E) return;
    unsigned d = (unsigned)dst[e];
    if (d >= (unsigned)NN) return;
    unsigned p = atomicAdd(&cursor[d], 1u);
    if (p < (unsigned)E) {
        csr_src[p] = src[e];
        csr_eid[p] = e;
    }
}

// ---------------- MFMA GEMM: C[M,N] = act(A16[M,K] @ W16[N,K]^T + bias) ----------------
__global__ __launch_bounds__(256) void gemm_mfma(const f16* __restrict__ A,
                                                 const f16* __restrict__ W,
                                                 const float* __restrict__ bias,
                                                 float* __restrict__ Cf,
                                                 f16* __restrict__ Ch,
                                                 int M, int N, int K, int act)
{
    __shared__ __align__(16) f16 sA[64 * 40];
    const int tid  = threadIdx.x;
    const int lane = tid & 63;
    const int wid  = tid >> 6;
    const int wy = wid >> 1, wx = wid & 1;
    const int m0 = blockIdx.x << 6, n0 = blockIdx.y << 6;
    const int n_ = lane & 15, quad = lane >> 4;

    f32x4 acc[2][2] = {};
    int boff0 = (n0 + wx * 32 + n_) * K + quad * 8;
    int boff1 = boff0 + 16 * K;

    const int srow = tid >> 2;
    const int skc  = (tid & 3) << 3;

    for (int k0 = 0; k0 < K; k0 += 32) {
        half8 av = {};
        int gm = m0 + srow;
        if (gm < M) av = *(const half8*)(A + (size_t)gm * K + k0 + skc);
        *(half8*)(sA + srow * 40 + skc) = av;
        __syncthreads();
        half8 a0 = *(const half8*)(sA + (wy * 32 + n_) * 40 + quad * 8);
        half8 a1 = *(const half8*)(sA + (wy * 32 + 16 + n_) * 40 + quad * 8);
        half8 b0 = *(const half8*)(W + boff0 + k0);
        half8 b1 = *(const half8*)(W + boff1 + k0);
        acc[0][0] = __builtin_amdgcn_mfma_f32_16x16x32_f16(a0, b0, acc[0][0], 0, 0, 0);
        acc[0][1] = __builtin_amdgcn_mfma_f32_16x16x32_f16(a0, b1, acc[0][1], 0, 0, 0);
        acc[1][0] = __builtin_amdgcn_mfma_f32_16x16x32_f16(a1, b0, acc[1][0], 0, 0, 0);
        acc[1][1] = __builtin_amdgcn_mfma_f32_16x16x32_f16(a1, b1, acc[1][1], 0, 0, 0);
        __syncthreads();
    }
    #pragma unroll
    for (int i = 0; i < 2; i++)
        #pragma unroll
        for (int j = 0; j < 2; j++) {
            int col = n0 + wx * 32 + j * 16 + n_;
            float bv = bias ? bias[col] : 0.f;
            #pragma unroll
            for (int reg = 0; reg < 4; reg++) {
                int row = m0 + wy * 32 + i * 16 + quad * 4 + reg;
                if (row >= M) continue;
                float v = acc[i][j][reg] + bv;
                if (act == 1) v = v >= 0.f ? v : 0.01f * v;
                if (Cf) Cf[(size_t)row * N + col] = v;
                if (Ch) Ch[(size_t)row * N + col] = (f16)v;
            }
        }
}

// ---------------- fused MFMA GRU: X16 = relu(GRU(H16, X16)) in place, 32 rows/block ----------------
// B operands from FRAGMENT-PACKED weights (pack_frag layout): every load coalesced 1 KB/wave.
// Merged r/z accumulators; n gate separate. Barrier-free 6-chunk main loop.
#define GRU_LDP 208
__global__ __launch_bounds__(256, 2) void gru_mfma(const f16* __restrict__ H16,
                                                   f16* __restrict__ X16,
                                                   const f16* __restrict__ Pih,
                                                   const f16* __restrict__ Phh,
                                                   const float* __restrict__ bih,
                                                   const float* __restrict__ bhh,
                                                   int M)
{
    __shared__ __align__(16) f16 sH[32 * GRU_LDP];
    __shared__ __align__(16) f16 sX[32 * GRU_LDP];
    const int tid  = threadIdx.x;
    const int lane = tid & 63;
    const int w    = tid >> 6;
    const int n_ = lane & 15, quad = lane >> 4;
    const int node0 = blockIdx.x << 5;

    // ---- stage all 32x192 of h and x ----
    {
        const int r  = tid >> 3;
        const int cb = (tid & 7) * 24;
        const int gm = node0 + r;
        if (gm < M) {
            const f16* hp = H16 + (size_t)gm * 192 + cb;
            const f16* xp = X16 + (size_t)gm * 192 + cb;
            #pragma unroll
            for (int q = 0; q < 3; q++) {
                *(half8*)(sH + r * GRU_LDP + cb + q * 8) = *(const half8*)(hp + q * 8);
                *(half8*)(sX + r * GRU_LDP + cb + q * 8) = *(const half8*)(xp + q * 8);
            }
        } else {
            half8 z = {};
            #pragma unroll
            for (int q = 0; q < 3; q++) {
                *(half8*)(sH + r * GRU_LDP + cb + q * 8) = z;
                *(half8*)(sX + r * GRU_LDP + cb + q * 8) = z;
            }
        }
    }
    __syncthreads();

    f32x4 aRZ[2][2][3] = {};   // [row-half][gate r/z][tile]
    f32x4 aIN[2][3] = {};
    f32x4 aHN[2][3] = {};
    // packed fragment base: col-block cb = g*12 + w*3 + t; offset = cb*3072 + c*512 + lane*8
    int fb[3][3];
    #pragma unroll
    for (int g = 0; g < 3; g++)
        #pragma unroll
        for (int t = 0; t < 3; t++)
            fb[g][t] = (g * 12 + w * 3 + t) * 3072 + lane * 8;

    #pragma unroll 1
    for (int c = 0; c < 6; c++) {
        int k0 = c * 32;
        int po = c * 512;
        half8 ah0 = *(const half8*)(sH + n_ * GRU_LDP + k0 + quad * 8);
        half8 ah1 = *(const half8*)(sH + (16 + n_) * GRU_LDP + k0 + quad * 8);
        half8 ax0 = *(const half8*)(sX + n_ * GRU_LDP + k0 + quad * 8);
        half8 ax1 = *(const half8*)(sX + (16 + n_) * GRU_LDP + k0 + quad * 8);
        #pragma unroll
        for (int g = 0; g < 2; g++)
            #pragma unroll
            for (int t = 0; t < 3; t++) {
                half8 bI = *(const half8*)(Pih + fb[g][t] + po);
                half8 bH = *(const half8*)(Phh + fb[g][t] + po);
                aRZ[0][g][t] = __builtin_amdgcn_mfma_f32_16x16x32_f16(ah0, bI, aRZ[0][g][t], 0, 0, 0);
                aRZ[1][g][t] = __builtin_amdgcn_mfma_f32_16x16x32_f16(ah1, bI, aRZ[1][g][t], 0, 0, 0);
                aRZ[0][g][t] = __builtin_amdgcn_mfma_f32_16x16x32_f16(ax0, bH, aRZ[0][g][t], 0, 0, 0);
                aRZ[1][g][t] = __builtin_amdgcn_mfma_f32_16x16x32_f16(ax1, bH, aRZ[1][g][t], 0, 0, 0);
            }
        #pragma unroll
        for (int t = 0; t < 3; t++) {
            half8 bI = *(const half8*)(Pih + fb[2][t] + po);
            half8 bH = *(const half8*)(Phh + fb[2][t] + po);
            aIN[0][t] = __builtin_amdgcn_mfma_f32_16x16x32_f16(ah0, bI, aIN[0][t], 0, 0, 0);
            aIN[1][t] = __builtin_amdgcn_mfma_f32_16x16x32_f16(ah1, bI, aIN[1][t], 0, 0, 0);
            aHN[0][t] = __builtin_amdgcn_mfma_f32_16x16x32_f16(ax0, bH, aHN[0][t], 0, 0, 0);
            aHN[1][t] = __builtin_amdgcn_mfma_f32_16x16x32_f16(ax1, bH, aHN[1][t], 0, 0, 0);
        }
    }

    #pragma unroll
    for (int t = 0; t < 3; t++) {
        int c0 = w * 48 + t * 16 + n_;
        float brz = bih[c0] + bhh[c0];
        float bzz = bih[c0 + 192] + bhh[c0 + 192];
        float bin = bih[c0 + 384], bhn = bhh[c0 + 384];
        #pragma unroll
        for (int half = 0; half < 2; half++) {
            #pragma unroll
            for (int reg = 0; reg < 4; reg++) {
                int rl = half * 16 + quad * 4 + reg;
                int node = node0 + rl;
                if (node >= M) continue;
                float hx = (float)sX[rl * GRU_LDP + c0];
                float r  = 1.f / (1.f + expf(-(aRZ[half][0][t][reg] + brz)));
                float z  = 1.f / (1.f + expf(-(aRZ[half][1][t][reg] + bzz)));
                float nn = tanhf(aIN[half][t][reg] + bin + r * (aHN[half][t][reg] + bhn));
                float o  = (1.f - z) * nn + z * hx;
                X16[(size_t)node * 192 + c0] = (f16)(o > 0.f ? o : 0.f);
            }
        }
    }
}

// ---------------- small vector compose ----------------
__global__ void compose_vec(const float* __restrict__ W, const float* __restrict__ v,
                            float* __restrict__ out, int rows, int cols)
{
    int j = threadIdx.x;
    if (j >= cols) return;
    float acc = 0.f;
    for (int i = 0; i < rows; i++) acc += v[i] * W[(size_t)i * cols + j];
    out[j] = acc;
}

// ---------------- edge_attr column sums -> per-block partials (no atomics) ----------------
__global__ __launch_bounds__(256) void ea_sum_kernel(const float* __restrict__ ea,
                                                     float* __restrict__ partials, int E)
{
    __shared__ float ws[4][16];
    int tid = threadIdx.x;
    int lane = tid & 63, w = tid >> 6;
    float acc[16];
    #pragma unroll
    for (int f = 0; f < 16; f++) acc[f] = 0.f;
    for (int e = blockIdx.x * blockDim.x + tid; e < E; e += gridDim.x * blockDim.x) {
        const float4* p = (const float4*)(ea + (size_t)e * 16);
        float4 v0 = p[0], v1 = p[1], v2 = p[2], v3 = p[3];
        acc[0] += v0.x; acc[1] += v0.y; acc[2] += v0.z; acc[3] += v0.w;
        acc[4] += v1.x; acc[5] += v1.y; acc[6] += v1.z; acc[7] += v1.w;
        acc[8] += v2.x; acc[9] += v2.y; acc[10] += v2.z; acc[11] += v2.w;
        acc[12] += v3.x; acc[13] += v3.y; acc[14] += v3.z; acc[15] += v3.w;
    }
    #pragma unroll
    for (int off = 32; off > 0; off >>= 1)
        #pragma unroll
        for (int f = 0; f < 16; f++) acc[f] += __shfl_down(acc[f], off);
    if (lane == 0)
        #pragma unroll
        for (int f = 0; f < 16; f++) ws[w][f] = acc[f];
    __syncthreads();
    if (tid < 16)
        partials[blockIdx.x * 16 + tid] = ws[0][tid] + ws[1][tid] + ws[2][tid] + ws[3][tid];
}

__global__ void finalize_aloop(const float* __restrict__ partials, const float* __restrict__ ve,
                               float* __restrict__ aloop, float invE, int nblk)
{
    int lane = threadIdx.x & 63;
    float s = 0.f;
    if (lane < 16) {
        for (int b = 0; b < nblk; b += 4) {
            s += partials[b * 16 + lane]
               + partials[(b + 1) * 16 + lane]
               + partials[(b + 2) * 16 + lane]
               + partials[(b + 3) * 16 + lane];
        }
        s *= invE * ve[lane];
    }
    #pragma unroll
    for (int off = 8; off > 0; off >>= 1) s += __shfl_down(s, off);
    if (lane == 0) *aloop = s;
}

// ---------------- per-row dots on fp16 matrix (1-2 vectors) ----------------
__global__ void row_dots_h(const f16* __restrict__ Mat, int M,
                           const float* __restrict__ v1, float* __restrict__ o1,
                           const float* __restrict__ v2, float* __restrict__ o2,
                           const float* __restrict__ bias)
{
    int row = blockIdx.x * 4 + (threadIdx.x >> 6);
    if (row >= M) return;
    int lane = threadIdx.x & 63;
    const f16* rp = Mat + (size_t)row * 192;
    float a1 = 0.f, a2 = 0.f;
    #pragma unroll
    for (int k = 0; k < 3; k++) {
        int f = lane + 64 * k;
        float x = (float)rp[f];
        a1 += x * v1[f];
        if (o2) a2 += x * v2[f];
    }
    #pragma unroll
    for (int off = 32; off > 0; off >>= 1) {
        a1 += __shfl_down(a1, off);
        a2 += __shfl_down(a2, off);
    }
    if (lane == 0) {
        o1[row] = a1 + (bias ? bias[0] : 0.f);
        if (o2) o2[row] = a2;
    }
}

// ---------------- alpha + segment max ----------------
__global__ void edge_alpha_max(const int* __restrict__ srcp, const int* __restrict__ dstp,
                               int E_real, int Etot,
                               const float* __restrict__ as_, const float* __restrict__ ad_,
                               const float* __restrict__ ea, const float* __restrict__ ve,
                               const float* __restrict__ aloop, float slope,
                               float* __restrict__ ab, unsigned* __restrict__ mb)
{
    int i = blockIdx.x * blockDim.x + threadIdx.x;
    if (i >= Etot) return;
    int s_, d_;
    float aext = 0.f;
    if (i < E_real) {
        s_ = srcp ? srcp[i] : i;
        d_ = dstp[i];
        if (ea) {
            const float4* p = (const float4*)(ea + (size_t)i * 16);
            const float4* q = (const float4*)ve;
            float4 e0 = p[0], e1 = p[1], e2 = p[2], e3 = p[3];
            float4 w0 = q[0], w1 = q[1], w2 = q[2], w3 = q[3];
            aext = e0.x * w0.x + e0.y * w0.y + e0.z * w0.z + e0.w * w0.w
                 + e1.x * w1.x + e1.y * w1.y + e1.z * w1.z + e1.w * w1.w
                 + e2.x * w2.x + e2.y * w2.y + e2.z * w2.z + e2.w * w2.w
                 + e3.x * w3.x + e3.y * w3.y + e3.z * w3.z + e3.w * w3.w;
        }
    } else {
        s_ = d_ = i - E_real;
        aext = *aloop;
    }
    float a = as_[s_] + ad_[d_] + aext;
    a = a >= 0.f ? a : slope * a;
    ab[i] = a;
    atomicMax(&mb[d_], fmap(a));
}

// ---------------- exp(alpha - max) + segment sum ----------------
__global__ void edge_exp_sum(const int* __restrict__ dstp, int E_real, int Etot,
                             float* __restrict__ ab, const unsigned* __restrict__ mb,
                             float* __restrict__ sb)
{
    int i = blockIdx.x * blockDim.x + threadIdx.x;
    if (i >= Etot) return;
    int d_ = (i < E_real) ? dstp[i] : i - E_real;
    float m = funmap(mb[d_]);
    float e = expf(ab[i] - m);
    ab[i] = e;
    atomicAdd(&sb[d_], e);
}

// ---------------- CSR aggregate: Hout16[dst] = elu(sum_e w_e*F[src_e]/sum + bias), fp16 out ----------------
__global__ __launch_bounds__(256) void csr_aggregate(const int* __restrict__ rowptr,
                                                     const int* __restrict__ csr_src,
                                                     const int* __restrict__ csr_eid,
                                                     int Ndst, int nF, int nAb,
                                                     int selfloop, int selfAb,
                                                     const float* __restrict__ ab,
                                                     const float* __restrict__ sb,
                                                     const f16* __restrict__ F,
                                                     const float* __restrict__ bias,
                                                     f16* __restrict__ Hout16)
{
    int node = blockIdx.x * 4 + (threadIdx.x >> 6);
    if (node >= Ndst) return;
    int lane = threadIdx.x & 63;
    int start = rowptr[node];
    int deg = rowptr[node + 1] - start;
    deg = min(max(deg, 0), 1 << 20);
    float inv = 1.f / (sb[node] + 1e-16f);

    float acc0 = 0.f, acc1 = 0.f, acc2 = 0.f;
    for (int base = 0; base < deg; base += 64) {
        int i = base + lane;
        float wv = 0.f;
        int s = 0;
        if (i < deg) {
            int pos = start + i;
            s = csr_src ? csr_src[pos] : pos;
            if ((unsigned)s >= (unsigned)nF) s = 0;
            unsigned eid = csr_eid ? (unsigned)csr_eid[pos] : (unsigned)pos;
            if (eid >= (unsigned)nAb) eid = 0;
            wv = ab[eid];
        }
        int cnt = min(64, deg - base);
        for (int j = 0; j < cnt; j++) {
            float wj = __shfl(wv, j);
            int   sj = __shfl(s, j);
            const f16* fr = F + (size_t)sj * 192;
            acc0 += wj * (float)fr[lane];
            acc1 += wj * (float)fr[lane + 64];
            acc2 += wj * (float)fr[lane + 128];
        }
    }
    if (selfloop) {
        unsigned eid = (unsigned)(selfAb + node);
        float wv = (eid < (unsigned)nAb) ? ab[eid] : 0.f;
        int s = min(node, nF - 1);
        const f16* fr = F + (size_t)s * 192;
        acc0 += wv * (float)fr[lane];
        acc1 += wv * (float)fr[lane + 64];
        acc2 += wv * (float)fr[lane + 128];
    }
    float h0 = acc0 * inv + bias[lane];
    float h1 = acc1 * inv + bias[lane + 64];
    float h2 = acc2 * inv + bias[lane + 128];
    f16* orow = Hout16 + (size_t)node * 192;
    orow[lane]       = (f16)(h0 > 0.f ? h0 : expm1f(h0));
    orow[lane + 64]  = (f16)(h1 > 0.f ? h1 : expm1f(h1));
    orow[lane + 128] = (f16)(h2 > 0.f ? h2 : expm1f(h2));
}

// ---------------- pool: per-graph wave sum over contiguous node range, relu, fp16 ----------------
__global__ void pool_csr(const int* __restrict__ brow, const f16* __restrict__ X,
                         f16* __restrict__ outg16, int G)
{
    int g = blockIdx.x * 4 + (threadIdx.x >> 6);
    if (g >= G) return;
    int lane = threadIdx.x & 63;
    float a0 = 0.f, a1 = 0.f, a2 = 0.f;
    int s = max(brow[g], 0);
    int e = min(brow[g + 1], NN);
    for (int n = s; n < e; n++) {
        const f16* xr = X + (size_t)n * 192;
        a0 += (float)xr[lane];
        a1 += (float)xr[lane + 64];
        a2 += (float)xr[lane + 128];
    }
    f16* o = outg16 + (size_t)g * 192;
    o[lane]       = (f16)(a0 > 0.f ? a0 : 0.f);
    o[lane + 64]  = (f16)(a1 > 0.f ? a1 : 0.f);
    o[lane + 128] = (f16)(a2 > 0.f ? a2 : 0.f);
}

// ---------------- launch ----------------
extern "C" void kernel_launch(void* const* d_in, const int* in_sizes, int n_in,
                              void* d_out, int out_size, void* d_ws, size_t ws_size,
                              hipStream_t stream)
{
    const float* x_in        = (const float*)d_in[0];
    const int*   ei          = (const int*)  d_in[1];
    const float* eattr       = (const float*)d_in[2];
    const int*   batch       = (const int*)  d_in[3];
    const float* lin1_W      = (const float*)d_in[4];
    const float* lin1_b      = (const float*)d_in[5];
    const float* conv0_W     = (const float*)d_in[6];
    const float* conv0_att_s = (const float*)d_in[7];
    const float* conv0_att_d = (const float*)d_in[8];
    const float* conv0_We    = (const float*)d_in[9];
    const float* conv0_att_e = (const float*)d_in[10];
    const float* conv0_b     = (const float*)d_in[11];
    const float* convs_W     = (const float*)d_in[12];
    const float* convs_att_s = (const float*)d_in[13];
    const float* convs_att_d = (const float*)d_in[14];
    const float* convs_b     = (const float*)d_in[15];
    const float* gru_Wih     = (const float*)d_in[16];
    const float* gru_Whh     = (const float*)d_in[17];
    const float* gru_bih     = (const float*)d_in[18];
    const float* gru_bhh     = (const float*)d_in[19];
    const float* mol_Wsrc    = (const float*)d_in[20];
    const float* mol_Wdst    = (const float*)d_in[21];
    const float* mol_att_s   = (const float*)d_in[22];
    const float* mol_att_d   = (const float*)d_in[23];
    const float* mol_b       = (const float*)d_in[24];
    const float* mgru_Wih    = (const float*)d_in[25];
    const float* mgru_Whh    = (const float*)d_in[26];
    const float* mgru_bih    = (const float*)d_in[27];
    const float* mgru_bhh    = (const float*)d_in[28];
    const float* lin2_W      = (const float*)d_in[29];
    const float* lin2_b      = (const float*)d_in[30];

    const int* src = ei;
    const int* dst = ei + EE;

    // ---- workspace layout ----
    char* base = (char*)d_ws;
    size_t off = 0;
    auto alloc = [&](size_t bytes) -> void* {
        void* p = base + off;
        off = (off + bytes + 63) & ~(size_t)63;
        return p;
    };
    f16*      w16    = (f16*)alloc((size_t)NN * HH * 2);
    f16*      h16    = (f16*)alloc((size_t)NN * HH * 2);
    f16*      x16    = (f16*)alloc((size_t)NN * HH * 2);
    f16*      xin16  = (f16*)alloc((size_t)NN * CIN * 2);
    float*    abuf   = (float*)alloc((size_t)(EE + NN) * 4);
    float*    asb    = (float*)alloc((size_t)NN * 4);
    float*    adb    = (float*)alloc((size_t)NN * 4);
    float*    sb     = (float*)alloc((size_t)NN * 4);
    unsigned* mb     = (unsigned*)alloc((size_t)NN * 4);
    f16*      hg16   = (f16*)alloc((size_t)GG * HH * 2);
    f16*      outg16 = (f16*)alloc((size_t)GG * HH * 2);
    float*    adg    = (float*)alloc((size_t)GG * 4);
    float*    sg     = (float*)alloc((size_t)GG * 4);
    unsigned* mg     = (unsigned*)alloc((size_t)GG * 4);
    int*      degb   = (int*)alloc((size_t)NN * 4);
    int*      rowptr = (int*)alloc((size_t)(NN + 1) * 4);
    unsigned* cursor = (unsigned*)alloc((size_t)NN * 4);
    int*      csr_src = (int*)alloc((size_t)EE * 4);
    int*      csr_eid = (int*)alloc((size_t)EE * 4);
    int*      bdeg   = (int*)alloc((size_t)GG * 4);
    int*      brow   = (int*)alloc((size_t)(GG + 1) * 4);
    int*      csum   = (int*)alloc(64 * 4);
    int*      choff  = (int*)alloc(65 * 4);
    float*    ve     = (float*)alloc(64);
    float*    eapart = (float*)alloc((size_t)EA_BLOCKS * 16 * 4);
    float*    vd     = (float*)alloc(HH * 4);
    float*    aloop  = (float*)alloc(64);
    f16*      lin1W16   = (f16*)alloc((size_t)HH * CIN * 2);
    f16*      conv0W16  = (f16*)alloc((size_t)HH * HH * 2);
    f16*      convsW16  = (f16*)alloc((size_t)2 * HH * HH * 2);
    f16*      gruWih16  = (f16*)alloc((size_t)3 * H3 * HH * 2);
    f16*      gruWhh16  = (f16*)alloc((size_t)3 * H3 * HH * 2);
    f16*      molWs16   = (f16*)alloc((size_t)HH * HH * 2);
    f16*      mgruWih16 = (f16*)alloc((size_t)H3 * HH * 2);
    f16*      mgruWhh16 = (f16*)alloc((size_t)H3 * HH * 2);
    // fragment-packed GRU weights (8 matrices of 576x192)
    f16*      gruWihP   = (f16*)alloc((size_t)3 * FRAG_ELEMS * 8 * 2);
    f16*      gruWhhP   = (f16*)alloc((size_t)3 * FRAG_ELEMS * 8 * 2);
    f16*      mgruWihP  = (f16*)alloc((size_t)FRAG_ELEMS * 8 * 2);
    f16*      mgruWhhP  = (f16*)alloc((size_t)FRAG_ELEMS * 8 * 2);
    if (off > ws_size) return;

    // ---- weight + input converts ----
    cvt_f2h<<<(NN * CIN + 255) / 256, 256, 0, stream>>>(x_in, xin16, NN * CIN);
    Cvt8 cv;
    cv.s[0] = lin1_W;   cv.d[0] = lin1W16;   cv.n[0] = HH * CIN;
    cv.s[1] = conv0_W;  cv.d[1] = conv0W16;  cv.n[1] = HH * HH;
    cv.s[2] = convs_W;  cv.d[2] = convsW16;  cv.n[2] = 2 * HH * HH;
    cv.s[3] = gru_Wih;  cv.d[3] = gruWih16;  cv.n[3] = 3 * H3 * HH;
    cv.s[4] = gru_Whh;  cv.d[4] = gruWhh16;  cv.n[4] = 3 * H3 * HH;
    cv.s[5] = mol_Wsrc; cv.d[5] = molWs16;   cv.n[5] = HH * HH;
    cv.s[6] = mgru_Wih; cv.d[6] = mgruWih16; cv.n[6] = H3 * HH;
    cv.s[7] = mgru_Whh; cv.d[7] = mgruWhh16; cv.n[7] = H3 * HH;
    cvt_multi<<<dim3((3 * H3 * HH + 255) / 256, 8), 256, 0, stream>>>(cv);

    // ---- pack GRU weights into fragment-major layout ----
    Pack8 pk;
    const size_t WM = (size_t)H3 * HH;             // 110592 halves per matrix
    pk.s[0] = gruWih16;            pk.d[0] = gruWihP;
    pk.s[1] = gruWih16 + WM;       pk.d[1] = gruWihP + WM;
    pk.s[2] = gruWih16 + 2 * WM;   pk.d[2] = gruWihP + 2 * WM;
    pk.s[3] = gruWhh16;            pk.d[3] = gruWhhP;
    pk.s[4] = gruWhh16 + WM;       pk.d[4] = gruWhhP + WM;
    pk.s[5] = gruWhh16 + 2 * WM;   pk.d[5] = gruWhhP + 2 * WM;
    pk.s[6] = mgruWih16;           pk.d[6] = mgruWihP;
    pk.s[7] = mgruWhh16;           pk.d[7] = mgruWhhP;
    pack_frag<<<dim3((FRAG_ELEMS + 255) / 256, 8), 256, 0, stream>>>(pk);

    // ---- CSR build ----
    const int nchunks = (NN + 1023) / 1024;   // 49
    hipMemsetAsync(degb, 0, NN * sizeof(int), stream);
    hist_kernel<<<(EE + 255) / 256, 256, 0, stream>>>(dst, degb, EE, NN);
    chunk_sum<<<nchunks, 256, 0, stream>>>(degb, csum, NN);
    scan_wave<<<1, 64, 0, stream>>>(csum, choff, nullptr, nchunks);
    local_scan<<<nchunks, 256, 0, stream>>>(degb, choff, rowptr, cursor, NN, nchunks);
    scatter_kernel<<<(EE + 255) / 256, 256, 0, stream>>>(src, dst, cursor, csr_src, csr_eid, EE);
    hipMemsetAsync(bdeg, 0, GG * sizeof(int), stream);
    hist_kernel<<<(NN + 255) / 256, 256, 0, stream>>>(batch, bdeg, NN, GG);
    scan_wave<<<1, 64, 0, stream>>>(bdeg, brow, nullptr, GG);

    // ---- conv0 prep ----
    compose_vec<<<1, 256, 0, stream>>>(conv0_We, conv0_att_e, ve, HH, EDIM);
    ea_sum_kernel<<<EA_BLOCKS, 256, 0, stream>>>(eattr, eapart, EE);
    finalize_aloop<<<1, 64, 0, stream>>>(eapart, ve, aloop, 1.0f / EE, EA_BLOCKS);

    const dim3 gemmGrid((NN + 63) / 64, HH / 64);

    // ---- lin1 ----
    gemm_mfma<<<gemmGrid, 256, 0, stream>>>(xin16, lin1W16, lin1_b, nullptr, x16, NN, HH, CIN, 1);

    // ---- conv0 (edge feats + self loops, slope 0.2) ----
    gemm_mfma<<<gemmGrid, 256, 0, stream>>>(x16, conv0W16, nullptr, nullptr, w16, NN, HH, HH, 0);
    row_dots_h<<<(NN + 3) / 4, 256, 0, stream>>>(w16, NN, conv0_att_s, asb, conv0_att_d, adb, nullptr);
    hipMemsetAsync(mb, 0, NN * sizeof(unsigned), stream);
    edge_alpha_max<<<(EE + NN + 255) / 256, 256, 0, stream>>>(src, dst, EE, EE + NN, asb, adb,
                                                              eattr, ve, aloop, 0.2f, abuf, mb);
    hipMemsetAsync(sb, 0, NN * sizeof(float), stream);
    edge_exp_sum<<<(EE + NN + 255) / 256, 256, 0, stream>>>(dst, EE, EE + NN, abuf, mb, sb);
    csr_aggregate<<<(NN + 3) / 4, 256, 0, stream>>>(rowptr, csr_src, csr_eid, NN, NN, EE + NN,
                                                    1, EE, abuf, sb, w16, conv0_b, h16);
    gru_mfma<<<(NN + 31) / 32, 256, 0, stream>>>(h16, x16, gruWihP, gruWhhP, gru_bih, gru_bhh, NN);

    // ---- remaining atom convs (no self loops, slope 0.01) ----
    for (int l = 0; l < 2; l++) {
        gemm_mfma<<<gemmGrid, 256, 0, stream>>>(x16, convsW16 + (size_t)l * HH * HH,
                                                nullptr, nullptr, w16, NN, HH, HH, 0);
        row_dots_h<<<(NN + 3) / 4, 256, 0, stream>>>(w16, NN, convs_att_s + l * HH, asb,
                                                     convs_att_d + l * HH, adb, nullptr);
        hipMemsetAsync(mb, 0, NN * sizeof(unsigned), stream);
        edge_alpha_max<<<(EE + 255) / 256, 256, 0, stream>>>(src, dst, EE, EE, asb, adb,
                                                             nullptr, nullptr, nullptr, 0.01f, abuf, mb);
        hipMemsetAsync(sb, 0, NN * sizeof(float), stream);
        edge_exp_sum<<<(EE + 255) / 256, 256, 0, stream>>>(dst, EE, EE, abuf, mb, sb);
        csr_aggregate<<<(NN + 3) / 4, 256, 0, stream>>>(rowptr, csr_src, csr_eid, NN, NN, EE,
                                                        0, 0, abuf, sb, w16, convs_b + l * HH, h16);
        gru_mfma<<<(NN + 31) / 32, 256, 0, stream>>>(h16, x16,
                                                     gruWihP + (size_t)(l + 1) * WM,
                                                     gruWhhP + (size_t)(l + 1) * WM,
                                                     gru_bih + (size_t)(l + 1) * H3,
                                                     gru_bhh + (size_t)(l + 1) * H3, NN);
    }

    // ---- molecule readout ----
    pool_csr<<<(GG + 3) / 4, 256, 0, stream>>>(brow, x16, outg16, GG);
    gemm_mfma<<<gemmGrid, 256, 0, stream>>>(x16, molWs16, nullptr, nullptr, w16, NN, HH, HH, 0);
    row_dots_h<<<(NN + 3) / 4, 256, 0, stream>>>(w16, NN, mol_att_s, asb, nullptr, nullptr, nullptr);
    compose_vec<<<1, 256, 0, stream>>>(mol_Wdst, mol_att_d, vd, HH, HH);

    for (int t = 0; t < 2; t++) {
        row_dots_h<<<(GG + 3) / 4, 256, 0, stream>>>(outg16, GG, vd, adg, nullptr, nullptr, nullptr);
        hipMemsetAsync(mg, 0, GG * sizeof(unsigned), stream);
        edge_alpha_max<<<(NN + 255) / 256, 256, 0, stream>>>(nullptr, batch, NN, NN, asb, adg,
                                                             nullptr, nullptr, nullptr, 0.01f, abuf, mg);
        hipMemsetAsync(sg, 0, GG * sizeof(float), stream);
        edge_exp_sum<<<(NN + 255) / 256, 256, 0, stream>>>(batch, NN, NN, abuf, mg, sg);
        csr_aggregate<<<(GG + 3) / 4, 256, 0, stream>>>(brow, nullptr, nullptr, GG, NN, NN,
                                                        0, 0, abuf, sg, w16, mol_b, hg16);
        gru_mfma<<<(GG + 31) / 32, 256, 0, stream>>>(hg16, outg16, mgruWihP, mgruWhhP,
                                                     mgru_bih, mgru_bhh, GG);
    }

    // ---- final linear ----
    row_dots_h<<<(GG + 3) / 4, 256, 0, stream>>>(outg16, GG, lin2_W, (float*)d_out,
                                                 nullptr, nullptr, lin2_b);
}